// Round 5
// baseline (622.370 us; speedup 1.0000x reference)
//
#include <hip/hip_runtime.h>
#include <hip/hip_bf16.h>

typedef __hip_bfloat16 hbf16;
typedef unsigned int u32;
typedef __attribute__((ext_vector_type(4))) short bf16x4;
typedef __attribute__((ext_vector_type(8))) short bf16x8;
typedef __attribute__((ext_vector_type(4))) float f32x4;

__device__ __forceinline__ float us2f(unsigned short s) {
  return __uint_as_float(((u32)s) << 16);
}

// load CPT bf16 elements (16B-aligned when CPT>=8) -> f32
template <int CPT>
__device__ __forceinline__ void loadRowBf16(const short* p, float* o) {
  if constexpr (CPT == 4) {
    bf16x4 v = *(const bf16x4*)p;
#pragma unroll
    for (int c = 0; c < 4; ++c) o[c] = us2f((unsigned short)v[c]);
  } else {
#pragma unroll
    for (int t = 0; t < CPT / 8; ++t) {
      bf16x8 v = *(const bf16x8*)(p + t * 8);
#pragma unroll
      for (int c = 0; c < 8; ++c) o[t * 8 + c] = us2f((unsigned short)v[c]);
    }
  }
}

__device__ __forceinline__ void storeO(float* p, float v) { *p = v; }
__device__ __forceinline__ void storeO(hbf16* p, float v) { *p = __float2bfloat16(v); }

// ---------------- f32 -> bf16 convert ----------------
__global__ __launch_bounds__(256) void cvt_kernel(const float* __restrict__ in,
                                                  hbf16* __restrict__ out, int n) {
  int i = (blockIdx.x * 256 + threadIdx.x) * 4;
  if (i >= n) return;
  float4 v = *(const float4*)(in + i);
  out[i] = __float2bfloat16(v.x);
  out[i + 1] = __float2bfloat16(v.y);
  out[i + 2] = __float2bfloat16(v.z);
  out[i + 3] = __float2bfloat16(v.w);
}

// ---------------- W[K][N] f32 -> Wt[N][K] bf16 (32x32 tiles) ----------------
__global__ __launch_bounds__(256) void transpose_cvt_kernel(
    const float* __restrict__ W, hbf16* __restrict__ Wt, int K, int N) {
  __shared__ hbf16 tile[32][33];
  const int n0 = blockIdx.x * 32, k0 = blockIdx.y * 32;
  const int tx = threadIdx.x, ty = threadIdx.y;  // 32 x 8
#pragma unroll
  for (int i = 0; i < 4; ++i)
    tile[ty * 4 + i][tx] = __float2bfloat16(W[(size_t)(k0 + ty * 4 + i) * N + n0 + tx]);
  __syncthreads();
#pragma unroll
  for (int i = 0; i < 4; ++i)
    Wt[(size_t)(n0 + ty * 4 + i) * K + k0 + tx] = tile[tx][ty * 4 + i];
}

// ---------------- MFMA GEMM: C[M,N] = A[M,K](bf16) @ Bt[N,K](bf16)^T + bias ----
__global__ __launch_bounds__(256) void mfma_gemm_kernel_dummy() {}
template <typename OutT>
__global__ __launch_bounds__(256) void mfma_gemm_kernel(
    const hbf16* __restrict__ A, const hbf16* __restrict__ Bt,
    const float* __restrict__ bias, OutT* __restrict__ C, int M, int N, int K) {
  const int tid = threadIdx.x, lane = tid & 63, w = tid >> 6;
  const int wr = w >> 1, wc = w & 1;
  const int rowb = blockIdx.y * 128 + wr * 64;
  const int colb = blockIdx.x * 128 + wc * 64;
  const int lr = lane & 15, lk = (lane >> 4) * 8;

  f32x4 acc[4][4];
#pragma unroll
  for (int mi = 0; mi < 4; ++mi)
#pragma unroll
    for (int ni = 0; ni < 4; ++ni) acc[mi][ni] = {0.f, 0.f, 0.f, 0.f};

  const short* Ap = (const short*)A;
  const short* Bp = (const short*)Bt;

  int ar[4];
#pragma unroll
  for (int mi = 0; mi < 4; ++mi) {
    int r = rowb + mi * 16 + lr;
    ar[mi] = (r < M) ? r : (M - 1);  // clamp: garbage rows never stored
  }

#pragma unroll 2
  for (int k0 = 0; k0 < K; k0 += 32) {
    bf16x8 af[4], bfr[4];
#pragma unroll
    for (int mi = 0; mi < 4; ++mi)
      af[mi] = *(const bf16x8*)(Ap + (size_t)ar[mi] * K + k0 + lk);
#pragma unroll
    for (int ni = 0; ni < 4; ++ni)
      bfr[ni] = *(const bf16x8*)(Bp + (size_t)(colb + ni * 16 + lr) * K + k0 + lk);
#pragma unroll
    for (int mi = 0; mi < 4; ++mi)
#pragma unroll
      for (int ni = 0; ni < 4; ++ni)
        acc[mi][ni] = __builtin_amdgcn_mfma_f32_16x16x32_bf16(af[mi], bfr[ni],
                                                              acc[mi][ni], 0, 0, 0);
  }

  float bv[4];
#pragma unroll
  for (int ni = 0; ni < 4; ++ni) bv[ni] = bias[colb + ni * 16 + lr];
#pragma unroll
  for (int mi = 0; mi < 4; ++mi) {
    const int row0 = rowb + mi * 16 + (lane >> 4) * 4;
#pragma unroll
    for (int r = 0; r < 4; ++r) {
      const int row = row0 + r;
      if (row >= M) continue;
#pragma unroll
      for (int ni = 0; ni < 4; ++ni)
        storeO(&C[(size_t)row * N + colb + ni * 16 + lr], acc[mi][ni][r] + bv[ni]);
    }
  }
}

// ---------------- CSR build ----------------
__global__ __launch_bounds__(256) void hist_kernel(const int* __restrict__ dst,
                                                   int* __restrict__ P, int E) {
  int i = blockIdx.x * 256 + threadIdx.x;
  if (i < E) atomicAdd(&P[dst[i]], 1);
}

__global__ __launch_bounds__(256) void scan_kernel(int* __restrict__ P, int n) {
  __shared__ int buf[256];
  __shared__ int carry;
  if (threadIdx.x == 0) carry = 0;
  __syncthreads();
  for (int base = 0; base < n; base += 256) {
    int i = base + threadIdx.x;
    int v = (i < n) ? P[i] : 0;
    buf[threadIdx.x] = v;
    __syncthreads();
#pragma unroll
    for (int off = 1; off < 256; off <<= 1) {
      int t = (threadIdx.x >= off) ? buf[threadIdx.x - off] : 0;
      __syncthreads();
      buf[threadIdx.x] += t;
      __syncthreads();
    }
    int excl = buf[threadIdx.x] - v + carry;
    if (i < n) P[i] = excl;
    int tot = buf[255];
    __syncthreads();
    if (threadIdx.x == 0) carry += tot;
    __syncthreads();
  }
}

__global__ __launch_bounds__(256) void scatter_kernel(const int* __restrict__ dst,
                                                      int* __restrict__ P,
                                                      int* __restrict__ perm, int E) {
  int i = blockIdx.x * 256 + threadIdx.x;
  if (i < E) {
    int pos = atomicAdd(&P[dst[i]], 1);
    perm[pos] = i;
  }
}

// ---------------- fused GATv2 edge phase ----------------
// One block per dst node, 4 waves. Each wave handles 1/4 of the node's edges
// across ALL heads: 16 lanes per head, CPT channels per lane (HC = 64*CPT).
// Independent online-softmax state per wave; LDS merge at the end.
template <int CPT, bool SILU, bool WLOG>
__global__ __launch_bounds__(256) void fused_gat_kernel(
    const hbf16* __restrict__ xl, const hbf16* __restrict__ xr,
    const float* __restrict__ ea, const float* __restrict__ We,
    const float* __restrict__ att, const int* __restrict__ src,
    const int* __restrict__ Pend, const int* __restrict__ perm,
    const float* __restrict__ bias, hbf16* __restrict__ out,
    float* __restrict__ logit_out, float* __restrict__ mfin,
    float* __restrict__ sfin) {
  constexpr int HC = 64 * CPT;
  const int d = blockIdx.x;
  const int tid = threadIdx.x, lane = tid & 63, w = tid >> 6;
  const int beg = (d == 0) ? 0 : Pend[d - 1], end = Pend[d];
  const int j0 = lane * CPT;
  const int h = lane >> 4;

  float xrv[CPT], attv[CPT], we0[CPT], we1[CPT], we2[CPT];
  loadRowBf16<CPT>((const short*)xr + (size_t)d * HC + j0, xrv);
#pragma unroll
  for (int c = 0; c < CPT; ++c) {
    attv[c] = att[j0 + c];
    we0[c] = We[j0 + c];
    we1[c] = We[HC + j0 + c];
    we2[c] = We[2 * HC + j0 + c];
  }

  float m_run = -INFINITY, ssum = 0.f, acc[CPT];
#pragma unroll
  for (int c = 0; c < CPT; ++c) acc[c] = 0.f;

  // software pipeline: row 1 edge ahead, scalars 2 edges ahead
  int i = beg + w;
  int eidC = 0, eidN = 0;
  float e0C = 0, e1C = 0, e2C = 0, e0N = 0, e1N = 0, e2N = 0;
  float xln[CPT];
  if (i < end) {
    eidC = perm[i];
    int s = src[eidC];
    e0C = ea[3 * (size_t)eidC]; e1C = ea[3 * (size_t)eidC + 1]; e2C = ea[3 * (size_t)eidC + 2];
    loadRowBf16<CPT>((const short*)xl + (size_t)s * HC + j0, xln);
  }
  if (i + 4 < end) {
    eidN = perm[i + 4];
    e0N = ea[3 * (size_t)eidN]; e1N = ea[3 * (size_t)eidN + 1]; e2N = ea[3 * (size_t)eidN + 2];
  }

  while (i < end) {
    float xlv[CPT];
#pragma unroll
    for (int c = 0; c < CPT; ++c) xlv[c] = xln[c];
    const int eid = eidC;
    const float e0 = e0C, e1 = e1C, e2 = e2C;
    if (i + 4 < end) {
      int s = src[eidN];
      loadRowBf16<CPT>((const short*)xl + (size_t)s * HC + j0, xln);
      eidC = eidN; e0C = e0N; e1C = e1N; e2C = e2N;
      if (i + 8 < end) {
        eidN = perm[i + 8];
        e0N = ea[3 * (size_t)eidN]; e1N = ea[3 * (size_t)eidN + 1];
        e2N = ea[3 * (size_t)eidN + 2];
      }
    }
    float p = 0.f;
#pragma unroll
    for (int c = 0; c < CPT; ++c) {
      float u = xlv[c] + xrv[c] + e0 * we0[c] + e1 * we1[c] + e2 * we2[c];
      u = (u > 0.f) ? u : 0.2f * u;
      p = fmaf(u, attv[c], p);
    }
    p += __shfl_xor(p, 1);
    p += __shfl_xor(p, 2);
    p += __shfl_xor(p, 4);
    p += __shfl_xor(p, 8);
    if (WLOG && (lane & 15) == 0) logit_out[(size_t)eid * 4 + h] = p;
    if (p > m_run) {  // group-uniform defer-rescale (predicated across groups)
      const float sc = __expf(m_run - p);
      ssum *= sc;
#pragma unroll
      for (int c = 0; c < CPT; ++c) acc[c] *= sc;
      m_run = p;
    }
    const float pe = __expf(p - m_run);
    ssum += pe;
#pragma unroll
    for (int c = 0; c < CPT; ++c) acc[c] = fmaf(pe, xlv[c], acc[c]);
    i += 4;
  }

  // merge 4 per-wave softmax states (c-major LDS: conflict-free)
  __shared__ float accS[4][CPT][64];
  __shared__ float msS[4][2][64];
#pragma unroll
  for (int c = 0; c < CPT; ++c) accS[w][c][lane] = acc[c];
  msS[w][0][lane] = m_run;
  msS[w][1][lane] = ssum;
  __syncthreads();
  if (w == 0) {
    const float m0 = msS[0][0][lane], m1 = msS[1][0][lane];
    const float m2 = msS[2][0][lane], m3 = msS[3][0][lane];
    const float ms = fmaxf(fmaxf(m0, m1), fmaxf(m2, m3));
    const float f0 = (m0 == -INFINITY) ? 0.f : __expf(m0 - ms);
    const float f1 = (m1 == -INFINITY) ? 0.f : __expf(m1 - ms);
    const float f2 = (m2 == -INFINITY) ? 0.f : __expf(m2 - ms);
    const float f3 = (m3 == -INFINITY) ? 0.f : __expf(m3 - ms);
    const float st = f0 * msS[0][1][lane] + f1 * msS[1][1][lane] +
                     f2 * msS[2][1][lane] + f3 * msS[3][1][lane];
    const float inv = (end > beg) ? 1.f / st : 0.f;
#pragma unroll
    for (int c = 0; c < CPT; ++c) {
      float a = f0 * accS[0][c][lane] + f1 * accS[1][c][lane] +
                f2 * accS[2][c][lane] + f3 * accS[3][c][lane];
      float o = a * inv + bias[j0 + c];
      if (SILU) o = o / (1.f + __expf(-o));
      out[(size_t)d * HC + j0 + c] = __float2bfloat16(o);
    }
    if (WLOG && (lane & 15) == 0) {
      mfin[d * 4 + h] = ms;
      sfin[d * 4 + h] = st;
    }
  }
}

// in-place: logit -> alpha = exp(l - mfin[dst]) / sfin[dst]
__global__ __launch_bounds__(256) void alpha_kernel(
    float* __restrict__ la, const float* __restrict__ mfin,
    const float* __restrict__ sfin, const int* __restrict__ dst, int n4) {
  int i = blockIdx.x * 256 + threadIdx.x;
  if (i >= n4) return;
  int e = i >> 2, h = i & 3;
  int d = dst[e];
  la[i] = __expf(la[i] - mfin[d * 4 + h]) / sfin[d * 4 + h];
}

extern "C" void kernel_launch(void* const* d_in, const int* in_sizes, int n_in,
                              void* d_out, int out_size, void* d_ws, size_t ws_size,
                              hipStream_t stream) {
  const float* x    = (const float*)d_in[0];
  const int*   ei   = (const int*)d_in[1];
  const float* ea   = (const float*)d_in[2];
  const float* W1l  = (const float*)d_in[3];
  const float* b1l  = (const float*)d_in[4];
  const float* W1r  = (const float*)d_in[5];
  const float* b1r  = (const float*)d_in[6];
  const float* W1e  = (const float*)d_in[7];
  const float* att1 = (const float*)d_in[8];
  const float* bias1= (const float*)d_in[9];
  const float* W2l  = (const float*)d_in[10];
  const float* b2l  = (const float*)d_in[11];
  const float* W2r  = (const float*)d_in[12];
  const float* b2r  = (const float*)d_in[13];
  const float* W2e  = (const float*)d_in[14];
  const float* att2 = (const float*)d_in[15];
  const float* bias2= (const float*)d_in[16];
  const float* Wp   = (const float*)d_in[17];
  const float* bp   = (const float*)d_in[18];

  const int N = in_sizes[0] / 256;  // 10000
  const int E = in_sizes[1] / 2;    // 320000
  const int* srcI = ei;
  const int* dstI = ei + E;

  // workspace (~70 MB)
  float* wsf = (float*)d_ws;
  float* mfin = wsf;                              // 4N
  float* sfin = mfin + (size_t)4 * N;             // 4N
  int*   P    = (int*)(sfin + (size_t)4 * N);     // N
  int*   perm = P + N;                            // E
  hbf16* xb   = (hbf16*)(perm + E);               // N*256
  hbf16* xlb  = xb + (size_t)N * 256;             // N*1024 (L1: first N*256)
  hbf16* xrb  = xlb + (size_t)N * 1024;           // N*1024
  hbf16* ho   = xrb + (size_t)N * 1024;           // N*1024 (h first N*256, then out2)
  hbf16* W1lt = ho + (size_t)N * 1024;            // 256*256
  hbf16* W1rt = W1lt + 256 * 256;
  hbf16* W2lt = W1rt + 256 * 256;                 // 1024*256
  hbf16* W2rt = W2lt + 1024 * 256;
  hbf16* Wpt  = W2rt + 1024 * 256;                // 256*1024

  float* yout = (float*)d_out;                    // N*256
  float* alpha_out = yout + (size_t)N * 256;      // E*4

  const int eB = (E + 255) / 256;
  const dim3 tb(32, 8);

  // CSR build
  hipMemsetAsync(P, 0, (size_t)N * 4, stream);
  hist_kernel<<<eB, 256, 0, stream>>>(dstI, P, E);
  scan_kernel<<<1, 256, 0, stream>>>(P, N);
  scatter_kernel<<<eB, 256, 0, stream>>>(dstI, P, perm, E);

  // bf16 conversions
  cvt_kernel<<<(N * 256 / 4 + 255) / 256, 256, 0, stream>>>(x, xb, N * 256);
  transpose_cvt_kernel<<<dim3(256 / 32, 256 / 32), tb, 0, stream>>>(W1l, W1lt, 256, 256);
  transpose_cvt_kernel<<<dim3(256 / 32, 256 / 32), tb, 0, stream>>>(W1r, W1rt, 256, 256);
  transpose_cvt_kernel<<<dim3(1024 / 32, 256 / 32), tb, 0, stream>>>(W2l, W2lt, 256, 1024);
  transpose_cvt_kernel<<<dim3(1024 / 32, 256 / 32), tb, 0, stream>>>(W2r, W2rt, 256, 1024);
  transpose_cvt_kernel<<<dim3(256 / 32, 1024 / 32), tb, 0, stream>>>(Wp, Wpt, 1024, 256);

  const dim3 g256(256 / 128, (N + 127) / 128);
  const dim3 g1024(1024 / 128, (N + 127) / 128);

  // ---------------- layer 1 (HC=256, CPT=4) ----------------
  mfma_gemm_kernel<hbf16><<<g256, 256, 0, stream>>>(xb, W1lt, b1l, xlb, N, 256, 256);
  mfma_gemm_kernel<hbf16><<<g256, 256, 0, stream>>>(xb, W1rt, b1r, xrb, N, 256, 256);
  fused_gat_kernel<4, true, false><<<N, 256, 0, stream>>>(
      xlb, xrb, ea, W1e, att1, srcI, P, perm, bias1, ho /*h*/,
      nullptr, nullptr, nullptr);

  // ---------------- layer 2 (HC=1024, CPT=16) ----------------
  mfma_gemm_kernel<hbf16><<<g1024, 256, 0, stream>>>(ho, W2lt, b2l, xlb, N, 1024, 256);
  mfma_gemm_kernel<hbf16><<<g1024, 256, 0, stream>>>(ho, W2rt, b2r, xrb, N, 1024, 256);
  fused_gat_kernel<16, false, true><<<N, 256, 0, stream>>>(
      xlb, xrb, ea, W2e, att2, srcI, P, perm, bias2, ho /*out2, h dead*/,
      alpha_out, mfin, sfin);
  alpha_kernel<<<(E * 4 + 255) / 256, 256, 0, stream>>>(alpha_out, mfin, sfin, dstI, E * 4);

  // projector
  mfma_gemm_kernel<float><<<g256, 256, 0, stream>>>(ho, Wpt, bp, yout, N, 256, 1024);
}

// Round 6
// 527.052 us; speedup vs baseline: 1.1809x; 1.1809x over previous
//
#include <hip/hip_runtime.h>
#include <hip/hip_bf16.h>

typedef __hip_bfloat16 hbf16;
typedef unsigned int u32;
typedef __attribute__((ext_vector_type(4))) short bf16x4;
typedef __attribute__((ext_vector_type(8))) short bf16x8;
typedef __attribute__((ext_vector_type(4))) float f32x4;

__device__ __forceinline__ float us2f(unsigned short s) {
  return __uint_as_float(((u32)s) << 16);
}

template <int CPT>
__device__ __forceinline__ void loadRowBf16(const short* p, float* o) {
  if constexpr (CPT == 1) {
    o[0] = us2f(*(const unsigned short*)p);
  } else if constexpr (CPT == 4) {
    bf16x4 v = *(const bf16x4*)p;
#pragma unroll
    for (int c = 0; c < 4; ++c) o[c] = us2f((unsigned short)v[c]);
  }
}

__device__ __forceinline__ void storeO(float* p, float v) { *p = v; }
__device__ __forceinline__ void storeO(hbf16* p, float v) { *p = __float2bfloat16(v); }

// ---------------- f32 -> bf16 convert ----------------
__global__ __launch_bounds__(256) void cvt_kernel(const float* __restrict__ in,
                                                  hbf16* __restrict__ out, int n) {
  int i = (blockIdx.x * 256 + threadIdx.x) * 4;
  if (i >= n) return;
  float4 v = *(const float4*)(in + i);
  out[i] = __float2bfloat16(v.x);
  out[i + 1] = __float2bfloat16(v.y);
  out[i + 2] = __float2bfloat16(v.z);
  out[i + 3] = __float2bfloat16(v.w);
}

// ---------------- W[K][N] f32 -> Wt[N][K] bf16 (32x32 tiles) ----------------
__global__ __launch_bounds__(256) void transpose_cvt_kernel(
    const float* __restrict__ W, hbf16* __restrict__ Wt, int K, int N) {
  __shared__ hbf16 tile[32][33];
  const int n0 = blockIdx.x * 32, k0 = blockIdx.y * 32;
  const int tx = threadIdx.x, ty = threadIdx.y;  // 32 x 8
#pragma unroll
  for (int i = 0; i < 4; ++i)
    tile[ty * 4 + i][tx] = __float2bfloat16(W[(size_t)(k0 + ty * 4 + i) * N + n0 + tx]);
  __syncthreads();
#pragma unroll
  for (int i = 0; i < 4; ++i)
    Wt[(size_t)(n0 + ty * 4 + i) * K + k0 + tx] = tile[tx][ty * 4 + i];
}

// ---- MFMA GEMM: C[M,N] = A[M,K](bf16) @ Bt[N,K](bf16)^T + dual bias (split at NS) ----
// 128x128 tile, 256 thr = 2x2 waves, each wave 64x64 = 4x4 mfma_16x16x32 frags.
template <typename OutT>
__global__ __launch_bounds__(256) void mfma_gemm_kernel(
    const hbf16* __restrict__ A, const hbf16* __restrict__ Bt,
    const float* __restrict__ bias0, const float* __restrict__ bias1, int NS,
    OutT* __restrict__ C, int M, int N, int K) {
  const int tid = threadIdx.x, lane = tid & 63, w = tid >> 6;
  const int wr = w >> 1, wc = w & 1;
  const int rowb = blockIdx.y * 128 + wr * 64;
  const int colb = blockIdx.x * 128 + wc * 64;
  const int lr = lane & 15, lk = (lane >> 4) * 8;

  f32x4 acc[4][4];
#pragma unroll
  for (int mi = 0; mi < 4; ++mi)
#pragma unroll
    for (int ni = 0; ni < 4; ++ni) acc[mi][ni] = {0.f, 0.f, 0.f, 0.f};

  const short* Ap = (const short*)A;
  const short* Bp = (const short*)Bt;

  int ar[4];
#pragma unroll
  for (int mi = 0; mi < 4; ++mi) {
    int r = rowb + mi * 16 + lr;
    ar[mi] = (r < M) ? r : (M - 1);  // clamp: garbage rows never stored
  }

#pragma unroll 2
  for (int k0 = 0; k0 < K; k0 += 32) {
    bf16x8 af[4], bfr[4];
#pragma unroll
    for (int mi = 0; mi < 4; ++mi)
      af[mi] = *(const bf16x8*)(Ap + (size_t)ar[mi] * K + k0 + lk);
#pragma unroll
    for (int ni = 0; ni < 4; ++ni)
      bfr[ni] = *(const bf16x8*)(Bp + (size_t)(colb + ni * 16 + lr) * K + k0 + lk);
#pragma unroll
    for (int mi = 0; mi < 4; ++mi)
#pragma unroll
      for (int ni = 0; ni < 4; ++ni)
        acc[mi][ni] = __builtin_amdgcn_mfma_f32_16x16x32_bf16(af[mi], bfr[ni],
                                                              acc[mi][ni], 0, 0, 0);
  }

  float bv[4];
#pragma unroll
  for (int ni = 0; ni < 4; ++ni) {
    int gc = colb + ni * 16 + lr;
    bv[ni] = (gc < NS) ? bias0[gc] : bias1[gc - NS];
  }
#pragma unroll
  for (int mi = 0; mi < 4; ++mi) {
    const int row0 = rowb + mi * 16 + (lane >> 4) * 4;
#pragma unroll
    for (int r = 0; r < 4; ++r) {
      const int row = row0 + r;
      if (row >= M) continue;
#pragma unroll
      for (int ni = 0; ni < 4; ++ni)
        storeO(&C[(size_t)row * N + colb + ni * 16 + lr], acc[mi][ni][r] + bv[ni]);
    }
  }
}

// ---------------- CSR build ----------------
__global__ __launch_bounds__(256) void hist_kernel(const int* __restrict__ dst,
                                                   int* __restrict__ P, int E) {
  int i = blockIdx.x * 256 + threadIdx.x;
  if (i < E) atomicAdd(&P[dst[i]], 1);
}

__global__ __launch_bounds__(256) void scan_kernel(int* __restrict__ P, int n) {
  __shared__ int buf[256];
  __shared__ int carry;
  if (threadIdx.x == 0) carry = 0;
  __syncthreads();
  for (int base = 0; base < n; base += 256) {
    int i = base + threadIdx.x;
    int v = (i < n) ? P[i] : 0;
    buf[threadIdx.x] = v;
    __syncthreads();
#pragma unroll
    for (int off = 1; off < 256; off <<= 1) {
      int t = (threadIdx.x >= off) ? buf[threadIdx.x - off] : 0;
      __syncthreads();
      buf[threadIdx.x] += t;
      __syncthreads();
    }
    int excl = buf[threadIdx.x] - v + carry;
    if (i < n) P[i] = excl;
    int tot = buf[255];
    __syncthreads();
    if (threadIdx.x == 0) carry += tot;
    __syncthreads();
  }
}

__global__ __launch_bounds__(256) void scatter_kernel(const int* __restrict__ dst,
                                                      int* __restrict__ P,
                                                      int* __restrict__ perm, int E) {
  int i = blockIdx.x * 256 + threadIdx.x;
  if (i < E) {
    int pos = atomicAdd(&P[dst[i]], 1);
    perm[pos] = i;
  }
}

// ---------------- fused GATv2 edge phase: one block per destination node ----------
// 4 waves; wave w = head w; 256 threads cover HC = 256*CPT channels (CPT per thread).
// xl/xr rows have stride ldx (merged l|r GEMM output). bf16 in, bf16 out.
template <int CPT, bool SILU, bool WLOG>
__global__ __launch_bounds__(256) void fused_gat_kernel(
    const hbf16* __restrict__ xl, const hbf16* __restrict__ xr, int ldx,
    const float* __restrict__ ea, const float* __restrict__ We,
    const float* __restrict__ att, const int* __restrict__ src,
    const int* __restrict__ Pend, const int* __restrict__ perm,
    const float* __restrict__ bias, hbf16* __restrict__ out,
    float* __restrict__ logit_out, float* __restrict__ mfin,
    float* __restrict__ sfin) {
  constexpr int HC = 256 * CPT;
  const int d = blockIdx.x;
  const int tid = threadIdx.x;
  const int lane = tid & 63;
  const int w = tid >> 6;
  const int beg = (d == 0) ? 0 : Pend[d - 1];
  const int end = Pend[d];
  const int j0 = tid * CPT;

  float xrv[CPT], attv[CPT], we0[CPT], we1[CPT], we2[CPT];
  loadRowBf16<CPT>((const short*)xr + (size_t)d * ldx + j0, xrv);
#pragma unroll
  for (int c = 0; c < CPT; ++c) {
    attv[c] = att[j0 + c];
    we0[c] = We[j0 + c];
    we1[c] = We[HC + j0 + c];
    we2[c] = We[2 * HC + j0 + c];
  }

  float m_run = -INFINITY, ssum = 0.f, acc[CPT];
#pragma unroll
  for (int c = 0; c < CPT; ++c) acc[c] = 0.f;

  __shared__ int s_eid[64];
  __shared__ int s_src[64];
  __shared__ float s_ea0[64], s_ea1[64], s_ea2[64];

  for (int base = beg; base < end; base += 64) {
    const int nb = min(64, end - base);
    if (tid < nb) {
      int eid = perm[base + tid];
      s_eid[tid] = eid;
      s_src[tid] = src[eid];
      s_ea0[tid] = ea[(size_t)eid * 3];
      s_ea1[tid] = ea[(size_t)eid * 3 + 1];
      s_ea2[tid] = ea[(size_t)eid * 3 + 2];
    }
    __syncthreads();

    // software-pipelined bf16 gather of xl rows (1 edge ahead)
    float xln[CPT];
    loadRowBf16<CPT>((const short*)xl + (size_t)s_src[0] * ldx + j0, xln);
    for (int i = 0; i < nb; ++i) {
      float xlv[CPT];
#pragma unroll
      for (int c = 0; c < CPT; ++c) xlv[c] = xln[c];
      if (i + 1 < nb)
        loadRowBf16<CPT>((const short*)xl + (size_t)s_src[i + 1] * ldx + j0, xln);
      const float e0 = s_ea0[i], e1 = s_ea1[i], e2 = s_ea2[i];
      float p = 0.f;
#pragma unroll
      for (int c = 0; c < CPT; ++c) {
        float v = xlv[c] + xrv[c] + e0 * we0[c] + e1 * we1[c] + e2 * we2[c];
        v = (v > 0.f) ? v : 0.2f * v;
        p = fmaf(v, attv[c], p);
      }
#pragma unroll
      for (int off = 32; off; off >>= 1) p += __shfl_xor(p, off);

      // wave-uniform defer-rescale: taken ~ln(deg) times per node
      if (p > m_run) {
        const float sc = __expf(m_run - p);  // __expf(-inf)=0 handles first edge
        ssum *= sc;
#pragma unroll
        for (int c = 0; c < CPT; ++c) acc[c] *= sc;
        m_run = p;
      }
      const float pe = __expf(p - m_run);
      ssum += pe;
#pragma unroll
      for (int c = 0; c < CPT; ++c) acc[c] = fmaf(pe, xlv[c], acc[c]);
      if (WLOG && lane == 0) logit_out[(size_t)s_eid[i] * 4 + w] = p;
    }
    __syncthreads();
  }

  const float inv = (end > beg) ? 1.f / ssum : 0.f;
#pragma unroll
  for (int c = 0; c < CPT; ++c) {
    int j = j0 + c;
    float o = acc[c] * inv + bias[j];
    if (SILU) o = o / (1.f + __expf(-o));
    out[(size_t)d * HC + j] = __float2bfloat16(o);
  }
  if (WLOG && lane == 0) {
    mfin[d * 4 + w] = m_run;
    sfin[d * 4 + w] = ssum;
  }
}

// in-place: logit -> alpha = exp(l - mfin[dst]) / sfin[dst]
__global__ __launch_bounds__(256) void alpha_kernel(
    float* __restrict__ la, const float* __restrict__ mfin,
    const float* __restrict__ sfin, const int* __restrict__ dst, int n4) {
  int i = blockIdx.x * 256 + threadIdx.x;
  if (i >= n4) return;
  int e = i >> 2, h = i & 3;
  int d = dst[e];
  la[i] = __expf(la[i] - mfin[d * 4 + h]) / sfin[d * 4 + h];
}

extern "C" void kernel_launch(void* const* d_in, const int* in_sizes, int n_in,
                              void* d_out, int out_size, void* d_ws, size_t ws_size,
                              hipStream_t stream) {
  const float* x    = (const float*)d_in[0];
  const int*   ei   = (const int*)d_in[1];
  const float* ea   = (const float*)d_in[2];
  const float* W1l  = (const float*)d_in[3];
  const float* b1l  = (const float*)d_in[4];
  const float* W1r  = (const float*)d_in[5];
  const float* b1r  = (const float*)d_in[6];
  const float* W1e  = (const float*)d_in[7];
  const float* att1 = (const float*)d_in[8];
  const float* bias1= (const float*)d_in[9];
  const float* W2l  = (const float*)d_in[10];
  const float* b2l  = (const float*)d_in[11];
  const float* W2r  = (const float*)d_in[12];
  const float* b2r  = (const float*)d_in[13];
  const float* W2e  = (const float*)d_in[14];
  const float* att2 = (const float*)d_in[15];
  const float* bias2= (const float*)d_in[16];
  const float* Wp   = (const float*)d_in[17];
  const float* bp   = (const float*)d_in[18];

  const int N = in_sizes[0] / 256;  // 10000
  const int E = in_sizes[1] / 2;    // 320000
  const int* srcI = ei;
  const int* dstI = ei + E;

  // workspace (~68 MB)
  float* wsf = (float*)d_ws;
  float* mfin = wsf;                              // 4N
  float* sfin = mfin + (size_t)4 * N;             // 4N
  int*   P    = (int*)(sfin + (size_t)4 * N);     // N
  int*   perm = P + N;                            // E
  hbf16* xb   = (hbf16*)(perm + E);               // N*256 (x bf16)
  hbf16* xlr  = xb + (size_t)N * 256;             // N*2048 (merged xl|xr; L1 uses N*512)
  hbf16* ho   = xlr + (size_t)N * 2048;           // N*1024 (h first N*256, then out2)
  hbf16* W1lt = ho + (size_t)N * 1024;            // 256*256  (W1rt adjacent)
  hbf16* W1rt = W1lt + 256 * 256;
  hbf16* W2lt = W1rt + 256 * 256;                 // 1024*256 (W2rt adjacent)
  hbf16* W2rt = W2lt + 1024 * 256;
  hbf16* Wpt  = W2rt + 1024 * 256;                // 256*1024

  float* yout = (float*)d_out;                    // N*256
  float* alpha_out = yout + (size_t)N * 256;      // E*4

  const int eB = (E + 255) / 256;
  const dim3 tb(32, 8);

  // CSR build
  hipMemsetAsync(P, 0, (size_t)N * 4, stream);
  hist_kernel<<<eB, 256, 0, stream>>>(dstI, P, E);
  scan_kernel<<<1, 256, 0, stream>>>(P, N);
  scatter_kernel<<<eB, 256, 0, stream>>>(dstI, P, perm, E);

  // bf16 conversions
  cvt_kernel<<<(N * 256 / 4 + 255) / 256, 256, 0, stream>>>(x, xb, N * 256);
  transpose_cvt_kernel<<<dim3(256 / 32, 256 / 32), tb, 0, stream>>>(W1l, W1lt, 256, 256);
  transpose_cvt_kernel<<<dim3(256 / 32, 256 / 32), tb, 0, stream>>>(W1r, W1rt, 256, 256);
  transpose_cvt_kernel<<<dim3(1024 / 32, 256 / 32), tb, 0, stream>>>(W2l, W2lt, 256, 1024);
  transpose_cvt_kernel<<<dim3(1024 / 32, 256 / 32), tb, 0, stream>>>(W2r, W2rt, 256, 1024);
  transpose_cvt_kernel<<<dim3(256 / 32, 1024 / 32), tb, 0, stream>>>(Wp, Wpt, 1024, 256);

  // ---------------- layer 1 (HC=256, CPT=1), merged l|r GEMM N=512 ----------------
  mfma_gemm_kernel<hbf16><<<dim3(512 / 128, (N + 127) / 128), 256, 0, stream>>>(
      xb, W1lt, b1l, b1r, 256, xlr, N, 512, 256);
  fused_gat_kernel<1, true, false><<<N, 256, 0, stream>>>(
      xlr, xlr + 256, 512, ea, W1e, att1, srcI, P, perm, bias1, ho /*h*/,
      nullptr, nullptr, nullptr);

  // ---------------- layer 2 (HC=1024, CPT=4), merged l|r GEMM N=2048 ----------------
  mfma_gemm_kernel<hbf16><<<dim3(2048 / 128, (N + 127) / 128), 256, 0, stream>>>(
      ho, W2lt, b2l, b2r, 1024, xlr, N, 2048, 256);
  fused_gat_kernel<4, false, true><<<N, 256, 0, stream>>>(
      xlr, xlr + 1024, 2048, ea, W2e, att2, srcI, P, perm, bias2, ho /*out2*/,
      alpha_out, mfin, sfin);
  alpha_kernel<<<(E * 4 + 255) / 256, 256, 0, stream>>>(alpha_out, mfin, sfin, dstI, E * 4);

  // projector
  mfma_gemm_kernel<float><<<dim3(256 / 128, (N + 127) / 128), 256, 0, stream>>>(
      ho, Wpt, bp, bp, 256, yout, N, 256, 1024);
}

// Round 7
// 511.947 us; speedup vs baseline: 1.2157x; 1.0295x over previous
//
#include <hip/hip_runtime.h>
#include <hip/hip_bf16.h>

typedef __hip_bfloat16 hbf16;
typedef unsigned int u32;
typedef __attribute__((ext_vector_type(2))) float f32x2;
typedef __attribute__((ext_vector_type(4))) short bf16x4;
typedef __attribute__((ext_vector_type(8))) short bf16x8;
typedef __attribute__((ext_vector_type(4))) float f32x4;

__device__ __forceinline__ float us2f(unsigned short s) {
  return __uint_as_float(((u32)s) << 16);
}
// expand 2 packed bf16 (one u32) -> f32 pair
__device__ __forceinline__ f32x2 bf2pair(u32 v) {
  f32x2 o;
  o[0] = __uint_as_float(v << 16);
  o[1] = __uint_as_float(v & 0xffff0000u);
  return o;
}

// ---- packed f32 VOP3P helpers (2 floats / instruction / lane) ----
__device__ __forceinline__ f32x2 pk_add(f32x2 a, f32x2 b) {
  f32x2 d; asm("v_pk_add_f32 %0, %1, %2" : "=v"(d) : "v"(a), "v"(b)); return d;
}
__device__ __forceinline__ f32x2 pk_mul(f32x2 a, f32x2 b) {
  f32x2 d; asm("v_pk_mul_f32 %0, %1, %2" : "=v"(d) : "v"(a), "v"(b)); return d;
}
__device__ __forceinline__ f32x2 pk_fma(f32x2 a, f32x2 b, f32x2 c) {
  f32x2 d; asm("v_pk_fma_f32 %0, %1, %2, %3" : "=v"(d) : "v"(a), "v"(b), "v"(c)); return d;
}
// d = a * bcast(b.lo) + c
__device__ __forceinline__ f32x2 pk_fma_b0(f32x2 a, f32x2 b, f32x2 c) {
  f32x2 d;
  asm("v_pk_fma_f32 %0, %1, %2, %3 op_sel:[0,0,0] op_sel_hi:[1,0,1]"
      : "=v"(d) : "v"(a), "v"(b), "v"(c));
  return d;
}
// d = a * bcast(b.hi) + c
__device__ __forceinline__ f32x2 pk_fma_b1(f32x2 a, f32x2 b, f32x2 c) {
  f32x2 d;
  asm("v_pk_fma_f32 %0, %1, %2, %3 op_sel:[0,1,0] op_sel_hi:[1,1,1]"
      : "=v"(d) : "v"(a), "v"(b), "v"(c));
  return d;
}

__device__ __forceinline__ void storeO(float* p, float v) { *p = v; }
__device__ __forceinline__ void storeO(hbf16* p, float v) { *p = __float2bfloat16(v); }

// ---------------- f32 -> bf16 convert ----------------
__global__ __launch_bounds__(256) void cvt_kernel(const float* __restrict__ in,
                                                  hbf16* __restrict__ out, int n) {
  int i = (blockIdx.x * 256 + threadIdx.x) * 4;
  if (i >= n) return;
  float4 v = *(const float4*)(in + i);
  out[i] = __float2bfloat16(v.x);
  out[i + 1] = __float2bfloat16(v.y);
  out[i + 2] = __float2bfloat16(v.z);
  out[i + 3] = __float2bfloat16(v.w);
}

// ---------------- W[K][N] f32 -> Wt[N][K] bf16 (32x32 tiles) ----------------
__global__ __launch_bounds__(256) void transpose_cvt_kernel(
    const float* __restrict__ W, hbf16* __restrict__ Wt, int K, int N) {
  __shared__ hbf16 tile[32][33];
  const int n0 = blockIdx.x * 32, k0 = blockIdx.y * 32;
  const int tx = threadIdx.x, ty = threadIdx.y;  // 32 x 8
#pragma unroll
  for (int i = 0; i < 4; ++i)
    tile[ty * 4 + i][tx] = __float2bfloat16(W[(size_t)(k0 + ty * 4 + i) * N + n0 + tx]);
  __syncthreads();
#pragma unroll
  for (int i = 0; i < 4; ++i)
    Wt[(size_t)(n0 + ty * 4 + i) * K + k0 + tx] = tile[tx][ty * 4 + i];
}

// ---- MFMA GEMM: C[M,N] = A[M,K](bf16) @ Bt[N,K](bf16)^T + dual bias (split at NS) ----
template <typename OutT>
__global__ __launch_bounds__(256) void mfma_gemm_kernel(
    const hbf16* __restrict__ A, const hbf16* __restrict__ Bt,
    const float* __restrict__ bias0, const float* __restrict__ bias1, int NS,
    OutT* __restrict__ C, int M, int N, int K) {
  const int tid = threadIdx.x, lane = tid & 63, w = tid >> 6;
  const int wr = w >> 1, wc = w & 1;
  const int rowb = blockIdx.y * 128 + wr * 64;
  const int colb = blockIdx.x * 128 + wc * 64;
  const int lr = lane & 15, lk = (lane >> 4) * 8;

  f32x4 acc[4][4];
#pragma unroll
  for (int mi = 0; mi < 4; ++mi)
#pragma unroll
    for (int ni = 0; ni < 4; ++ni) acc[mi][ni] = {0.f, 0.f, 0.f, 0.f};

  const short* Ap = (const short*)A;
  const short* Bp = (const short*)Bt;

  int ar[4];
#pragma unroll
  for (int mi = 0; mi < 4; ++mi) {
    int r = rowb + mi * 16 + lr;
    ar[mi] = (r < M) ? r : (M - 1);  // clamp: garbage rows never stored
  }

#pragma unroll 2
  for (int k0 = 0; k0 < K; k0 += 32) {
    bf16x8 af[4], bfr[4];
#pragma unroll
    for (int mi = 0; mi < 4; ++mi)
      af[mi] = *(const bf16x8*)(Ap + (size_t)ar[mi] * K + k0 + lk);
#pragma unroll
    for (int ni = 0; ni < 4; ++ni)
      bfr[ni] = *(const bf16x8*)(Bp + (size_t)(colb + ni * 16 + lr) * K + k0 + lk);
#pragma unroll
    for (int mi = 0; mi < 4; ++mi)
#pragma unroll
      for (int ni = 0; ni < 4; ++ni)
        acc[mi][ni] = __builtin_amdgcn_mfma_f32_16x16x32_bf16(af[mi], bfr[ni],
                                                              acc[mi][ni], 0, 0, 0);
  }

  float bv[4];
#pragma unroll
  for (int ni = 0; ni < 4; ++ni) {
    int gc = colb + ni * 16 + lr;
    bv[ni] = (gc < NS) ? bias0[gc] : bias1[gc - NS];
  }
#pragma unroll
  for (int mi = 0; mi < 4; ++mi) {
    const int row0 = rowb + mi * 16 + (lane >> 4) * 4;
#pragma unroll
    for (int r = 0; r < 4; ++r) {
      const int row = row0 + r;
      if (row >= M) continue;
#pragma unroll
      for (int ni = 0; ni < 4; ++ni)
        storeO(&C[(size_t)row * N + colb + ni * 16 + lr], acc[mi][ni][r] + bv[ni]);
    }
  }
}

// ---------------- CSR build ----------------
__global__ __launch_bounds__(256) void hist_kernel(const int* __restrict__ dst,
                                                   int* __restrict__ P, int E) {
  int i = blockIdx.x * 256 + threadIdx.x;
  if (i < E) atomicAdd(&P[dst[i]], 1);
}

__global__ __launch_bounds__(256) void scan_kernel(int* __restrict__ P, int n) {
  __shared__ int buf[256];
  __shared__ int carry;
  if (threadIdx.x == 0) carry = 0;
  __syncthreads();
  for (int base = 0; base < n; base += 256) {
    int i = base + threadIdx.x;
    int v = (i < n) ? P[i] : 0;
    buf[threadIdx.x] = v;
    __syncthreads();
#pragma unroll
    for (int off = 1; off < 256; off <<= 1) {
      int t = (threadIdx.x >= off) ? buf[threadIdx.x - off] : 0;
      __syncthreads();
      buf[threadIdx.x] += t;
      __syncthreads();
    }
    int excl = buf[threadIdx.x] - v + carry;
    if (i < n) P[i] = excl;
    int tot = buf[255];
    __syncthreads();
    if (threadIdx.x == 0) carry += tot;
    __syncthreads();
  }
}

__global__ __launch_bounds__(256) void scatter_kernel(const int* __restrict__ dst,
                                                      int* __restrict__ P,
                                                      int* __restrict__ perm, int E) {
  int i = blockIdx.x * 256 + threadIdx.x;
  if (i < E) {
    int pos = atomicAdd(&P[dst[i]], 1);
    perm[pos] = i;
  }
}

// ---------------- fused GATv2 layer 1 (HC=256, CPT=1, scalar path) ----------------
__global__ __launch_bounds__(256) void fused_gat_l1_kernel(
    const hbf16* __restrict__ xl, const hbf16* __restrict__ xr, int ldx,
    const float* __restrict__ ea, const float* __restrict__ We,
    const float* __restrict__ att, const int* __restrict__ src,
    const int* __restrict__ Pend, const int* __restrict__ perm,
    const float* __restrict__ bias, hbf16* __restrict__ out) {
  constexpr int HC = 256;
  const int d = blockIdx.x;
  const int tid = threadIdx.x;
  const int beg = (d == 0) ? 0 : Pend[d - 1];
  const int end = Pend[d];
  const int j0 = tid;

  float xrv = us2f(*((const unsigned short*)xr + (size_t)d * ldx + j0));
  const float attv = att[j0];
  const float we0 = We[j0], we1 = We[HC + j0], we2 = We[2 * HC + j0];

  float m_run = -INFINITY, ssum = 0.f, acc = 0.f;

  __shared__ int s_src[64];
  __shared__ float s_ea0[64], s_ea1[64], s_ea2[64];

  for (int base = beg; base < end; base += 64) {
    const int nb = min(64, end - base);
    if (tid < nb) {
      int eid = perm[base + tid];
      s_src[tid] = src[eid];
      s_ea0[tid] = ea[(size_t)eid * 3];
      s_ea1[tid] = ea[(size_t)eid * 3 + 1];
      s_ea2[tid] = ea[(size_t)eid * 3 + 2];
    }
    __syncthreads();

    float xln = us2f(*((const unsigned short*)xl + (size_t)s_src[0] * ldx + j0));
    for (int i = 0; i < nb; ++i) {
      float xlv = xln;
      if (i + 1 < nb)
        xln = us2f(*((const unsigned short*)xl + (size_t)s_src[i + 1] * ldx + j0));
      float v = xlv + xrv + s_ea0[i] * we0 + s_ea1[i] * we1 + s_ea2[i] * we2;
      v = (v > 0.f) ? v : 0.2f * v;
      float p = v * attv;
#pragma unroll
      for (int off = 32; off; off >>= 1) p += __shfl_xor(p, off);

      if (p > m_run) {
        const float sc = __expf(m_run - p);
        ssum *= sc;
        acc *= sc;
        m_run = p;
      }
      const float pe = __expf(p - m_run);
      ssum += pe;
      acc = fmaf(pe, xlv, acc);
    }
    __syncthreads();
  }

  const float inv = (end > beg) ? 1.f / ssum : 0.f;
  float o = acc * inv + bias[j0];
  o = o / (1.f + __expf(-o));  // silu
  out[(size_t)d * HC + j0] = __float2bfloat16(o);
}

// ---------------- fused GATv2 layer 2 (HC=1024, CPT=4, packed-f32 path) ----------
// 4 waves; wave w = head w (64 lanes x 4 ch). leaky folded: att*leaky(u) =
// (0.6 att) u + (0.4 att)|u|.
template <bool WLOG>
__global__ __launch_bounds__(256) void fused_gat_pk_kernel(
    const hbf16* __restrict__ xl, const hbf16* __restrict__ xr,
    const float* __restrict__ ea, const float* __restrict__ We,
    const float* __restrict__ att, const int* __restrict__ src,
    const int* __restrict__ Pend, const int* __restrict__ perm,
    const float* __restrict__ bias, hbf16* __restrict__ out,
    float* __restrict__ logit_out, float* __restrict__ mfin,
    float* __restrict__ sfin) {
  constexpr int HC = 1024, LDX = 2048, CPT = 4;
  const int d = blockIdx.x;
  const int tid = threadIdx.x, lane = tid & 63, w = tid >> 6;
  const int beg = (d == 0) ? 0 : Pend[d - 1], end = Pend[d];
  const int j0 = tid * CPT;

  f32x2 xrp[2], at6[2], at4[2], w0p[2], w1p[2], w2p[2];
  {
    uint2 rr = *(const uint2*)((const short*)xr + (size_t)d * LDX + j0);
    xrp[0] = bf2pair(rr.x);
    xrp[1] = bf2pair(rr.y);
#pragma unroll
    for (int k = 0; k < 2; ++k) {
      f32x2 a = *(const f32x2*)(att + j0 + 2 * k);
      at6[k][0] = 0.6f * a[0]; at6[k][1] = 0.6f * a[1];
      at4[k][0] = 0.4f * a[0]; at4[k][1] = 0.4f * a[1];
      w0p[k] = *(const f32x2*)(We + j0 + 2 * k);
      w1p[k] = *(const f32x2*)(We + HC + j0 + 2 * k);
      w2p[k] = *(const f32x2*)(We + 2 * HC + j0 + 2 * k);
    }
  }

  float m_run = -INFINITY, ssum = 0.f;
  f32x2 accp[2] = {{0.f, 0.f}, {0.f, 0.f}};

  __shared__ int s_src[64];
  __shared__ int s_eid[64];
  __shared__ f32x2 s_e01[64];
  __shared__ f32x2 s_e22[64];

  for (int base = beg; base < end; base += 64) {
    const int nb = min(64, end - base);
    if (tid < nb) {
      int eid = perm[base + tid];
      s_eid[tid] = eid;
      s_src[tid] = src[eid];
      float a0 = ea[(size_t)eid * 3], a1 = ea[(size_t)eid * 3 + 1],
            a2 = ea[(size_t)eid * 3 + 2];
      f32x2 t01; t01[0] = a0; t01[1] = a1;
      f32x2 t22; t22[0] = a2; t22[1] = a2;
      s_e01[tid] = t01;
      s_e22[tid] = t22;
    }
    __syncthreads();

    // software-pipelined bf16 gather (1 edge ahead)
    uint2 raw = *(const uint2*)((const short*)xl + (size_t)s_src[0] * LDX + j0);
    for (int i = 0; i < nb; ++i) {
      const uint2 cr = raw;
      if (i + 1 < nb)
        raw = *(const uint2*)((const short*)xl + (size_t)s_src[i + 1] * LDX + j0);
      const f32x2 x0 = bf2pair(cr.x), x1 = bf2pair(cr.y);
      const f32x2 e01 = s_e01[i], e22 = s_e22[i];

      f32x2 u0 = pk_add(x0, xrp[0]);
      u0 = pk_fma_b0(w0p[0], e01, u0);
      u0 = pk_fma_b1(w1p[0], e01, u0);
      u0 = pk_fma(w2p[0], e22, u0);
      f32x2 u1 = pk_add(x1, xrp[1]);
      u1 = pk_fma_b0(w0p[1], e01, u1);
      u1 = pk_fma_b1(w1p[1], e01, u1);
      u1 = pk_fma(w2p[1], e22, u1);
      f32x2 b0, b1v;
      b0[0] = __builtin_fabsf(u0[0]); b0[1] = __builtin_fabsf(u0[1]);
      b1v[0] = __builtin_fabsf(u1[0]); b1v[1] = __builtin_fabsf(u1[1]);
      f32x2 p2 = pk_mul(u0, at6[0]);
      p2 = pk_fma(b0, at4[0], p2);
      p2 = pk_fma(u1, at6[1], p2);
      p2 = pk_fma(b1v, at4[1], p2);
      float p = p2[0] + p2[1];
#pragma unroll
      for (int off = 32; off; off >>= 1) p += __shfl_xor(p, off);

      if (WLOG && lane == 0) logit_out[(size_t)s_eid[i] * 4 + w] = p;

      if (p > m_run) {  // wave-uniform, ~ln(deg) times
        const float sc = __expf(m_run - p);
        ssum *= sc;
        f32x2 scv; scv[0] = sc; scv[1] = sc;
        accp[0] = pk_mul(accp[0], scv);
        accp[1] = pk_mul(accp[1], scv);
        m_run = p;
      }
      const float pe = __expf(p - m_run);
      ssum += pe;
      f32x2 pev; pev[0] = pe; pev[1] = pe;
      accp[0] = pk_fma(x0, pev, accp[0]);
      accp[1] = pk_fma(x1, pev, accp[1]);
    }
    __syncthreads();
  }

  const float inv = (end > beg) ? 1.f / ssum : 0.f;
#pragma unroll
  for (int k = 0; k < 2; ++k)
#pragma unroll
    for (int b = 0; b < 2; ++b) {
      int j = j0 + k * 2 + b;
      out[(size_t)d * HC + j] = __float2bfloat16(accp[k][b] * inv + bias[j]);
    }
  if (WLOG && lane == 0) {
    mfin[d * 4 + w] = m_run;
    sfin[d * 4 + w] = ssum;
  }
}

// in-place: logit -> alpha = exp(l - mfin[dst]) / sfin[dst]
__global__ __launch_bounds__(256) void alpha_kernel(
    float* __restrict__ la, const float* __restrict__ mfin,
    const float* __restrict__ sfin, const int* __restrict__ dst, int n4) {
  int i = blockIdx.x * 256 + threadIdx.x;
  if (i >= n4) return;
  int e = i >> 2, h = i & 3;
  int d = dst[e];
  la[i] = __expf(la[i] - mfin[d * 4 + h]) / sfin[d * 4 + h];
}

extern "C" void kernel_launch(void* const* d_in, const int* in_sizes, int n_in,
                              void* d_out, int out_size, void* d_ws, size_t ws_size,
                              hipStream_t stream) {
  const float* x    = (const float*)d_in[0];
  const int*   ei   = (const int*)d_in[1];
  const float* ea   = (const float*)d_in[2];
  const float* W1l  = (const float*)d_in[3];
  const float* b1l  = (const float*)d_in[4];
  const float* W1r  = (const float*)d_in[5];
  const float* b1r  = (const float*)d_in[6];
  const float* W1e  = (const float*)d_in[7];
  const float* att1 = (const float*)d_in[8];
  const float* bias1= (const float*)d_in[9];
  const float* W2l  = (const float*)d_in[10];
  const float* b2l  = (const float*)d_in[11];
  const float* W2r  = (const float*)d_in[12];
  const float* b2r  = (const float*)d_in[13];
  const float* W2e  = (const float*)d_in[14];
  const float* att2 = (const float*)d_in[15];
  const float* bias2= (const float*)d_in[16];
  const float* Wp   = (const float*)d_in[17];
  const float* bp   = (const float*)d_in[18];

  const int N = in_sizes[0] / 256;  // 10000
  const int E = in_sizes[1] / 2;    // 320000
  const int* srcI = ei;
  const int* dstI = ei + E;

  // workspace (~68 MB)
  float* wsf = (float*)d_ws;
  float* mfin = wsf;                              // 4N
  float* sfin = mfin + (size_t)4 * N;             // 4N
  int*   P    = (int*)(sfin + (size_t)4 * N);     // N
  int*   perm = P + N;                            // E
  hbf16* xb   = (hbf16*)(perm + E);               // N*256 (x bf16)
  hbf16* xlr  = xb + (size_t)N * 256;             // N*2048 (merged xl|xr; L1 uses N*512)
  hbf16* ho   = xlr + (size_t)N * 2048;           // N*1024 (h first N*256, then out2)
  hbf16* W1lt = ho + (size_t)N * 1024;            // 256*256  (W1rt adjacent)
  hbf16* W1rt = W1lt + 256 * 256;
  hbf16* W2lt = W1rt + 256 * 256;                 // 1024*256 (W2rt adjacent)
  hbf16* W2rt = W2lt + 1024 * 256;
  hbf16* Wpt  = W2rt + 1024 * 256;                // 256*1024

  float* yout = (float*)d_out;                    // N*256
  float* alpha_out = yout + (size_t)N * 256;      // E*4

  const int eB = (E + 255) / 256;
  const dim3 tb(32, 8);

  // CSR build
  hipMemsetAsync(P, 0, (size_t)N * 4, stream);
  hist_kernel<<<eB, 256, 0, stream>>>(dstI, P, E);
  scan_kernel<<<1, 256, 0, stream>>>(P, N);
  scatter_kernel<<<eB, 256, 0, stream>>>(dstI, P, perm, E);

  // bf16 conversions
  cvt_kernel<<<(N * 256 / 4 + 255) / 256, 256, 0, stream>>>(x, xb, N * 256);
  transpose_cvt_kernel<<<dim3(256 / 32, 256 / 32), tb, 0, stream>>>(W1l, W1lt, 256, 256);
  transpose_cvt_kernel<<<dim3(256 / 32, 256 / 32), tb, 0, stream>>>(W1r, W1rt, 256, 256);
  transpose_cvt_kernel<<<dim3(1024 / 32, 256 / 32), tb, 0, stream>>>(W2l, W2lt, 256, 1024);
  transpose_cvt_kernel<<<dim3(1024 / 32, 256 / 32), tb, 0, stream>>>(W2r, W2rt, 256, 1024);
  transpose_cvt_kernel<<<dim3(256 / 32, 1024 / 32), tb, 0, stream>>>(Wp, Wpt, 1024, 256);

  // ---------------- layer 1 (HC=256), merged l|r GEMM N=512 ----------------
  mfma_gemm_kernel<hbf16><<<dim3(512 / 128, (N + 127) / 128), 256, 0, stream>>>(
      xb, W1lt, b1l, b1r, 256, xlr, N, 512, 256);
  fused_gat_l1_kernel<<<N, 256, 0, stream>>>(
      xlr, xlr + 256, 512, ea, W1e, att1, srcI, P, perm, bias1, ho /*h*/);

  // ---------------- layer 2 (HC=1024), merged l|r GEMM N=2048 ----------------
  mfma_gemm_kernel<hbf16><<<dim3(2048 / 128, (N + 127) / 128), 256, 0, stream>>>(
      ho, W2lt, b2l, b2r, 1024, xlr, N, 2048, 256);
  fused_gat_pk_kernel<true><<<N, 256, 0, stream>>>(
      xlr, xlr + 1024, ea, W2e, att2, srcI, P, perm, bias2, ho /*out2*/,
      alpha_out, mfin, sfin);
  alpha_kernel<<<(E * 4 + 255) / 256, 256, 0, stream>>>(alpha_out, mfin, sfin, dstI, E * 4);

  // projector
  mfma_gemm_kernel<float><<<dim3(256 / 128, (N + 127) / 128), 256, 0, stream>>>(
      ho, Wpt, bp, bp, 256, yout, N, 256, 1024);
}

// Round 8
// 422.263 us; speedup vs baseline: 1.4739x; 1.2124x over previous
//
#include <hip/hip_runtime.h>
#include <hip/hip_bf16.h>

typedef __hip_bfloat16 hbf16;
typedef unsigned int u32;
typedef __attribute__((ext_vector_type(2))) float f32x2;
typedef __attribute__((ext_vector_type(8))) short bf16x8;
typedef __attribute__((ext_vector_type(4))) float f32x4;

__device__ __forceinline__ f32x2 bf2pair(u32 v) {
  f32x2 o;
  o[0] = __uint_as_float(v << 16);
  o[1] = __uint_as_float(v & 0xffff0000u);
  return o;
}
__device__ __forceinline__ float rdlane_f(float v, int i) {
  return __uint_as_float(__builtin_amdgcn_readlane(__float_as_uint(v), i));
}

// ---- packed f32 VOP3P helpers ----
__device__ __forceinline__ f32x2 pk_add(f32x2 a, f32x2 b) {
  f32x2 d; asm("v_pk_add_f32 %0, %1, %2" : "=v"(d) : "v"(a), "v"(b)); return d;
}
__device__ __forceinline__ f32x2 pk_mul(f32x2 a, f32x2 b) {
  f32x2 d; asm("v_pk_mul_f32 %0, %1, %2" : "=v"(d) : "v"(a), "v"(b)); return d;
}
__device__ __forceinline__ f32x2 pk_fma(f32x2 a, f32x2 b, f32x2 c) {
  f32x2 d; asm("v_pk_fma_f32 %0, %1, %2, %3" : "=v"(d) : "v"(a), "v"(b), "v"(c)); return d;
}
// d = a * bcast(b.lo) + c   (verified R7)
__device__ __forceinline__ f32x2 pk_fma_b0(f32x2 a, f32x2 b, f32x2 c) {
  f32x2 d;
  asm("v_pk_fma_f32 %0, %1, %2, %3 op_sel:[0,0,0] op_sel_hi:[1,0,1]"
      : "=v"(d) : "v"(a), "v"(b), "v"(c));
  return d;
}
// d = a * bcast(b.hi) + c   (verified R7)
__device__ __forceinline__ f32x2 pk_fma_b1(f32x2 a, f32x2 b, f32x2 c) {
  f32x2 d;
  asm("v_pk_fma_f32 %0, %1, %2, %3 op_sel:[0,1,0] op_sel_hi:[1,1,1]"
      : "=v"(d) : "v"(a), "v"(b), "v"(c));
  return d;
}
// d = a * bcast(b.lo)
__device__ __forceinline__ f32x2 pk_mul_b0(f32x2 a, f32x2 b) {
  f32x2 d;
  asm("v_pk_mul_f32 %0, %1, %2 op_sel:[0,0] op_sel_hi:[1,0]"
      : "=v"(d) : "v"(a), "v"(b));
  return d;
}

__device__ __forceinline__ void storeO(float* p, float v) { *p = v; }
__device__ __forceinline__ void storeO(hbf16* p, float v) { *p = __float2bfloat16(v); }

// ---------------- f32 -> bf16 convert ----------------
__global__ __launch_bounds__(256) void cvt_kernel(const float* __restrict__ in,
                                                  hbf16* __restrict__ out, int n) {
  int i = (blockIdx.x * 256 + threadIdx.x) * 4;
  if (i >= n) return;
  float4 v = *(const float4*)(in + i);
  out[i] = __float2bfloat16(v.x);
  out[i + 1] = __float2bfloat16(v.y);
  out[i + 2] = __float2bfloat16(v.z);
  out[i + 3] = __float2bfloat16(v.w);
}

// ---------------- W[K][N] f32 -> Wt[N][K] bf16 (32x32 tiles) ----------------
__global__ __launch_bounds__(256) void transpose_cvt_kernel(
    const float* __restrict__ W, hbf16* __restrict__ Wt, int K, int N) {
  __shared__ hbf16 tile[32][33];
  const int n0 = blockIdx.x * 32, k0 = blockIdx.y * 32;
  const int tx = threadIdx.x, ty = threadIdx.y;  // 32 x 8
#pragma unroll
  for (int i = 0; i < 4; ++i)
    tile[ty * 4 + i][tx] = __float2bfloat16(W[(size_t)(k0 + ty * 4 + i) * N + n0 + tx]);
  __syncthreads();
#pragma unroll
  for (int i = 0; i < 4; ++i)
    Wt[(size_t)(n0 + ty * 4 + i) * K + k0 + tx] = tile[tx][ty * 4 + i];
}

// ---- MFMA GEMM: C[M,N] = A[M,K](bf16) @ Bt[N,K](bf16)^T + dual bias (split at NS) ----
template <typename OutT>
__global__ __launch_bounds__(256) void mfma_gemm_kernel(
    const hbf16* __restrict__ A, const hbf16* __restrict__ Bt,
    const float* __restrict__ bias0, const float* __restrict__ bias1, int NS,
    OutT* __restrict__ C, int M, int N, int K) {
  const int tid = threadIdx.x, lane = tid & 63, w = tid >> 6;
  const int wr = w >> 1, wc = w & 1;
  const int rowb = blockIdx.y * 128 + wr * 64;
  const int colb = blockIdx.x * 128 + wc * 64;
  const int lr = lane & 15, lk = (lane >> 4) * 8;

  f32x4 acc[4][4];
#pragma unroll
  for (int mi = 0; mi < 4; ++mi)
#pragma unroll
    for (int ni = 0; ni < 4; ++ni) acc[mi][ni] = {0.f, 0.f, 0.f, 0.f};

  const short* Ap = (const short*)A;
  const short* Bp = (const short*)Bt;

  int ar[4];
#pragma unroll
  for (int mi = 0; mi < 4; ++mi) {
    int r = rowb + mi * 16 + lr;
    ar[mi] = (r < M) ? r : (M - 1);  // clamp: garbage rows never stored
  }

#pragma unroll 2
  for (int k0 = 0; k0 < K; k0 += 32) {
    bf16x8 af[4], bfr[4];
#pragma unroll
    for (int mi = 0; mi < 4; ++mi)
      af[mi] = *(const bf16x8*)(Ap + (size_t)ar[mi] * K + k0 + lk);
#pragma unroll
    for (int ni = 0; ni < 4; ++ni)
      bfr[ni] = *(const bf16x8*)(Bp + (size_t)(colb + ni * 16 + lr) * K + k0 + lk);
#pragma unroll
    for (int mi = 0; mi < 4; ++mi)
#pragma unroll
      for (int ni = 0; ni < 4; ++ni)
        acc[mi][ni] = __builtin_amdgcn_mfma_f32_16x16x32_bf16(af[mi], bfr[ni],
                                                              acc[mi][ni], 0, 0, 0);
  }

  float bv[4];
#pragma unroll
  for (int ni = 0; ni < 4; ++ni) {
    int gc = colb + ni * 16 + lr;
    bv[ni] = (gc < NS) ? bias0[gc] : bias1[gc - NS];
  }
#pragma unroll
  for (int mi = 0; mi < 4; ++mi) {
    const int row0 = rowb + mi * 16 + (lane >> 4) * 4;
#pragma unroll
    for (int r = 0; r < 4; ++r) {
      const int row = row0 + r;
      if (row >= M) continue;
#pragma unroll
      for (int ni = 0; ni < 4; ++ni)
        storeO(&C[(size_t)row * N + colb + ni * 16 + lr], acc[mi][ni][r] + bv[ni]);
    }
  }
}

// ---------------- CSR build ----------------
__global__ __launch_bounds__(256) void hist_kernel(const int* __restrict__ dst,
                                                   int* __restrict__ P, int E) {
  int i = blockIdx.x * 256 + threadIdx.x;
  if (i < E) atomicAdd(&P[dst[i]], 1);
}

__global__ __launch_bounds__(256) void scan_kernel(int* __restrict__ P, int n) {
  __shared__ int buf[256];
  __shared__ int carry;
  if (threadIdx.x == 0) carry = 0;
  __syncthreads();
  for (int base = 0; base < n; base += 256) {
    int i = base + threadIdx.x;
    int v = (i < n) ? P[i] : 0;
    buf[threadIdx.x] = v;
    __syncthreads();
#pragma unroll
    for (int off = 1; off < 256; off <<= 1) {
      int t = (threadIdx.x >= off) ? buf[threadIdx.x - off] : 0;
      __syncthreads();
      buf[threadIdx.x] += t;
      __syncthreads();
    }
    int excl = buf[threadIdx.x] - v + carry;
    if (i < n) P[i] = excl;
    int tot = buf[255];
    __syncthreads();
    if (threadIdx.x == 0) carry += tot;
    __syncthreads();
  }
}

__global__ __launch_bounds__(256) void scatter_kernel(const int* __restrict__ dst,
                                                      int* __restrict__ P,
                                                      int* __restrict__ perm, int E) {
  int i = blockIdx.x * 256 + threadIdx.x;
  if (i < E) {
    int pos = atomicAdd(&P[dst[i]], 1);
    perm[pos] = i;
  }
}

// ---------------- fused GATv2 edge phase: ONE WAVE PER NODE ----------------
// Head h = lanes [16h,16h+16); CPT = 2*PAIRS channels/lane; HC = 128*PAIRS.
// 4 independent nodes per 256-thread block; no __syncthreads.
template <int PAIRS, bool SILU, bool WLOG>
__global__ __launch_bounds__(256) void fused_gat_wpn_kernel(
    const hbf16* __restrict__ xl, const hbf16* __restrict__ xr, int ldx,
    const float* __restrict__ ea, const float* __restrict__ We,
    const float* __restrict__ att, const int* __restrict__ src,
    const int* __restrict__ Pend, const int* __restrict__ perm,
    const float* __restrict__ bias, hbf16* __restrict__ out,
    float* __restrict__ logit_out, float* __restrict__ mfin,
    float* __restrict__ sfin, int NN) {
  constexpr int CPT = 2 * PAIRS;
  constexpr int HC = 64 * CPT;
  const int lane = threadIdx.x & 63;
  const int w = threadIdx.x >> 6;
  const int d = blockIdx.x * 4 + w;
  __shared__ float4 s_ef[4][64];
  if (d >= NN) return;
  const int beg = (d == 0) ? 0 : Pend[d - 1];
  const int end = Pend[d];
  const int j0 = lane * CPT;
  const int hgrp = lane >> 4;

  // per-lane constants
  f32x2 w0p[PAIRS], w1p[PAIRS], w2p[PAIRS], atp[PAIRS], xrp[PAIRS];
  {
    u32 xraw[PAIRS];
    const u32* xrrow = (const u32*)((const short*)xr + (size_t)d * ldx + j0);
    if constexpr (PAIRS == 2) {
      *(uint2*)xraw = *(const uint2*)xrrow;
    } else {
      *(uint4*)xraw = *(const uint4*)xrrow;
      *(uint4*)(xraw + 4) = *(const uint4*)(xrrow + 4);
    }
#pragma unroll
    for (int k = 0; k < PAIRS; ++k) {
      xrp[k] = bf2pair(xraw[k]);
      w0p[k] = *(const f32x2*)(We + j0 + 2 * k);
      w1p[k] = *(const f32x2*)(We + HC + j0 + 2 * k);
      w2p[k] = *(const f32x2*)(We + 2 * HC + j0 + 2 * k);
      atp[k] = *(const f32x2*)(att + j0 + 2 * k);
    }
  }
  f32x2 p02;
  p02[0] = 0.2f; p02[1] = 0.2f;

  float m_run = -INFINITY, ssum = 0.f;
  f32x2 accp[PAIRS];
#pragma unroll
  for (int k = 0; k < PAIRS; ++k) accp[k] = {0.f, 0.f};

  const short* xls = (const short*)xl;

  for (int base = beg; base < end; base += 64) {
    const int nb = min(64, end - base);
    int eidv = 0, sv = 0;
    if (lane < nb) {
      eidv = perm[base + lane];
      sv = src[eidv];
      float a0 = ea[3 * (size_t)eidv], a1 = ea[3 * (size_t)eidv + 1],
            a2 = ea[3 * (size_t)eidv + 2];
      s_ef[w][lane] = make_float4(a0, a1, a2, a2);
    }
    asm volatile("s_waitcnt lgkmcnt(0)" ::: "memory");

    // 1-edge-ahead pipeline on the gather
    u32 raw[PAIRS];
    {
      int s0 = __builtin_amdgcn_readlane(sv, 0);
      const u32* rp = (const u32*)(xls + (size_t)s0 * ldx + j0);
      if constexpr (PAIRS == 2) {
        *(uint2*)raw = *(const uint2*)rp;
      } else {
        *(uint4*)raw = *(const uint4*)rp;
        *(uint4*)(raw + 4) = *(const uint4*)(rp + 4);
      }
    }
    for (int i = 0; i < nb; ++i) {
      u32 cur[PAIRS];
#pragma unroll
      for (int k = 0; k < PAIRS; ++k) cur[k] = raw[k];
      const int eid = __builtin_amdgcn_readlane(eidv, i);
      if (i + 1 < nb) {
        int sn = __builtin_amdgcn_readlane(sv, i + 1);
        const u32* rp = (const u32*)(xls + (size_t)sn * ldx + j0);
        if constexpr (PAIRS == 2) {
          *(uint2*)raw = *(const uint2*)rp;
        } else {
          *(uint4*)raw = *(const uint4*)rp;
          *(uint4*)(raw + 4) = *(const uint4*)(rp + 4);
        }
      }
      const float4 ef = s_ef[w][i];
      f32x2 e01, e22;
      e01[0] = ef.x; e01[1] = ef.y;
      e22[0] = ef.z; e22[1] = ef.w;

      f32x2 xvp[PAIRS];
      f32x2 p2 = {0.f, 0.f};
#pragma unroll
      for (int k = 0; k < PAIRS; ++k) {
        f32x2 xv = bf2pair(cur[k]);
        xvp[k] = xv;
        f32x2 u = pk_add(xv, xrp[k]);
        u = pk_fma_b0(w0p[k], e01, u);
        u = pk_fma_b1(w1p[k], e01, u);
        u = pk_fma(w2p[k], e22, u);
        f32x2 t = pk_mul(u, p02);
        f32x2 l;
        l[0] = fmaxf(u[0], t[0]);
        l[1] = fmaxf(u[1], t[1]);
        p2 = pk_fma(l, atp[k], p2);
      }
      float p = p2[0] + p2[1];
      p += __shfl_xor(p, 1);
      p += __shfl_xor(p, 2);
      p += __shfl_xor(p, 4);
      p += __shfl_xor(p, 8);

      if (WLOG && (lane & 15) == 0) logit_out[(size_t)eid * 4 + hgrp] = p;

      if (__any(p > m_run)) {  // exp(0)=1 for non-growing groups -> exact
        const float nm = fmaxf(m_run, p);
        const float sc = __expf(m_run - nm);
        ssum *= sc;
        f32x2 scp;
        scp[0] = sc; scp[1] = sc;
#pragma unroll
        for (int k = 0; k < PAIRS; ++k) accp[k] = pk_mul_b0(accp[k], scp);
        m_run = nm;
      }
      const float pe = __expf(p - m_run);
      ssum += pe;
      f32x2 pep;
      pep[0] = pe; pep[1] = pe;
#pragma unroll
      for (int k = 0; k < PAIRS; ++k) accp[k] = pk_fma_b0(xvp[k], pep, accp[k]);
    }
  }

  const float inv = (end > beg) ? 1.f / ssum : 0.f;
  u32 ow[PAIRS];
#pragma unroll
  for (int k = 0; k < PAIRS; ++k) {
    float o0 = accp[k][0] * inv + bias[j0 + 2 * k];
    float o1 = accp[k][1] * inv + bias[j0 + 2 * k + 1];
    if (SILU) {
      o0 = o0 / (1.f + __expf(-o0));
      o1 = o1 / (1.f + __expf(-o1));
    }
    hbf16 h0 = __float2bfloat16(o0), h1 = __float2bfloat16(o1);
    ow[k] = (u32)(*(unsigned short*)&h0) | ((u32)(*(unsigned short*)&h1) << 16);
  }
  u32* orow = (u32*)((short*)out + (size_t)d * HC + j0);
  if constexpr (PAIRS == 2) {
    *(uint2*)orow = *(const uint2*)ow;
  } else {
    *(uint4*)orow = *(const uint4*)ow;
    *(uint4*)(orow + 4) = *(const uint4*)(ow + 4);
  }
  if (WLOG && (lane & 15) == 0) {
    mfin[d * 4 + hgrp] = m_run;
    sfin[d * 4 + hgrp] = ssum;
  }
}

// in-place: logit -> alpha = exp(l - mfin[dst]) / sfin[dst]
__global__ __launch_bounds__(256) void alpha_kernel(
    float* __restrict__ la, const float* __restrict__ mfin,
    const float* __restrict__ sfin, const int* __restrict__ dst, int n4) {
  int i = blockIdx.x * 256 + threadIdx.x;
  if (i >= n4) return;
  int e = i >> 2, h = i & 3;
  int d = dst[e];
  la[i] = __expf(la[i] - mfin[d * 4 + h]) / sfin[d * 4 + h];
}

extern "C" void kernel_launch(void* const* d_in, const int* in_sizes, int n_in,
                              void* d_out, int out_size, void* d_ws, size_t ws_size,
                              hipStream_t stream) {
  const float* x    = (const float*)d_in[0];
  const int*   ei   = (const int*)d_in[1];
  const float* ea   = (const float*)d_in[2];
  const float* W1l  = (const float*)d_in[3];
  const float* b1l  = (const float*)d_in[4];
  const float* W1r  = (const float*)d_in[5];
  const float* b1r  = (const float*)d_in[6];
  const float* W1e  = (const float*)d_in[7];
  const float* att1 = (const float*)d_in[8];
  const float* bias1= (const float*)d_in[9];
  const float* W2l  = (const float*)d_in[10];
  const float* b2l  = (const float*)d_in[11];
  const float* W2r  = (const float*)d_in[12];
  const float* b2r  = (const float*)d_in[13];
  const float* W2e  = (const float*)d_in[14];
  const float* att2 = (const float*)d_in[15];
  const float* bias2= (const float*)d_in[16];
  const float* Wp   = (const float*)d_in[17];
  const float* bp   = (const float*)d_in[18];

  const int N = in_sizes[0] / 256;  // 10000
  const int E = in_sizes[1] / 2;    // 320000
  const int* srcI = ei;
  const int* dstI = ei + E;

  // workspace (~68 MB)
  float* wsf = (float*)d_ws;
  float* mfin = wsf;                              // 4N
  float* sfin = mfin + (size_t)4 * N;             // 4N
  int*   P    = (int*)(sfin + (size_t)4 * N);     // N
  int*   perm = P + N;                            // E
  hbf16* xb   = (hbf16*)(perm + E);               // N*256 (x bf16)
  hbf16* xlr  = xb + (size_t)N * 256;             // N*2048 (merged xl|xr; L1 uses N*512)
  hbf16* ho   = xlr + (size_t)N * 2048;           // N*1024 (h first N*256, then out2)
  hbf16* W1lt = ho + (size_t)N * 1024;            // 256*256  (W1rt adjacent)
  hbf16* W1rt = W1lt + 256 * 256;
  hbf16* W2lt = W1rt + 256 * 256;                 // 1024*256 (W2rt adjacent)
  hbf16* W2rt = W2lt + 1024 * 256;
  hbf16* Wpt  = W2rt + 1024 * 256;                // 256*1024

  float* yout = (float*)d_out;                    // N*256
  float* alpha_out = yout + (size_t)N * 256;      // E*4

  const int eB = (E + 255) / 256;
  const dim3 tb(32, 8);

  // CSR build
  hipMemsetAsync(P, 0, (size_t)N * 4, stream);
  hist_kernel<<<eB, 256, 0, stream>>>(dstI, P, E);
  scan_kernel<<<1, 256, 0, stream>>>(P, N);
  scatter_kernel<<<eB, 256, 0, stream>>>(dstI, P, perm, E);

  // bf16 conversions
  cvt_kernel<<<(N * 256 / 4 + 255) / 256, 256, 0, stream>>>(x, xb, N * 256);
  transpose_cvt_kernel<<<dim3(256 / 32, 256 / 32), tb, 0, stream>>>(W1l, W1lt, 256, 256);
  transpose_cvt_kernel<<<dim3(256 / 32, 256 / 32), tb, 0, stream>>>(W1r, W1rt, 256, 256);
  transpose_cvt_kernel<<<dim3(1024 / 32, 256 / 32), tb, 0, stream>>>(W2l, W2lt, 256, 1024);
  transpose_cvt_kernel<<<dim3(1024 / 32, 256 / 32), tb, 0, stream>>>(W2r, W2rt, 256, 1024);
  transpose_cvt_kernel<<<dim3(256 / 32, 1024 / 32), tb, 0, stream>>>(Wp, Wpt, 1024, 256);

  const int nB = (N + 3) / 4;

  // ---------------- layer 1 (HC=256), merged l|r GEMM N=512 ----------------
  mfma_gemm_kernel<hbf16><<<dim3(512 / 128, (N + 127) / 128), 256, 0, stream>>>(
      xb, W1lt, b1l, b1r, 256, xlr, N, 512, 256);
  fused_gat_wpn_kernel<2, true, false><<<nB, 256, 0, stream>>>(
      xlr, xlr + 256, 512, ea, W1e, att1, srcI, P, perm, bias1, ho /*h*/,
      nullptr, nullptr, nullptr, N);

  // ---------------- layer 2 (HC=1024), merged l|r GEMM N=2048 ----------------
  mfma_gemm_kernel<hbf16><<<dim3(2048 / 128, (N + 127) / 128), 256, 0, stream>>>(
      ho, W2lt, b2l, b2r, 1024, xlr, N, 2048, 256);
  fused_gat_wpn_kernel<8, false, true><<<nB, 256, 0, stream>>>(
      xlr, xlr + 1024, 2048, ea, W2e, att2, srcI, P, perm, bias2, ho /*out2*/,
      alpha_out, mfin, sfin, N);
  alpha_kernel<<<(E * 4 + 255) / 256, 256, 0, stream>>>(alpha_out, mfin, sfin, dstI, E * 4);

  // projector
  mfma_gemm_kernel<float><<<dim3(256 / 128, (N + 127) / 128), 256, 0, stream>>>(
      ho, Wpt, bp, bp, 256, yout, N, 256, 1024);
}

// Round 9
// 406.160 us; speedup vs baseline: 1.5323x; 1.0396x over previous
//
#include <hip/hip_runtime.h>
#include <hip/hip_bf16.h>

typedef __hip_bfloat16 hbf16;
typedef unsigned int u32;
typedef __attribute__((ext_vector_type(2))) float f32x2;
typedef __attribute__((ext_vector_type(8))) short bf16x8;
typedef __attribute__((ext_vector_type(4))) float f32x4;

__device__ __forceinline__ f32x2 bf2pair(u32 v) {
  f32x2 o;
  o[0] = __uint_as_float(v << 16);
  o[1] = __uint_as_float(v & 0xffff0000u);
  return o;
}

// ---- packed f32 VOP3P helpers ----
__device__ __forceinline__ f32x2 pk_add(f32x2 a, f32x2 b) {
  f32x2 d; asm("v_pk_add_f32 %0, %1, %2" : "=v"(d) : "v"(a), "v"(b)); return d;
}
__device__ __forceinline__ f32x2 pk_mul(f32x2 a, f32x2 b) {
  f32x2 d; asm("v_pk_mul_f32 %0, %1, %2" : "=v"(d) : "v"(a), "v"(b)); return d;
}
__device__ __forceinline__ f32x2 pk_fma(f32x2 a, f32x2 b, f32x2 c) {
  f32x2 d; asm("v_pk_fma_f32 %0, %1, %2, %3" : "=v"(d) : "v"(a), "v"(b), "v"(c)); return d;
}
// d = a * bcast(b.lo) + c   (verified R7)
__device__ __forceinline__ f32x2 pk_fma_b0(f32x2 a, f32x2 b, f32x2 c) {
  f32x2 d;
  asm("v_pk_fma_f32 %0, %1, %2, %3 op_sel:[0,0,0] op_sel_hi:[1,0,1]"
      : "=v"(d) : "v"(a), "v"(b), "v"(c));
  return d;
}
// d = a * bcast(b.hi) + c   (verified R7)
__device__ __forceinline__ f32x2 pk_fma_b1(f32x2 a, f32x2 b, f32x2 c) {
  f32x2 d;
  asm("v_pk_fma_f32 %0, %1, %2, %3 op_sel:[0,1,0] op_sel_hi:[1,1,1]"
      : "=v"(d) : "v"(a), "v"(b), "v"(c));
  return d;
}
// d = a * bcast(b.lo)
__device__ __forceinline__ f32x2 pk_mul_b0(f32x2 a, f32x2 b) {
  f32x2 d;
  asm("v_pk_mul_f32 %0, %1, %2 op_sel:[0,0] op_sel_hi:[1,0]"
      : "=v"(d) : "v"(a), "v"(b));
  return d;
}

__device__ __forceinline__ void storeO(float* p, float v) { *p = v; }
__device__ __forceinline__ void storeO(hbf16* p, float v) { *p = __float2bfloat16(v); }

// ---------------- f32 -> bf16 convert ----------------
__global__ __launch_bounds__(256) void cvt_kernel(const float* __restrict__ in,
                                                  hbf16* __restrict__ out, int n) {
  int i = (blockIdx.x * 256 + threadIdx.x) * 4;
  if (i >= n) return;
  float4 v = *(const float4*)(in + i);
  out[i] = __float2bfloat16(v.x);
  out[i + 1] = __float2bfloat16(v.y);
  out[i + 2] = __float2bfloat16(v.z);
  out[i + 3] = __float2bfloat16(v.w);
}

// ---------------- W[K][N] f32 -> Wt[N][K] bf16 (32x32 tiles) ----------------
__global__ __launch_bounds__(256) void transpose_cvt_kernel(
    const float* __restrict__ W, hbf16* __restrict__ Wt, int K, int N) {
  __shared__ hbf16 tile[32][33];
  const int n0 = blockIdx.x * 32, k0 = blockIdx.y * 32;
  const int tx = threadIdx.x, ty = threadIdx.y;  // 32 x 8
#pragma unroll
  for (int i = 0; i < 4; ++i)
    tile[ty * 4 + i][tx] = __float2bfloat16(W[(size_t)(k0 + ty * 4 + i) * N + n0 + tx]);
  __syncthreads();
#pragma unroll
  for (int i = 0; i < 4; ++i)
    Wt[(size_t)(n0 + ty * 4 + i) * K + k0 + tx] = tile[tx][ty * 4 + i];
}

// ---- MFMA GEMM: C[M,N] = A[M,K](bf16) @ Bt[N,K](bf16)^T + dual bias (split at NS) ----
template <typename OutT>
__global__ __launch_bounds__(256) void mfma_gemm_kernel(
    const hbf16* __restrict__ A, const hbf16* __restrict__ Bt,
    const float* __restrict__ bias0, const float* __restrict__ bias1, int NS,
    OutT* __restrict__ C, int M, int N, int K) {
  const int tid = threadIdx.x, lane = tid & 63, w = tid >> 6;
  const int wr = w >> 1, wc = w & 1;
  const int rowb = blockIdx.y * 128 + wr * 64;
  const int colb = blockIdx.x * 128 + wc * 64;
  const int lr = lane & 15, lk = (lane >> 4) * 8;

  f32x4 acc[4][4];
#pragma unroll
  for (int mi = 0; mi < 4; ++mi)
#pragma unroll
    for (int ni = 0; ni < 4; ++ni) acc[mi][ni] = {0.f, 0.f, 0.f, 0.f};

  const short* Ap = (const short*)A;
  const short* Bp = (const short*)Bt;

  int ar[4];
#pragma unroll
  for (int mi = 0; mi < 4; ++mi) {
    int r = rowb + mi * 16 + lr;
    ar[mi] = (r < M) ? r : (M - 1);  // clamp: garbage rows never stored
  }

#pragma unroll 2
  for (int k0 = 0; k0 < K; k0 += 32) {
    bf16x8 af[4], bfr[4];
#pragma unroll
    for (int mi = 0; mi < 4; ++mi)
      af[mi] = *(const bf16x8*)(Ap + (size_t)ar[mi] * K + k0 + lk);
#pragma unroll
    for (int ni = 0; ni < 4; ++ni)
      bfr[ni] = *(const bf16x8*)(Bp + (size_t)(colb + ni * 16 + lr) * K + k0 + lk);
#pragma unroll
    for (int mi = 0; mi < 4; ++mi)
#pragma unroll
      for (int ni = 0; ni < 4; ++ni)
        acc[mi][ni] = __builtin_amdgcn_mfma_f32_16x16x32_bf16(af[mi], bfr[ni],
                                                              acc[mi][ni], 0, 0, 0);
  }

  float bv[4];
#pragma unroll
  for (int ni = 0; ni < 4; ++ni) {
    int gc = colb + ni * 16 + lr;
    bv[ni] = (gc < NS) ? bias0[gc] : bias1[gc - NS];
  }
#pragma unroll
  for (int mi = 0; mi < 4; ++mi) {
    const int row0 = rowb + mi * 16 + (lane >> 4) * 4;
#pragma unroll
    for (int r = 0; r < 4; ++r) {
      const int row = row0 + r;
      if (row >= M) continue;
#pragma unroll
      for (int ni = 0; ni < 4; ++ni)
        storeO(&C[(size_t)row * N + colb + ni * 16 + lr], acc[mi][ni][r] + bv[ni]);
    }
  }
}

// ---------------- CSR build (parallel 2-level scan) ----------------
__global__ __launch_bounds__(256) void hist_kernel(const int* __restrict__ dst,
                                                   int* __restrict__ P, int E) {
  int i = blockIdx.x * 256 + threadIdx.x;
  if (i < E) atomicAdd(&P[dst[i]], 1);
}

// per-block sums of 256-chunks
__global__ __launch_bounds__(256) void scan_sum_kernel(const int* __restrict__ P,
                                                       int* __restrict__ part, int n) {
  __shared__ int s[256];
  int i = blockIdx.x * 256 + threadIdx.x;
  s[threadIdx.x] = (i < n) ? P[i] : 0;
  __syncthreads();
#pragma unroll
  for (int off = 128; off; off >>= 1) {
    if (threadIdx.x < off) s[threadIdx.x] += s[threadIdx.x + off];
    __syncthreads();
  }
  if (threadIdx.x == 0) part[blockIdx.x] = s[0];
}

// single-block exclusive scan of partials (nb <= 256)
__global__ __launch_bounds__(256) void scan_part_kernel(int* __restrict__ part, int nb) {
  __shared__ int s[256];
  int v = (threadIdx.x < nb) ? part[threadIdx.x] : 0;
  s[threadIdx.x] = v;
  __syncthreads();
#pragma unroll
  for (int off = 1; off < 256; off <<= 1) {
    int t = (threadIdx.x >= off) ? s[threadIdx.x - off] : 0;
    __syncthreads();
    s[threadIdx.x] += t;
    __syncthreads();
  }
  if (threadIdx.x < nb) part[threadIdx.x] = s[threadIdx.x] - v;
}

// per-block exclusive scan + block offset -> P becomes exclusive offsets
__global__ __launch_bounds__(256) void scan_apply_kernel(int* __restrict__ P,
                                                         const int* __restrict__ part,
                                                         int n) {
  __shared__ int s[256];
  int i = blockIdx.x * 256 + threadIdx.x;
  int v = (i < n) ? P[i] : 0;
  s[threadIdx.x] = v;
  __syncthreads();
#pragma unroll
  for (int off = 1; off < 256; off <<= 1) {
    int t = (threadIdx.x >= off) ? s[threadIdx.x - off] : 0;
    __syncthreads();
    s[threadIdx.x] += t;
    __syncthreads();
  }
  if (i < n) P[i] = s[threadIdx.x] - v + part[blockIdx.x];
}

__global__ __launch_bounds__(256) void scatter_kernel(const int* __restrict__ dst,
                                                      int* __restrict__ P,
                                                      int* __restrict__ perm, int E) {
  int i = blockIdx.x * 256 + threadIdx.x;
  if (i < E) {
    int pos = atomicAdd(&P[dst[i]], 1);
    perm[pos] = i;
  }
}

// ---------------- fused GATv2 edge phase: ONE WAVE PER NODE, 2-edge pipeline ------
// Head h = lanes [16h,16h+16); CPT = 2*PAIRS channels/lane; HC = 128*PAIRS.
// 4 independent nodes per 256-thread block; no __syncthreads.
template <int PAIRS, bool SILU, bool WLOG>
__global__ __launch_bounds__(256) void fused_gat_wpn_kernel(
    const hbf16* __restrict__ xl, const hbf16* __restrict__ xr, int ldx,
    const float* __restrict__ ea, const float* __restrict__ We,
    const float* __restrict__ att, const int* __restrict__ src,
    const int* __restrict__ Pend, const int* __restrict__ perm,
    const float* __restrict__ bias, hbf16* __restrict__ out,
    float* __restrict__ logit_out, float* __restrict__ mfin,
    float* __restrict__ sfin, int NN) {
  constexpr int CPT = 2 * PAIRS;
  constexpr int HC = 64 * CPT;
  const int lane = threadIdx.x & 63;
  const int w = threadIdx.x >> 6;
  const int d = blockIdx.x * 4 + w;
  __shared__ float4 s_ef[4][64];
  if (d >= NN) return;
  const int beg = (d == 0) ? 0 : Pend[d - 1];
  const int end = Pend[d];
  const int j0 = lane * CPT;
  const int hgrp = lane >> 4;

  // per-lane constants
  f32x2 w0p[PAIRS], w1p[PAIRS], w2p[PAIRS], atp[PAIRS], xrp[PAIRS];
  {
    u32 xraw[PAIRS];
    const u32* xrrow = (const u32*)((const short*)xr + (size_t)d * ldx + j0);
    if constexpr (PAIRS == 2) {
      *(uint2*)xraw = *(const uint2*)xrrow;
    } else {
      *(uint4*)xraw = *(const uint4*)xrrow;
      *(uint4*)(xraw + 4) = *(const uint4*)(xrrow + 4);
    }
#pragma unroll
    for (int k = 0; k < PAIRS; ++k) {
      xrp[k] = bf2pair(xraw[k]);
      w0p[k] = *(const f32x2*)(We + j0 + 2 * k);
      w1p[k] = *(const f32x2*)(We + HC + j0 + 2 * k);
      w2p[k] = *(const f32x2*)(We + 2 * HC + j0 + 2 * k);
      atp[k] = *(const f32x2*)(att + j0 + 2 * k);
    }
  }
  f32x2 p02;
  p02[0] = 0.2f; p02[1] = 0.2f;

  float m_run = -INFINITY, ssum = 0.f;
  f32x2 accp[PAIRS];
#pragma unroll
  for (int k = 0; k < PAIRS; ++k) accp[k] = {0.f, 0.f};

  const short* xls = (const short*)xl;

  for (int base = beg; base < end; base += 64) {
    const int nb = min(64, end - base);
    int eidv = 0, sv = 0;
    if (lane < nb) {
      eidv = perm[base + lane];
      sv = src[eidv];
      float a0 = ea[3 * (size_t)eidv], a1 = ea[3 * (size_t)eidv + 1],
            a2 = ea[3 * (size_t)eidv + 2];
      s_ef[w][lane] = make_float4(a0, a1, a2, a2);
    }
    asm volatile("s_waitcnt lgkmcnt(0)" ::: "memory");

    // 2-edge-deep pipeline
    u32 rawA[PAIRS], rawB[PAIRS];
    {
      int s0 = __builtin_amdgcn_readlane(sv, 0);
      const u32* rp = (const u32*)(xls + (size_t)s0 * ldx + j0);
      if constexpr (PAIRS == 2) { *(uint2*)rawA = *(const uint2*)rp; }
      else { *(uint4*)rawA = *(const uint4*)rp; *(uint4*)(rawA + 4) = *(const uint4*)(rp + 4); }
    }
    if (nb > 1) {
      int s1 = __builtin_amdgcn_readlane(sv, 1);
      const u32* rp = (const u32*)(xls + (size_t)s1 * ldx + j0);
      if constexpr (PAIRS == 2) { *(uint2*)rawB = *(const uint2*)rp; }
      else { *(uint4*)rawB = *(const uint4*)rp; *(uint4*)(rawB + 4) = *(const uint4*)(rp + 4); }
    }

    for (int i = 0; i < nb; i += 2) {
      const bool hasB = (i + 1) < nb;
      // ---- dot A ----
      const float4 efA = s_ef[w][i];
      f32x2 eA01, eA22;
      eA01[0] = efA.x; eA01[1] = efA.y; eA22[0] = efA.z; eA22[1] = efA.w;
      f32x2 pa2 = {0.f, 0.f};
#pragma unroll
      for (int k = 0; k < PAIRS; ++k) {
        f32x2 xv = bf2pair(rawA[k]);
        f32x2 u = pk_add(xv, xrp[k]);
        u = pk_fma_b0(w0p[k], eA01, u);
        u = pk_fma_b1(w1p[k], eA01, u);
        u = pk_fma(w2p[k], eA22, u);
        f32x2 t = pk_mul(u, p02);
        f32x2 l;
        l[0] = fmaxf(u[0], t[0]);
        l[1] = fmaxf(u[1], t[1]);
        pa2 = pk_fma(l, atp[k], pa2);
      }
      float pA = pa2[0] + pa2[1];
      // ---- dot B ----
      float pB = 0.f;
      if (hasB) {
        const float4 efB = s_ef[w][i + 1];
        f32x2 eB01, eB22;
        eB01[0] = efB.x; eB01[1] = efB.y; eB22[0] = efB.z; eB22[1] = efB.w;
        f32x2 pb2 = {0.f, 0.f};
#pragma unroll
        for (int k = 0; k < PAIRS; ++k) {
          f32x2 xv = bf2pair(rawB[k]);
          f32x2 u = pk_add(xv, xrp[k]);
          u = pk_fma_b0(w0p[k], eB01, u);
          u = pk_fma_b1(w1p[k], eB01, u);
          u = pk_fma(w2p[k], eB22, u);
          f32x2 t = pk_mul(u, p02);
          f32x2 l;
          l[0] = fmaxf(u[0], t[0]);
          l[1] = fmaxf(u[1], t[1]);
          pb2 = pk_fma(l, atp[k], pb2);
        }
        pB = pb2[0] + pb2[1];
      }
      // ---- interleaved 16-lane-group reduces ----
      pA += __shfl_xor(pA, 1);
      if (hasB) pB += __shfl_xor(pB, 1);
      pA += __shfl_xor(pA, 2);
      if (hasB) pB += __shfl_xor(pB, 2);
      pA += __shfl_xor(pA, 4);
      if (hasB) pB += __shfl_xor(pB, 4);
      pA += __shfl_xor(pA, 8);
      if (hasB) pB += __shfl_xor(pB, 8);

      if (WLOG && (lane & 15) == 0) {
        const int eidA = __builtin_amdgcn_readlane(eidv, i);
        logit_out[(size_t)eidA * 4 + hgrp] = pA;
      }
      // ---- softmax update A ----
      if (__any(pA > m_run)) {
        const float nm = fmaxf(m_run, pA);
        const float sc = __expf(m_run - nm);
        ssum *= sc;
        f32x2 scp; scp[0] = sc; scp[1] = sc;
#pragma unroll
        for (int k = 0; k < PAIRS; ++k) accp[k] = pk_mul_b0(accp[k], scp);
        m_run = nm;
      }
      {
        const float pe = __expf(pA - m_run);
        ssum += pe;
        f32x2 pep; pep[0] = pe; pep[1] = pe;
#pragma unroll
        for (int k = 0; k < PAIRS; ++k)
          accp[k] = pk_fma_b0(bf2pair(rawA[k]), pep, accp[k]);
      }
      // ---- softmax update B ----
      if (hasB) {
        if (WLOG && (lane & 15) == 0) {
          const int eidB = __builtin_amdgcn_readlane(eidv, i + 1);
          logit_out[(size_t)eidB * 4 + hgrp] = pB;
        }
        if (__any(pB > m_run)) {
          const float nm = fmaxf(m_run, pB);
          const float sc = __expf(m_run - nm);
          ssum *= sc;
          f32x2 scp; scp[0] = sc; scp[1] = sc;
#pragma unroll
          for (int k = 0; k < PAIRS; ++k) accp[k] = pk_mul_b0(accp[k], scp);
          m_run = nm;
        }
        const float pe = __expf(pB - m_run);
        ssum += pe;
        f32x2 pep; pep[0] = pe; pep[1] = pe;
#pragma unroll
        for (int k = 0; k < PAIRS; ++k)
          accp[k] = pk_fma_b0(bf2pair(rawB[k]), pep, accp[k]);
      }
      // ---- prefetch edges i+2, i+3 ----
      if (i + 2 < nb) {
        int s = __builtin_amdgcn_readlane(sv, i + 2);
        const u32* rp = (const u32*)(xls + (size_t)s * ldx + j0);
        if constexpr (PAIRS == 2) { *(uint2*)rawA = *(const uint2*)rp; }
        else { *(uint4*)rawA = *(const uint4*)rp; *(uint4*)(rawA + 4) = *(const uint4*)(rp + 4); }
      }
      if (i + 3 < nb) {
        int s = __builtin_amdgcn_readlane(sv, i + 3);
        const u32* rp = (const u32*)(xls + (size_t)s * ldx + j0);
        if constexpr (PAIRS == 2) { *(uint2*)rawB = *(const uint2*)rp; }
        else { *(uint4*)rawB = *(const uint4*)rp; *(uint4*)(rawB + 4) = *(const uint4*)(rp + 4); }
      }
    }
  }

  const float inv = (end > beg) ? 1.f / ssum : 0.f;
  u32 ow[PAIRS];
#pragma unroll
  for (int k = 0; k < PAIRS; ++k) {
    float o0 = accp[k][0] * inv + bias[j0 + 2 * k];
    float o1 = accp[k][1] * inv + bias[j0 + 2 * k + 1];
    if (SILU) {
      o0 = o0 / (1.f + __expf(-o0));
      o1 = o1 / (1.f + __expf(-o1));
    }
    hbf16 h0 = __float2bfloat16(o0), h1 = __float2bfloat16(o1);
    ow[k] = (u32)(*(unsigned short*)&h0) | ((u32)(*(unsigned short*)&h1) << 16);
  }
  u32* orow = (u32*)((short*)out + (size_t)d * HC + j0);
  if constexpr (PAIRS == 2) {
    *(uint2*)orow = *(const uint2*)ow;
  } else {
    *(uint4*)orow = *(const uint4*)ow;
    *(uint4*)(orow + 4) = *(const uint4*)(ow + 4);
  }
  if (WLOG && (lane & 15) == 0) {
    mfin[d * 4 + hgrp] = m_run;
    sfin[d * 4 + hgrp] = ssum;
  }
}

// in-place: logit -> alpha = exp(l - mfin[dst]) / sfin[dst]
__global__ __launch_bounds__(256) void alpha_kernel(
    float* __restrict__ la, const float* __restrict__ mfin,
    const float* __restrict__ sfin, const int* __restrict__ dst, int n4) {
  int i = blockIdx.x * 256 + threadIdx.x;
  if (i >= n4) return;
  int e = i >> 2, h = i & 3;
  int d = dst[e];
  la[i] = __expf(la[i] - mfin[d * 4 + h]) / sfin[d * 4 + h];
}

extern "C" void kernel_launch(void* const* d_in, const int* in_sizes, int n_in,
                              void* d_out, int out_size, void* d_ws, size_t ws_size,
                              hipStream_t stream) {
  const float* x    = (const float*)d_in[0];
  const int*   ei   = (const int*)d_in[1];
  const float* ea   = (const float*)d_in[2];
  const float* W1l  = (const float*)d_in[3];
  const float* b1l  = (const float*)d_in[4];
  const float* W1r  = (const float*)d_in[5];
  const float* b1r  = (const float*)d_in[6];
  const float* W1e  = (const float*)d_in[7];
  const float* att1 = (const float*)d_in[8];
  const float* bias1= (const float*)d_in[9];
  const float* W2l  = (const float*)d_in[10];
  const float* b2l  = (const float*)d_in[11];
  const float* W2r  = (const float*)d_in[12];
  const float* b2r  = (const float*)d_in[13];
  const float* W2e  = (const float*)d_in[14];
  const float* att2 = (const float*)d_in[15];
  const float* bias2= (const float*)d_in[16];
  const float* Wp   = (const float*)d_in[17];
  const float* bp   = (const float*)d_in[18];

  const int N = in_sizes[0] / 256;  // 10000
  const int E = in_sizes[1] / 2;    // 320000
  const int* srcI = ei;
  const int* dstI = ei + E;

  // workspace (~68 MB)
  float* wsf = (float*)d_ws;
  float* mfin = wsf;                              // 4N
  float* sfin = mfin + (size_t)4 * N;             // 4N
  int*   P    = (int*)(sfin + (size_t)4 * N);     // N
  int*   part = P + N;                            // 256 (scan partials)
  int*   perm = part + 256;                       // E
  hbf16* xb   = (hbf16*)(perm + E);               // N*256 (x bf16)
  hbf16* xlr  = xb + (size_t)N * 256;             // N*2048 (merged xl|xr; L1 uses N*512)
  hbf16* ho   = xlr + (size_t)N * 2048;           // N*1024 (h first N*256, then out2)
  hbf16* W1lt = ho + (size_t)N * 1024;            // 256*256  (W1rt adjacent)
  hbf16* W1rt = W1lt + 256 * 256;
  hbf16* W2lt = W1rt + 256 * 256;                 // 1024*256 (W2rt adjacent)
  hbf16* W2rt = W2lt + 1024 * 256;
  hbf16* Wpt  = W2rt + 1024 * 256;                // 256*1024

  float* yout = (float*)d_out;                    // N*256
  float* alpha_out = yout + (size_t)N * 256;      // E*4

  const int eB = (E + 255) / 256;
  const int sB = (N + 255) / 256;                 // 40 scan blocks
  const dim3 tb(32, 8);

  // CSR build: hist -> 2-level scan -> scatter
  hipMemsetAsync(P, 0, (size_t)N * 4, stream);
  hist_kernel<<<eB, 256, 0, stream>>>(dstI, P, E);
  scan_sum_kernel<<<sB, 256, 0, stream>>>(P, part, N);
  scan_part_kernel<<<1, 256, 0, stream>>>(part, sB);
  scan_apply_kernel<<<sB, 256, 0, stream>>>(P, part, N);
  scatter_kernel<<<eB, 256, 0, stream>>>(dstI, P, perm, E);

  // bf16 conversions
  cvt_kernel<<<(N * 256 / 4 + 255) / 256, 256, 0, stream>>>(x, xb, N * 256);
  transpose_cvt_kernel<<<dim3(256 / 32, 256 / 32), tb, 0, stream>>>(W1l, W1lt, 256, 256);
  transpose_cvt_kernel<<<dim3(256 / 32, 256 / 32), tb, 0, stream>>>(W1r, W1rt, 256, 256);
  transpose_cvt_kernel<<<dim3(1024 / 32, 256 / 32), tb, 0, stream>>>(W2l, W2lt, 256, 1024);
  transpose_cvt_kernel<<<dim3(1024 / 32, 256 / 32), tb, 0, stream>>>(W2r, W2rt, 256, 1024);
  transpose_cvt_kernel<<<dim3(256 / 32, 1024 / 32), tb, 0, stream>>>(Wp, Wpt, 1024, 256);

  const int nB = (N + 3) / 4;

  // ---------------- layer 1 (HC=256), merged l|r GEMM N=512 ----------------
  mfma_gemm_kernel<hbf16><<<dim3(512 / 128, (N + 127) / 128), 256, 0, stream>>>(
      xb, W1lt, b1l, b1r, 256, xlr, N, 512, 256);
  fused_gat_wpn_kernel<2, true, false><<<nB, 256, 0, stream>>>(
      xlr, xlr + 256, 512, ea, W1e, att1, srcI, P, perm, bias1, ho /*h*/,
      nullptr, nullptr, nullptr, N);

  // ---------------- layer 2 (HC=1024), merged l|r GEMM N=2048 ----------------
  mfma_gemm_kernel<hbf16><<<dim3(2048 / 128, (N + 127) / 128), 256, 0, stream>>>(
      ho, W2lt, b2l, b2r, 1024, xlr, N, 2048, 256);
  fused_gat_wpn_kernel<8, false, true><<<nB, 256, 0, stream>>>(
      xlr, xlr + 1024, 2048, ea, W2e, att2, srcI, P, perm, bias2, ho /*out2*/,
      alpha_out, mfin, sfin, N);
  alpha_kernel<<<(E * 4 + 255) / 256, 256, 0, stream>>>(alpha_out, mfin, sfin, dstI, E * 4);

  // projector
  mfma_gemm_kernel<float><<<dim3(256 / 128, (N + 127) / 128), 256, 0, stream>>>(
      ho, Wpt, bp, bp, 256, yout, N, 256, 1024);
}

// Round 10
// 384.716 us; speedup vs baseline: 1.6177x; 1.0557x over previous
//
#include <hip/hip_runtime.h>
#include <hip/hip_bf16.h>

typedef __hip_bfloat16 hbf16;
typedef unsigned int u32;
typedef __attribute__((ext_vector_type(2))) float f32x2;
typedef __attribute__((ext_vector_type(8))) short bf16x8;
typedef __attribute__((ext_vector_type(4))) float f32x4;

__device__ __forceinline__ f32x2 bf2pair(u32 v) {
  f32x2 o;
  o[0] = __uint_as_float(v << 16);
  o[1] = __uint_as_float(v & 0xffff0000u);
  return o;
}

// ---- packed f32 VOP3P helpers ----
__device__ __forceinline__ f32x2 pk_add(f32x2 a, f32x2 b) {
  f32x2 d; asm("v_pk_add_f32 %0, %1, %2" : "=v"(d) : "v"(a), "v"(b)); return d;
}
__device__ __forceinline__ f32x2 pk_mul(f32x2 a, f32x2 b) {
  f32x2 d; asm("v_pk_mul_f32 %0, %1, %2" : "=v"(d) : "v"(a), "v"(b)); return d;
}
__device__ __forceinline__ f32x2 pk_fma(f32x2 a, f32x2 b, f32x2 c) {
  f32x2 d; asm("v_pk_fma_f32 %0, %1, %2, %3" : "=v"(d) : "v"(a), "v"(b), "v"(c)); return d;
}
// d = a * bcast(b.lo) + c   (verified R7)
__device__ __forceinline__ f32x2 pk_fma_b0(f32x2 a, f32x2 b, f32x2 c) {
  f32x2 d;
  asm("v_pk_fma_f32 %0, %1, %2, %3 op_sel:[0,0,0] op_sel_hi:[1,0,1]"
      : "=v"(d) : "v"(a), "v"(b), "v"(c));
  return d;
}
// d = a * bcast(b.hi) + c   (verified R7)
__device__ __forceinline__ f32x2 pk_fma_b1(f32x2 a, f32x2 b, f32x2 c) {
  f32x2 d;
  asm("v_pk_fma_f32 %0, %1, %2, %3 op_sel:[0,1,0] op_sel_hi:[1,1,1]"
      : "=v"(d) : "v"(a), "v"(b), "v"(c));
  return d;
}
// d = a * bcast(b.lo)
__device__ __forceinline__ f32x2 pk_mul_b0(f32x2 a, f32x2 b) {
  f32x2 d;
  asm("v_pk_mul_f32 %0, %1, %2 op_sel:[0,0] op_sel_hi:[1,0]"
      : "=v"(d) : "v"(a), "v"(b));
  return d;
}

__device__ __forceinline__ void storeO(float* p, float v) { *p = v; }
__device__ __forceinline__ void storeO(hbf16* p, float v) { *p = __float2bfloat16(v); }

// ---------------- f32 -> bf16 convert ----------------
__global__ __launch_bounds__(256) void cvt_kernel(const float* __restrict__ in,
                                                  hbf16* __restrict__ out, int n) {
  int i = (blockIdx.x * 256 + threadIdx.x) * 4;
  if (i >= n) return;
  float4 v = *(const float4*)(in + i);
  out[i] = __float2bfloat16(v.x);
  out[i + 1] = __float2bfloat16(v.y);
  out[i + 2] = __float2bfloat16(v.z);
  out[i + 3] = __float2bfloat16(v.w);
}

// ---------------- W[K][N] f32 -> Wt[N][K] bf16 (32x32 tiles) ----------------
__global__ __launch_bounds__(256) void transpose_cvt_kernel(
    const float* __restrict__ W, hbf16* __restrict__ Wt, int K, int N) {
  __shared__ hbf16 tile[32][33];
  const int n0 = blockIdx.x * 32, k0 = blockIdx.y * 32;
  const int tx = threadIdx.x, ty = threadIdx.y;  // 32 x 8
#pragma unroll
  for (int i = 0; i < 4; ++i)
    tile[ty * 4 + i][tx] = __float2bfloat16(W[(size_t)(k0 + ty * 4 + i) * N + n0 + tx]);
  __syncthreads();
#pragma unroll
  for (int i = 0; i < 4; ++i)
    Wt[(size_t)(n0 + ty * 4 + i) * K + k0 + tx] = tile[tx][ty * 4 + i];
}

// ---- MFMA GEMM: C[M,N] = A[M,K](bf16) @ Bt[N,K](bf16)^T + dual bias (split at NS) ----
template <typename OutT>
__global__ __launch_bounds__(256) void mfma_gemm_kernel(
    const hbf16* __restrict__ A, const hbf16* __restrict__ Bt,
    const float* __restrict__ bias0, const float* __restrict__ bias1, int NS,
    OutT* __restrict__ C, int M, int N, int K) {
  const int tid = threadIdx.x, lane = tid & 63, w = tid >> 6;
  const int wr = w >> 1, wc = w & 1;
  const int rowb = blockIdx.y * 128 + wr * 64;
  const int colb = blockIdx.x * 128 + wc * 64;
  const int lr = lane & 15, lk = (lane >> 4) * 8;

  f32x4 acc[4][4];
#pragma unroll
  for (int mi = 0; mi < 4; ++mi)
#pragma unroll
    for (int ni = 0; ni < 4; ++ni) acc[mi][ni] = {0.f, 0.f, 0.f, 0.f};

  const short* Ap = (const short*)A;
  const short* Bp = (const short*)Bt;

  int ar[4];
#pragma unroll
  for (int mi = 0; mi < 4; ++mi) {
    int r = rowb + mi * 16 + lr;
    ar[mi] = (r < M) ? r : (M - 1);  // clamp: garbage rows never stored
  }

#pragma unroll 2
  for (int k0 = 0; k0 < K; k0 += 32) {
    bf16x8 af[4], bfr[4];
#pragma unroll
    for (int mi = 0; mi < 4; ++mi)
      af[mi] = *(const bf16x8*)(Ap + (size_t)ar[mi] * K + k0 + lk);
#pragma unroll
    for (int ni = 0; ni < 4; ++ni)
      bfr[ni] = *(const bf16x8*)(Bp + (size_t)(colb + ni * 16 + lr) * K + k0 + lk);
#pragma unroll
    for (int mi = 0; mi < 4; ++mi)
#pragma unroll
      for (int ni = 0; ni < 4; ++ni)
        acc[mi][ni] = __builtin_amdgcn_mfma_f32_16x16x32_bf16(af[mi], bfr[ni],
                                                              acc[mi][ni], 0, 0, 0);
  }

  float bv[4];
#pragma unroll
  for (int ni = 0; ni < 4; ++ni) {
    int gc = colb + ni * 16 + lr;
    bv[ni] = (gc < NS) ? bias0[gc] : bias1[gc - NS];
  }
#pragma unroll
  for (int mi = 0; mi < 4; ++mi) {
    const int row0 = rowb + mi * 16 + (lane >> 4) * 4;
#pragma unroll
    for (int r = 0; r < 4; ++r) {
      const int row = row0 + r;
      if (row >= M) continue;
#pragma unroll
      for (int ni = 0; ni < 4; ++ni)
        storeO(&C[(size_t)row * N + colb + ni * 16 + lr], acc[mi][ni][r] + bv[ni]);
    }
  }
}

// ---------------- CSR build (parallel 2-level scan) ----------------
__global__ __launch_bounds__(256) void hist_kernel(const int* __restrict__ dst,
                                                   int* __restrict__ P, int E) {
  int i = blockIdx.x * 256 + threadIdx.x;
  if (i < E) atomicAdd(&P[dst[i]], 1);
}

__global__ __launch_bounds__(256) void scan_sum_kernel(const int* __restrict__ P,
                                                       int* __restrict__ part, int n) {
  __shared__ int s[256];
  int i = blockIdx.x * 256 + threadIdx.x;
  s[threadIdx.x] = (i < n) ? P[i] : 0;
  __syncthreads();
#pragma unroll
  for (int off = 128; off; off >>= 1) {
    if (threadIdx.x < off) s[threadIdx.x] += s[threadIdx.x + off];
    __syncthreads();
  }
  if (threadIdx.x == 0) part[blockIdx.x] = s[0];
}

__global__ __launch_bounds__(256) void scan_part_kernel(int* __restrict__ part, int nb) {
  __shared__ int s[256];
  int v = (threadIdx.x < nb) ? part[threadIdx.x] : 0;
  s[threadIdx.x] = v;
  __syncthreads();
#pragma unroll
  for (int off = 1; off < 256; off <<= 1) {
    int t = (threadIdx.x >= off) ? s[threadIdx.x - off] : 0;
    __syncthreads();
    s[threadIdx.x] += t;
    __syncthreads();
  }
  if (threadIdx.x < nb) part[threadIdx.x] = s[threadIdx.x] - v;
}

__global__ __launch_bounds__(256) void scan_apply_kernel(int* __restrict__ P,
                                                         const int* __restrict__ part,
                                                         int n) {
  __shared__ int s[256];
  int i = blockIdx.x * 256 + threadIdx.x;
  int v = (i < n) ? P[i] : 0;
  s[threadIdx.x] = v;
  __syncthreads();
#pragma unroll
  for (int off = 1; off < 256; off <<= 1) {
    int t = (threadIdx.x >= off) ? s[threadIdx.x - off] : 0;
    __syncthreads();
    s[threadIdx.x] += t;
    __syncthreads();
  }
  if (i < n) P[i] = s[threadIdx.x] - v + part[blockIdx.x];
}

__global__ __launch_bounds__(256) void scatter_kernel(const int* __restrict__ dst,
                                                      int* __restrict__ P,
                                                      int* __restrict__ perm, int E) {
  int i = blockIdx.x * 256 + threadIdx.x;
  if (i < E) {
    int pos = atomicAdd(&P[dst[i]], 1);
    perm[pos] = i;
  }
}

// ---------------- fused GATv2 layer 1: ONE WAVE PER NODE (PAIRS=2, CPT=4) --------
template <int PAIRS, bool SILU>
__global__ __launch_bounds__(256) void fused_gat_wpn_kernel(
    const hbf16* __restrict__ xl, const hbf16* __restrict__ xr, int ldx,
    const float* __restrict__ ea, const float* __restrict__ We,
    const float* __restrict__ att, const int* __restrict__ src,
    const int* __restrict__ Pend, const int* __restrict__ perm,
    const float* __restrict__ bias, hbf16* __restrict__ out, int NN) {
  constexpr int CPT = 2 * PAIRS;
  constexpr int HC = 64 * CPT;
  const int lane = threadIdx.x & 63;
  const int w = threadIdx.x >> 6;
  const int d = blockIdx.x * 4 + w;
  __shared__ float4 s_ef[4][64];
  if (d >= NN) return;
  const int beg = (d == 0) ? 0 : Pend[d - 1];
  const int end = Pend[d];
  const int j0 = lane * CPT;

  f32x2 w0p[PAIRS], w1p[PAIRS], w2p[PAIRS], atp[PAIRS], xrp[PAIRS];
  {
    u32 xraw[PAIRS];
    *(uint2*)xraw = *(const uint2*)((const u32*)((const short*)xr + (size_t)d * ldx + j0));
#pragma unroll
    for (int k = 0; k < PAIRS; ++k) {
      xrp[k] = bf2pair(xraw[k]);
      w0p[k] = *(const f32x2*)(We + j0 + 2 * k);
      w1p[k] = *(const f32x2*)(We + HC + j0 + 2 * k);
      w2p[k] = *(const f32x2*)(We + 2 * HC + j0 + 2 * k);
      atp[k] = *(const f32x2*)(att + j0 + 2 * k);
    }
  }
  f32x2 p02;
  p02[0] = 0.2f; p02[1] = 0.2f;

  float m_run = -INFINITY, ssum = 0.f;
  f32x2 accp[PAIRS];
#pragma unroll
  for (int k = 0; k < PAIRS; ++k) accp[k] = {0.f, 0.f};

  const short* xls = (const short*)xl;

  for (int base = beg; base < end; base += 64) {
    const int nb = min(64, end - base);
    int sv = 0;
    if (lane < nb) {
      int eid = perm[base + lane];
      sv = src[eid];
      float a0 = ea[3 * (size_t)eid], a1 = ea[3 * (size_t)eid + 1],
            a2 = ea[3 * (size_t)eid + 2];
      s_ef[w][lane] = make_float4(a0, a1, a2, a2);
    }
    asm volatile("s_waitcnt lgkmcnt(0)" ::: "memory");

    u32 rawA[PAIRS], rawB[PAIRS];
    {
      int s0 = __builtin_amdgcn_readlane(sv, 0);
      *(uint2*)rawA = *(const uint2*)((const u32*)(xls + (size_t)s0 * ldx + j0));
    }
    if (nb > 1) {
      int s1 = __builtin_amdgcn_readlane(sv, 1);
      *(uint2*)rawB = *(const uint2*)((const u32*)(xls + (size_t)s1 * ldx + j0));
    }

    for (int i = 0; i < nb; i += 2) {
      const bool hasB = (i + 1) < nb;
      const float4 efA = s_ef[w][i];
      f32x2 eA01, eA22;
      eA01[0] = efA.x; eA01[1] = efA.y; eA22[0] = efA.z; eA22[1] = efA.w;
      f32x2 pa2 = {0.f, 0.f};
#pragma unroll
      for (int k = 0; k < PAIRS; ++k) {
        f32x2 xv = bf2pair(rawA[k]);
        f32x2 u = pk_add(xv, xrp[k]);
        u = pk_fma_b0(w0p[k], eA01, u);
        u = pk_fma_b1(w1p[k], eA01, u);
        u = pk_fma(w2p[k], eA22, u);
        f32x2 t = pk_mul(u, p02);
        f32x2 l;
        l[0] = fmaxf(u[0], t[0]);
        l[1] = fmaxf(u[1], t[1]);
        pa2 = pk_fma(l, atp[k], pa2);
      }
      float pA = pa2[0] + pa2[1];
      float pB = 0.f;
      if (hasB) {
        const float4 efB = s_ef[w][i + 1];
        f32x2 eB01, eB22;
        eB01[0] = efB.x; eB01[1] = efB.y; eB22[0] = efB.z; eB22[1] = efB.w;
        f32x2 pb2 = {0.f, 0.f};
#pragma unroll
        for (int k = 0; k < PAIRS; ++k) {
          f32x2 xv = bf2pair(rawB[k]);
          f32x2 u = pk_add(xv, xrp[k]);
          u = pk_fma_b0(w0p[k], eB01, u);
          u = pk_fma_b1(w1p[k], eB01, u);
          u = pk_fma(w2p[k], eB22, u);
          f32x2 t = pk_mul(u, p02);
          f32x2 l;
          l[0] = fmaxf(u[0], t[0]);
          l[1] = fmaxf(u[1], t[1]);
          pb2 = pk_fma(l, atp[k], pb2);
        }
        pB = pb2[0] + pb2[1];
      }
      pA += __shfl_xor(pA, 1);
      if (hasB) pB += __shfl_xor(pB, 1);
      pA += __shfl_xor(pA, 2);
      if (hasB) pB += __shfl_xor(pB, 2);
      pA += __shfl_xor(pA, 4);
      if (hasB) pB += __shfl_xor(pB, 4);
      pA += __shfl_xor(pA, 8);
      if (hasB) pB += __shfl_xor(pB, 8);

      if (__any(pA > m_run)) {
        const float nm = fmaxf(m_run, pA);
        const float sc = __expf(m_run - nm);
        ssum *= sc;
        f32x2 scp; scp[0] = sc; scp[1] = sc;
#pragma unroll
        for (int k = 0; k < PAIRS; ++k) accp[k] = pk_mul_b0(accp[k], scp);
        m_run = nm;
      }
      {
        const float pe = __expf(pA - m_run);
        ssum += pe;
        f32x2 pep; pep[0] = pe; pep[1] = pe;
#pragma unroll
        for (int k = 0; k < PAIRS; ++k)
          accp[k] = pk_fma_b0(bf2pair(rawA[k]), pep, accp[k]);
      }
      if (hasB) {
        if (__any(pB > m_run)) {
          const float nm = fmaxf(m_run, pB);
          const float sc = __expf(m_run - nm);
          ssum *= sc;
          f32x2 scp; scp[0] = sc; scp[1] = sc;
#pragma unroll
          for (int k = 0; k < PAIRS; ++k) accp[k] = pk_mul_b0(accp[k], scp);
          m_run = nm;
        }
        const float pe = __expf(pB - m_run);
        ssum += pe;
        f32x2 pep; pep[0] = pe; pep[1] = pe;
#pragma unroll
        for (int k = 0; k < PAIRS; ++k)
          accp[k] = pk_fma_b0(bf2pair(rawB[k]), pep, accp[k]);
      }
      if (i + 2 < nb) {
        int s = __builtin_amdgcn_readlane(sv, i + 2);
        *(uint2*)rawA = *(const uint2*)((const u32*)(xls + (size_t)s * ldx + j0));
      }
      if (i + 3 < nb) {
        int s = __builtin_amdgcn_readlane(sv, i + 3);
        *(uint2*)rawB = *(const uint2*)((const u32*)(xls + (size_t)s * ldx + j0));
      }
    }
  }

  const float inv = (end > beg) ? 1.f / ssum : 0.f;
  u32 ow[PAIRS];
#pragma unroll
  for (int k = 0; k < PAIRS; ++k) {
    float o0 = accp[k][0] * inv + bias[j0 + 2 * k];
    float o1 = accp[k][1] * inv + bias[j0 + 2 * k + 1];
    if (SILU) {
      o0 = o0 / (1.f + __expf(-o0));
      o1 = o1 / (1.f + __expf(-o1));
    }
    hbf16 h0 = __float2bfloat16(o0), h1 = __float2bfloat16(o1);
    ow[k] = (u32)(*(unsigned short*)&h0) | ((u32)(*(unsigned short*)&h1) << 16);
  }
  *(uint2*)((u32*)((short*)out + (size_t)d * HC + j0)) = *(const uint2*)ow;
}

// ---------------- fused GATv2 layer 2: TWO WAVES PER NODE (PAIRS=4, CPT=8) --------
// Wave w owns heads {2w, 2w+1}; head group = 32 lanes; lane covers 8 channels.
// 2 nodes per 256-thread block; waves independent (no __syncthreads).
template <bool WLOG>
__global__ __launch_bounds__(256) void fused_gat_w2_kernel(
    const hbf16* __restrict__ xl, const hbf16* __restrict__ xr, int ldx,
    const float* __restrict__ ea, const float* __restrict__ We,
    const float* __restrict__ att, const int* __restrict__ src,
    const int* __restrict__ Pend, const int* __restrict__ perm,
    const float* __restrict__ bias, hbf16* __restrict__ out,
    float* __restrict__ logit_out, float* __restrict__ mfin,
    float* __restrict__ sfin, int NN) {
  constexpr int PAIRS = 4, HC = 1024;
  const int lane = threadIdx.x & 63;
  const int wv = threadIdx.x >> 6;       // 0..3 wave in block
  const int w = wv & 1;                  // wave within node
  const int d = blockIdx.x * 2 + (wv >> 1);
  __shared__ float4 s_ef[4][64];
  if (d >= NN) return;
  const int beg = (d == 0) ? 0 : Pend[d - 1];
  const int end = Pend[d];
  const int hgrp = (w << 1) | (lane >> 5);       // head 0..3
  const int j0 = hgrp * 256 + (lane & 31) * 8;   // element offset in row

  f32x2 w0p[PAIRS], w1p[PAIRS], w2p[PAIRS], atp[PAIRS], xrp[PAIRS];
  {
    u32 xraw[PAIRS];
    *(uint4*)xraw = *(const uint4*)((const u32*)((const short*)xr + (size_t)d * ldx + j0));
#pragma unroll
    for (int k = 0; k < PAIRS; ++k) {
      xrp[k] = bf2pair(xraw[k]);
      w0p[k] = *(const f32x2*)(We + j0 + 2 * k);
      w1p[k] = *(const f32x2*)(We + HC + j0 + 2 * k);
      w2p[k] = *(const f32x2*)(We + 2 * HC + j0 + 2 * k);
      atp[k] = *(const f32x2*)(att + j0 + 2 * k);
    }
  }
  f32x2 p02;
  p02[0] = 0.2f; p02[1] = 0.2f;

  float m_run = -INFINITY, ssum = 0.f;
  f32x2 accp[PAIRS];
#pragma unroll
  for (int k = 0; k < PAIRS; ++k) accp[k] = {0.f, 0.f};

  const short* xls = (const short*)xl;

  for (int base = beg; base < end; base += 64) {
    const int nb = min(64, end - base);
    int eidv = 0, sv = 0;
    if (lane < nb) {
      eidv = perm[base + lane];
      sv = src[eidv];
      float a0 = ea[3 * (size_t)eidv], a1 = ea[3 * (size_t)eidv + 1],
            a2 = ea[3 * (size_t)eidv + 2];
      s_ef[wv][lane] = make_float4(a0, a1, a2, a2);
    }
    asm volatile("s_waitcnt lgkmcnt(0)" ::: "memory");

    u32 rawA[PAIRS], rawB[PAIRS];
    {
      int s0 = __builtin_amdgcn_readlane(sv, 0);
      *(uint4*)rawA = *(const uint4*)((const u32*)(xls + (size_t)s0 * ldx + j0));
    }
    if (nb > 1) {
      int s1 = __builtin_amdgcn_readlane(sv, 1);
      *(uint4*)rawB = *(const uint4*)((const u32*)(xls + (size_t)s1 * ldx + j0));
    }

    for (int i = 0; i < nb; i += 2) {
      const bool hasB = (i + 1) < nb;
      // dot A
      const float4 efA = s_ef[wv][i];
      f32x2 eA01, eA22;
      eA01[0] = efA.x; eA01[1] = efA.y; eA22[0] = efA.z; eA22[1] = efA.w;
      f32x2 pa2 = {0.f, 0.f};
#pragma unroll
      for (int k = 0; k < PAIRS; ++k) {
        f32x2 xv = bf2pair(rawA[k]);
        f32x2 u = pk_add(xv, xrp[k]);
        u = pk_fma_b0(w0p[k], eA01, u);
        u = pk_fma_b1(w1p[k], eA01, u);
        u = pk_fma(w2p[k], eA22, u);
        f32x2 t = pk_mul(u, p02);
        f32x2 l;
        l[0] = fmaxf(u[0], t[0]);
        l[1] = fmaxf(u[1], t[1]);
        pa2 = pk_fma(l, atp[k], pa2);
      }
      float pA = pa2[0] + pa2[1];
      // dot B
      float pB = 0.f;
      if (hasB) {
        const float4 efB = s_ef[wv][i + 1];
        f32x2 eB01, eB22;
        eB01[0] = efB.x; eB01[1] = efB.y; eB22[0] = efB.z; eB22[1] = efB.w;
        f32x2 pb2 = {0.f, 0.f};
#pragma unroll
        for (int k = 0; k < PAIRS; ++k) {
          f32x2 xv = bf2pair(rawB[k]);
          f32x2 u = pk_add(xv, xrp[k]);
          u = pk_fma_b0(w0p[k], eB01, u);
          u = pk_fma_b1(w1p[k], eB01, u);
          u = pk_fma(w2p[k], eB22, u);
          f32x2 t = pk_mul(u, p02);
          f32x2 l;
          l[0] = fmaxf(u[0], t[0]);
          l[1] = fmaxf(u[1], t[1]);
          pb2 = pk_fma(l, atp[k], pb2);
        }
        pB = pb2[0] + pb2[1];
      }
      // 32-lane group reduces (interleaved)
      pA += __shfl_xor(pA, 1);
      if (hasB) pB += __shfl_xor(pB, 1);
      pA += __shfl_xor(pA, 2);
      if (hasB) pB += __shfl_xor(pB, 2);
      pA += __shfl_xor(pA, 4);
      if (hasB) pB += __shfl_xor(pB, 4);
      pA += __shfl_xor(pA, 8);
      if (hasB) pB += __shfl_xor(pB, 8);
      pA += __shfl_xor(pA, 16);
      if (hasB) pB += __shfl_xor(pB, 16);

      if (WLOG && (lane & 31) == 0) {
        const int eidA = __builtin_amdgcn_readlane(eidv, i);
        logit_out[(size_t)eidA * 4 + hgrp] = pA;
      }
      if (__any(pA > m_run)) {
        const float nm = fmaxf(m_run, pA);
        const float sc = __expf(m_run - nm);
        ssum *= sc;
        f32x2 scp; scp[0] = sc; scp[1] = sc;
#pragma unroll
        for (int k = 0; k < PAIRS; ++k) accp[k] = pk_mul_b0(accp[k], scp);
        m_run = nm;
      }
      {
        const float pe = __expf(pA - m_run);
        ssum += pe;
        f32x2 pep; pep[0] = pe; pep[1] = pe;
#pragma unroll
        for (int k = 0; k < PAIRS; ++k)
          accp[k] = pk_fma_b0(bf2pair(rawA[k]), pep, accp[k]);
      }
      if (hasB) {
        if (WLOG && (lane & 31) == 0) {
          const int eidB = __builtin_amdgcn_readlane(eidv, i + 1);
          logit_out[(size_t)eidB * 4 + hgrp] = pB;
        }
        if (__any(pB > m_run)) {
          const float nm = fmaxf(m_run, pB);
          const float sc = __expf(m_run - nm);
          ssum *= sc;
          f32x2 scp; scp[0] = sc; scp[1] = sc;
#pragma unroll
          for (int k = 0; k < PAIRS; ++k) accp[k] = pk_mul_b0(accp[k], scp);
          m_run = nm;
        }
        const float pe = __expf(pB - m_run);
        ssum += pe;
        f32x2 pep; pep[0] = pe; pep[1] = pe;
#pragma unroll
        for (int k = 0; k < PAIRS; ++k)
          accp[k] = pk_fma_b0(bf2pair(rawB[k]), pep, accp[k]);
      }
      if (i + 2 < nb) {
        int s = __builtin_amdgcn_readlane(sv, i + 2);
        *(uint4*)rawA = *(const uint4*)((const u32*)(xls + (size_t)s * ldx + j0));
      }
      if (i + 3 < nb) {
        int s = __builtin_amdgcn_readlane(sv, i + 3);
        *(uint4*)rawB = *(const uint4*)((const u32*)(xls + (size_t)s * ldx + j0));
      }
    }
  }

  const float inv = (end > beg) ? 1.f / ssum : 0.f;
  u32 ow[PAIRS];
#pragma unroll
  for (int k = 0; k < PAIRS; ++k) {
    float o0 = accp[k][0] * inv + bias[j0 + 2 * k];
    float o1 = accp[k][1] * inv + bias[j0 + 2 * k + 1];
    hbf16 h0 = __float2bfloat16(o0), h1 = __float2bfloat16(o1);
    ow[k] = (u32)(*(unsigned short*)&h0) | ((u32)(*(unsigned short*)&h1) << 16);
  }
  *(uint4*)((u32*)((short*)out + (size_t)d * HC + j0)) = *(const uint4*)ow;
  if (WLOG && (lane & 31) == 0) {
    mfin[d * 4 + hgrp] = m_run;
    sfin[d * 4 + hgrp] = ssum;
  }
}

// in-place: logit -> alpha = exp(l - mfin[dst]) / sfin[dst]
__global__ __launch_bounds__(256) void alpha_kernel(
    float* __restrict__ la, const float* __restrict__ mfin,
    const float* __restrict__ sfin, const int* __restrict__ dst, int n4) {
  int i = blockIdx.x * 256 + threadIdx.x;
  if (i >= n4) return;
  int e = i >> 2, h = i & 3;
  int d = dst[e];
  la[i] = __expf(la[i] - mfin[d * 4 + h]) / sfin[d * 4 + h];
}

extern "C" void kernel_launch(void* const* d_in, const int* in_sizes, int n_in,
                              void* d_out, int out_size, void* d_ws, size_t ws_size,
                              hipStream_t stream) {
  const float* x    = (const float*)d_in[0];
  const int*   ei   = (const int*)d_in[1];
  const float* ea   = (const float*)d_in[2];
  const float* W1l  = (const float*)d_in[3];
  const float* b1l  = (const float*)d_in[4];
  const float* W1r  = (const float*)d_in[5];
  const float* b1r  = (const float*)d_in[6];
  const float* W1e  = (const float*)d_in[7];
  const float* att1 = (const float*)d_in[8];
  const float* bias1= (const float*)d_in[9];
  const float* W2l  = (const float*)d_in[10];
  const float* b2l  = (const float*)d_in[11];
  const float* W2r  = (const float*)d_in[12];
  const float* b2r  = (const float*)d_in[13];
  const float* W2e  = (const float*)d_in[14];
  const float* att2 = (const float*)d_in[15];
  const float* bias2= (const float*)d_in[16];
  const float* Wp   = (const float*)d_in[17];
  const float* bp   = (const float*)d_in[18];

  const int N = in_sizes[0] / 256;  // 10000
  const int E = in_sizes[1] / 2;    // 320000
  const int* srcI = ei;
  const int* dstI = ei + E;

  // workspace (~68 MB)
  float* wsf = (float*)d_ws;
  float* mfin = wsf;                              // 4N
  float* sfin = mfin + (size_t)4 * N;             // 4N
  int*   P    = (int*)(sfin + (size_t)4 * N);     // N
  int*   part = P + N;                            // 256 (scan partials)
  int*   perm = part + 256;                       // E
  hbf16* xb   = (hbf16*)(perm + E);               // N*256 (x bf16)
  hbf16* xlr  = xb + (size_t)N * 256;             // N*2048 (merged xl|xr; L1 uses N*512)
  hbf16* ho   = xlr + (size_t)N * 2048;           // N*1024 (h first N*256, then out2)
  hbf16* W1lt = ho + (size_t)N * 1024;            // 256*256  (W1rt adjacent)
  hbf16* W1rt = W1lt + 256 * 256;
  hbf16* W2lt = W1rt + 256 * 256;                 // 1024*256 (W2rt adjacent)
  hbf16* W2rt = W2lt + 1024 * 256;
  hbf16* Wpt  = W2rt + 1024 * 256;                // 256*1024

  float* yout = (float*)d_out;                    // N*256
  float* alpha_out = yout + (size_t)N * 256;      // E*4

  const int eB = (E + 255) / 256;
  const int sB = (N + 255) / 256;                 // 40 scan blocks
  const dim3 tb(32, 8);

  // CSR build: hist -> 2-level scan -> scatter
  hipMemsetAsync(P, 0, (size_t)N * 4, stream);
  hist_kernel<<<eB, 256, 0, stream>>>(dstI, P, E);
  scan_sum_kernel<<<sB, 256, 0, stream>>>(P, part, N);
  scan_part_kernel<<<1, 256, 0, stream>>>(part, sB);
  scan_apply_kernel<<<sB, 256, 0, stream>>>(P, part, N);
  scatter_kernel<<<eB, 256, 0, stream>>>(dstI, P, perm, E);

  // bf16 conversions
  cvt_kernel<<<(N * 256 / 4 + 255) / 256, 256, 0, stream>>>(x, xb, N * 256);
  transpose_cvt_kernel<<<dim3(256 / 32, 256 / 32), tb, 0, stream>>>(W1l, W1lt, 256, 256);
  transpose_cvt_kernel<<<dim3(256 / 32, 256 / 32), tb, 0, stream>>>(W1r, W1rt, 256, 256);
  transpose_cvt_kernel<<<dim3(1024 / 32, 256 / 32), tb, 0, stream>>>(W2l, W2lt, 256, 1024);
  transpose_cvt_kernel<<<dim3(1024 / 32, 256 / 32), tb, 0, stream>>>(W2r, W2rt, 256, 1024);
  transpose_cvt_kernel<<<dim3(256 / 32, 1024 / 32), tb, 0, stream>>>(Wp, Wpt, 1024, 256);

  // ---------------- layer 1 (HC=256), merged l|r GEMM N=512 ----------------
  mfma_gemm_kernel<hbf16><<<dim3(512 / 128, (N + 127) / 128), 256, 0, stream>>>(
      xb, W1lt, b1l, b1r, 256, xlr, N, 512, 256);
  fused_gat_wpn_kernel<2, true><<<(N + 3) / 4, 256, 0, stream>>>(
      xlr, xlr + 256, 512, ea, W1e, att1, srcI, P, perm, bias1, ho /*h*/, N);

  // ---------------- layer 2 (HC=1024), merged l|r GEMM N=2048 ----------------
  mfma_gemm_kernel<hbf16><<<dim3(2048 / 128, (N + 127) / 128), 256, 0, stream>>>(
      ho, W2lt, b2l, b2r, 1024, xlr, N, 2048, 256);
  fused_gat_w2_kernel<true><<<(N + 1) / 2, 256, 0, stream>>>(
      xlr, xlr + 1024, 2048, ea, W2e, att2, srcI, P, perm, bias2, ho /*out2*/,
      alpha_out, mfin, sfin, N);
  alpha_kernel<<<(E * 4 + 255) / 256, 256, 0, stream>>>(alpha_out, mfin, sfin, dstI, E * 4);

  // projector
  mfma_gemm_kernel<float><<<dim3(256 / 128, (N + 127) / 128), 256, 0, stream>>>(
      ho, Wpt, bp, bp, 256, yout, N, 256, 1024);
}

// Round 11
// 341.092 us; speedup vs baseline: 1.8246x; 1.1279x over previous
//
#include <hip/hip_runtime.h>
#include <hip/hip_bf16.h>

typedef __hip_bfloat16 hbf16;
typedef unsigned int u32;
typedef __attribute__((ext_vector_type(2))) float f32x2;
typedef __attribute__((ext_vector_type(8))) short bf16x8;
typedef __attribute__((ext_vector_type(4))) float f32x4;

__device__ __forceinline__ f32x2 bf2pair(u32 v) {
  f32x2 o;
  o[0] = __uint_as_float(v << 16);
  o[1] = __uint_as_float(v & 0xffff0000u);
  return o;
}

// ---- packed f32 VOP3P helpers ----
__device__ __forceinline__ f32x2 pk_add(f32x2 a, f32x2 b) {
  f32x2 d; asm("v_pk_add_f32 %0, %1, %2" : "=v"(d) : "v"(a), "v"(b)); return d;
}
__device__ __forceinline__ f32x2 pk_mul(f32x2 a, f32x2 b) {
  f32x2 d; asm("v_pk_mul_f32 %0, %1, %2" : "=v"(d) : "v"(a), "v"(b)); return d;
}
__device__ __forceinline__ f32x2 pk_fma(f32x2 a, f32x2 b, f32x2 c) {
  f32x2 d; asm("v_pk_fma_f32 %0, %1, %2, %3" : "=v"(d) : "v"(a), "v"(b), "v"(c)); return d;
}
__device__ __forceinline__ f32x2 pk_fma_b0(f32x2 a, f32x2 b, f32x2 c) {
  f32x2 d;
  asm("v_pk_fma_f32 %0, %1, %2, %3 op_sel:[0,0,0] op_sel_hi:[1,0,1]"
      : "=v"(d) : "v"(a), "v"(b), "v"(c));
  return d;
}
__device__ __forceinline__ f32x2 pk_fma_b1(f32x2 a, f32x2 b, f32x2 c) {
  f32x2 d;
  asm("v_pk_fma_f32 %0, %1, %2, %3 op_sel:[0,1,0] op_sel_hi:[1,1,1]"
      : "=v"(d) : "v"(a), "v"(b), "v"(c));
  return d;
}
__device__ __forceinline__ f32x2 pk_mul_b0(f32x2 a, f32x2 b) {
  f32x2 d;
  asm("v_pk_mul_f32 %0, %1, %2 op_sel:[0,0] op_sel_hi:[1,0]"
      : "=v"(d) : "v"(a), "v"(b));
  return d;
}

// ---- DPP butterfly add steps (pure VALU, no DS) ----
// masks {1,2,7,15}: quad_perm xor1 (0xB1), quad_perm xor2 (0x4E),
// row_half_mirror = xor7 (0x141), row_mirror = xor15 (0x140)
template <int CTRL>
__device__ __forceinline__ float dpp_add(float p) {
  int t = __builtin_amdgcn_update_dpp(0, __float_as_int(p), CTRL, 0xF, 0xF, true);
  return p + __int_as_float(t);
}
// xor16 within 32-lane group via ds_swizzle bit-mode (no addr calc)
__device__ __forceinline__ float swz_add16(float p) {
  int t = __builtin_amdgcn_ds_swizzle(__float_as_int(p), 0x401F);
  return p + __int_as_float(t);
}

__device__ __forceinline__ void storeO(float* p, float v) { *p = v; }
__device__ __forceinline__ void storeO(hbf16* p, float v) { *p = __float2bfloat16(v); }

// ---------------- f32 -> bf16 convert ----------------
__global__ __launch_bounds__(256) void cvt_kernel(const float* __restrict__ in,
                                                  hbf16* __restrict__ out, int n) {
  int i = (blockIdx.x * 256 + threadIdx.x) * 4;
  if (i >= n) return;
  float4 v = *(const float4*)(in + i);
  out[i] = __float2bfloat16(v.x);
  out[i + 1] = __float2bfloat16(v.y);
  out[i + 2] = __float2bfloat16(v.z);
  out[i + 3] = __float2bfloat16(v.w);
}

// ---------------- W[K][N] f32 -> Wt[N][K] bf16 (32x32 tiles) ----------------
__global__ __launch_bounds__(256) void transpose_cvt_kernel(
    const float* __restrict__ W, hbf16* __restrict__ Wt, int K, int N) {
  __shared__ hbf16 tile[32][33];
  const int n0 = blockIdx.x * 32, k0 = blockIdx.y * 32;
  const int tx = threadIdx.x, ty = threadIdx.y;  // 32 x 8
#pragma unroll
  for (int i = 0; i < 4; ++i)
    tile[ty * 4 + i][tx] = __float2bfloat16(W[(size_t)(k0 + ty * 4 + i) * N + n0 + tx]);
  __syncthreads();
#pragma unroll
  for (int i = 0; i < 4; ++i)
    Wt[(size_t)(n0 + ty * 4 + i) * K + k0 + tx] = tile[tx][ty * 4 + i];
}

// ---- MFMA GEMM: C[M,N] = A[M,K](bf16) @ Bt[N,K](bf16)^T + dual bias (split at NS) ----
template <typename OutT>
__global__ __launch_bounds__(256) void mfma_gemm_kernel(
    const hbf16* __restrict__ A, const hbf16* __restrict__ Bt,
    const float* __restrict__ bias0, const float* __restrict__ bias1, int NS,
    OutT* __restrict__ C, int M, int N, int K) {
  const int tid = threadIdx.x, lane = tid & 63, w = tid >> 6;
  const int wr = w >> 1, wc = w & 1;
  const int rowb = blockIdx.y * 128 + wr * 64;
  const int colb = blockIdx.x * 128 + wc * 64;
  const int lr = lane & 15, lk = (lane >> 4) * 8;

  f32x4 acc[4][4];
#pragma unroll
  for (int mi = 0; mi < 4; ++mi)
#pragma unroll
    for (int ni = 0; ni < 4; ++ni) acc[mi][ni] = {0.f, 0.f, 0.f, 0.f};

  const short* Ap = (const short*)A;
  const short* Bp = (const short*)Bt;

  int ar[4];
#pragma unroll
  for (int mi = 0; mi < 4; ++mi) {
    int r = rowb + mi * 16 + lr;
    ar[mi] = (r < M) ? r : (M - 1);  // clamp: garbage rows never stored
  }

#pragma unroll 2
  for (int k0 = 0; k0 < K; k0 += 32) {
    bf16x8 af[4], bfr[4];
#pragma unroll
    for (int mi = 0; mi < 4; ++mi)
      af[mi] = *(const bf16x8*)(Ap + (size_t)ar[mi] * K + k0 + lk);
#pragma unroll
    for (int ni = 0; ni < 4; ++ni)
      bfr[ni] = *(const bf16x8*)(Bp + (size_t)(colb + ni * 16 + lr) * K + k0 + lk);
#pragma unroll
    for (int mi = 0; mi < 4; ++mi)
#pragma unroll
      for (int ni = 0; ni < 4; ++ni)
        acc[mi][ni] = __builtin_amdgcn_mfma_f32_16x16x32_bf16(af[mi], bfr[ni],
                                                              acc[mi][ni], 0, 0, 0);
  }

  float bv[4];
#pragma unroll
  for (int ni = 0; ni < 4; ++ni) {
    int gc = colb + ni * 16 + lr;
    bv[ni] = (gc < NS) ? bias0[gc] : bias1[gc - NS];
  }
#pragma unroll
  for (int mi = 0; mi < 4; ++mi) {
    const int row0 = rowb + mi * 16 + (lane >> 4) * 4;
#pragma unroll
    for (int r = 0; r < 4; ++r) {
      const int row = row0 + r;
      if (row >= M) continue;
#pragma unroll
      for (int ni = 0; ni < 4; ++ni)
        storeO(&C[(size_t)row * N + colb + ni * 16 + lr], acc[mi][ni][r] + bv[ni]);
    }
  }
}

// ---------------- CSR build (parallel 2-level scan) ----------------
__global__ __launch_bounds__(256) void hist_kernel(const int* __restrict__ dst,
                                                   int* __restrict__ P, int E) {
  int i = blockIdx.x * 256 + threadIdx.x;
  if (i < E) atomicAdd(&P[dst[i]], 1);
}

__global__ __launch_bounds__(256) void scan_sum_kernel(const int* __restrict__ P,
                                                       int* __restrict__ part, int n) {
  __shared__ int s[256];
  int i = blockIdx.x * 256 + threadIdx.x;
  s[threadIdx.x] = (i < n) ? P[i] : 0;
  __syncthreads();
#pragma unroll
  for (int off = 128; off; off >>= 1) {
    if (threadIdx.x < off) s[threadIdx.x] += s[threadIdx.x + off];
    __syncthreads();
  }
  if (threadIdx.x == 0) part[blockIdx.x] = s[0];
}

__global__ __launch_bounds__(256) void scan_part_kernel(int* __restrict__ part, int nb) {
  __shared__ int s[256];
  int v = (threadIdx.x < nb) ? part[threadIdx.x] : 0;
  s[threadIdx.x] = v;
  __syncthreads();
#pragma unroll
  for (int off = 1; off < 256; off <<= 1) {
    int t = (threadIdx.x >= off) ? s[threadIdx.x - off] : 0;
    __syncthreads();
    s[threadIdx.x] += t;
    __syncthreads();
  }
  if (threadIdx.x < nb) part[threadIdx.x] = s[threadIdx.x] - v;
}

__global__ __launch_bounds__(256) void scan_apply_kernel(int* __restrict__ P,
                                                         const int* __restrict__ part,
                                                         int n) {
  __shared__ int s[256];
  int i = blockIdx.x * 256 + threadIdx.x;
  int v = (i < n) ? P[i] : 0;
  s[threadIdx.x] = v;
  __syncthreads();
#pragma unroll
  for (int off = 1; off < 256; off <<= 1) {
    int t = (threadIdx.x >= off) ? s[threadIdx.x - off] : 0;
    __syncthreads();
    s[threadIdx.x] += t;
    __syncthreads();
  }
  if (i < n) P[i] = s[threadIdx.x] - v + part[blockIdx.x];
}

__global__ __launch_bounds__(256) void scatter_kernel(const int* __restrict__ dst,
                                                      int* __restrict__ P,
                                                      int* __restrict__ perm, int E) {
  int i = blockIdx.x * 256 + threadIdx.x;
  if (i < E) {
    int pos = atomicAdd(&P[dst[i]], 1);
    perm[pos] = i;
  }
}

// ---------------- fused GATv2 layer 1: ONE WAVE PER NODE (PAIRS=2, CPT=4) --------
// 16-lane head groups; reduce = 4 DPP steps, zero DS.
template <int PAIRS, bool SILU>
__global__ __launch_bounds__(256) void fused_gat_wpn_kernel(
    const hbf16* __restrict__ xl, const hbf16* __restrict__ xr, int ldx,
    const float* __restrict__ ea, const float* __restrict__ We,
    const float* __restrict__ att, const int* __restrict__ src,
    const int* __restrict__ Pend, const int* __restrict__ perm,
    const float* __restrict__ bias, hbf16* __restrict__ out, int NN) {
  constexpr int CPT = 2 * PAIRS;
  constexpr int HC = 64 * CPT;
  const int lane = threadIdx.x & 63;
  const int w = threadIdx.x >> 6;
  const int d = blockIdx.x * 4 + w;
  __shared__ float4 s_ef[4][64];
  if (d >= NN) return;
  const int beg = (d == 0) ? 0 : Pend[d - 1];
  const int end = Pend[d];
  const int j0 = lane * CPT;

  f32x2 w0p[PAIRS], w1p[PAIRS], w2p[PAIRS], atp[PAIRS], xrp[PAIRS];
  {
    u32 xraw[PAIRS];
    *(uint2*)xraw = *(const uint2*)((const u32*)((const short*)xr + (size_t)d * ldx + j0));
#pragma unroll
    for (int k = 0; k < PAIRS; ++k) {
      xrp[k] = bf2pair(xraw[k]);
      w0p[k] = *(const f32x2*)(We + j0 + 2 * k);
      w1p[k] = *(const f32x2*)(We + HC + j0 + 2 * k);
      w2p[k] = *(const f32x2*)(We + 2 * HC + j0 + 2 * k);
      atp[k] = *(const f32x2*)(att + j0 + 2 * k);
    }
  }
  f32x2 p02;
  p02[0] = 0.2f; p02[1] = 0.2f;

  float m_run = -INFINITY, ssum = 0.f;
  f32x2 accp[PAIRS];
#pragma unroll
  for (int k = 0; k < PAIRS; ++k) accp[k] = {0.f, 0.f};

  const short* xls = (const short*)xl;

  for (int base = beg; base < end; base += 64) {
    const int nb = min(64, end - base);
    int sv = 0;
    if (lane < nb) {
      int eid = perm[base + lane];
      sv = src[eid];
      float a0 = ea[3 * (size_t)eid], a1 = ea[3 * (size_t)eid + 1],
            a2 = ea[3 * (size_t)eid + 2];
      s_ef[w][lane] = make_float4(a0, a1, a2, a2);
    }
    asm volatile("s_waitcnt lgkmcnt(0)" ::: "memory");

    u32 rawA[PAIRS], rawB[PAIRS];
    {
      int s0 = __builtin_amdgcn_readlane(sv, 0);
      *(uint2*)rawA = *(const uint2*)((const u32*)(xls + (size_t)s0 * ldx + j0));
    }
    if (nb > 1) {
      int s1 = __builtin_amdgcn_readlane(sv, 1);
      *(uint2*)rawB = *(const uint2*)((const u32*)(xls + (size_t)s1 * ldx + j0));
    }

    for (int i = 0; i < nb; i += 2) {
      const bool hasB = (i + 1) < nb;
      const float4 efA = s_ef[w][i];
      f32x2 eA01, eA22;
      eA01[0] = efA.x; eA01[1] = efA.y; eA22[0] = efA.z; eA22[1] = efA.w;
      f32x2 xvA[PAIRS], xvB[PAIRS];
      f32x2 pa2 = {0.f, 0.f};
#pragma unroll
      for (int k = 0; k < PAIRS; ++k) {
        xvA[k] = bf2pair(rawA[k]);
        f32x2 u = pk_add(xvA[k], xrp[k]);
        u = pk_fma_b0(w0p[k], eA01, u);
        u = pk_fma_b1(w1p[k], eA01, u);
        u = pk_fma(w2p[k], eA22, u);
        f32x2 t = pk_mul(u, p02);
        f32x2 l;
        l[0] = fmaxf(u[0], t[0]);
        l[1] = fmaxf(u[1], t[1]);
        pa2 = pk_fma(l, atp[k], pa2);
      }
      float pA = pa2[0] + pa2[1];
      float pB = 0.f;
      {
        const float4 efB = s_ef[w][hasB ? (i + 1) : i];
        f32x2 eB01, eB22;
        eB01[0] = efB.x; eB01[1] = efB.y; eB22[0] = efB.z; eB22[1] = efB.w;
        f32x2 pb2 = {0.f, 0.f};
#pragma unroll
        for (int k = 0; k < PAIRS; ++k) {
          xvB[k] = bf2pair(rawB[k]);
          f32x2 u = pk_add(xvB[k], xrp[k]);
          u = pk_fma_b0(w0p[k], eB01, u);
          u = pk_fma_b1(w1p[k], eB01, u);
          u = pk_fma(w2p[k], eB22, u);
          f32x2 t = pk_mul(u, p02);
          f32x2 l;
          l[0] = fmaxf(u[0], t[0]);
          l[1] = fmaxf(u[1], t[1]);
          pb2 = pk_fma(l, atp[k], pb2);
        }
        pB = pb2[0] + pb2[1];
      }
      // prefetch edges i+2, i+3 (raw slots free: xv stashed)
      if (i + 2 < nb) {
        int s = __builtin_amdgcn_readlane(sv, i + 2);
        *(uint2*)rawA = *(const uint2*)((const u32*)(xls + (size_t)s * ldx + j0));
      }
      if (i + 3 < nb) {
        int s = __builtin_amdgcn_readlane(sv, i + 3);
        *(uint2*)rawB = *(const uint2*)((const u32*)(xls + (size_t)s * ldx + j0));
      }
      // 16-group butterfly: pure DPP
      pA = dpp_add<0xB1>(pA);  pB = dpp_add<0xB1>(pB);
      pA = dpp_add<0x4E>(pA);  pB = dpp_add<0x4E>(pB);
      pA = dpp_add<0x141>(pA); pB = dpp_add<0x141>(pB);
      pA = dpp_add<0x140>(pA); pB = dpp_add<0x140>(pB);

      if (__any(pA > m_run)) {
        const float nm = fmaxf(m_run, pA);
        const float sc = __expf(m_run - nm);
        ssum *= sc;
        f32x2 scp; scp[0] = sc; scp[1] = sc;
#pragma unroll
        for (int k = 0; k < PAIRS; ++k) accp[k] = pk_mul_b0(accp[k], scp);
        m_run = nm;
      }
      {
        const float pe = __expf(pA - m_run);
        ssum += pe;
        f32x2 pep; pep[0] = pe; pep[1] = pe;
#pragma unroll
        for (int k = 0; k < PAIRS; ++k) accp[k] = pk_fma_b0(xvA[k], pep, accp[k]);
      }
      if (hasB) {
        if (__any(pB > m_run)) {
          const float nm = fmaxf(m_run, pB);
          const float sc = __expf(m_run - nm);
          ssum *= sc;
          f32x2 scp; scp[0] = sc; scp[1] = sc;
#pragma unroll
          for (int k = 0; k < PAIRS; ++k) accp[k] = pk_mul_b0(accp[k], scp);
          m_run = nm;
        }
        const float pe = __expf(pB - m_run);
        ssum += pe;
        f32x2 pep; pep[0] = pe; pep[1] = pe;
#pragma unroll
        for (int k = 0; k < PAIRS; ++k) accp[k] = pk_fma_b0(xvB[k], pep, accp[k]);
      }
    }
  }

  const float inv = (end > beg) ? 1.f / ssum : 0.f;
  u32 ow[PAIRS];
#pragma unroll
  for (int k = 0; k < PAIRS; ++k) {
    float o0 = accp[k][0] * inv + bias[j0 + 2 * k];
    float o1 = accp[k][1] * inv + bias[j0 + 2 * k + 1];
    if (SILU) {
      o0 = o0 / (1.f + __expf(-o0));
      o1 = o1 / (1.f + __expf(-o1));
    }
    hbf16 h0 = __float2bfloat16(o0), h1 = __float2bfloat16(o1);
    ow[k] = (u32)(*(unsigned short*)&h0) | ((u32)(*(unsigned short*)&h1) << 16);
  }
  *(uint2*)((u32*)((short*)out + (size_t)d * HC + j0)) = *(const uint2*)ow;
}

// ---------------- fused GATv2 layer 2: TWO WAVES PER NODE (PAIRS=4, CPT=8) --------
// Wave w owns heads {2w,2w+1}; head group = 32 lanes; 4-edge-deep gather pipeline;
// reduce = 4 DPP + 1 ds_swizzle. 2 nodes / 256-thread block, waves independent.
template <bool WLOG>
__global__ __launch_bounds__(256) void fused_gat_w2_kernel(
    const hbf16* __restrict__ xl, const hbf16* __restrict__ xr, int ldx,
    const float* __restrict__ ea, const float* __restrict__ We,
    const float* __restrict__ att, const int* __restrict__ src,
    const int* __restrict__ Pend, const int* __restrict__ perm,
    const float* __restrict__ bias, hbf16* __restrict__ out,
    float* __restrict__ logit_out, float* __restrict__ mfin,
    float* __restrict__ sfin, int NN) {
  constexpr int PAIRS = 4, HC = 1024;
  const int lane = threadIdx.x & 63;
  const int wv = threadIdx.x >> 6;
  const int w = wv & 1;
  const int d = blockIdx.x * 2 + (wv >> 1);
  __shared__ float4 s_ef[4][64];
  if (d >= NN) return;
  const int beg = (d == 0) ? 0 : Pend[d - 1];
  const int end = Pend[d];
  const int hgrp = (w << 1) | (lane >> 5);
  const int j0 = hgrp * 256 + (lane & 31) * 8;

  f32x2 w0p[PAIRS], w1p[PAIRS], w2p[PAIRS], atp[PAIRS], xrp[PAIRS];
  {
    u32 xraw[PAIRS];
    *(uint4*)xraw = *(const uint4*)((const u32*)((const short*)xr + (size_t)d * ldx + j0));
#pragma unroll
    for (int k = 0; k < PAIRS; ++k) {
      xrp[k] = bf2pair(xraw[k]);
      w0p[k] = *(const f32x2*)(We + j0 + 2 * k);
      w1p[k] = *(const f32x2*)(We + HC + j0 + 2 * k);
      w2p[k] = *(const f32x2*)(We + 2 * HC + j0 + 2 * k);
      atp[k] = *(const f32x2*)(att + j0 + 2 * k);
    }
  }
  f32x2 p02;
  p02[0] = 0.2f; p02[1] = 0.2f;

  float m_run = -INFINITY, ssum = 0.f;
  f32x2 accp[PAIRS];
#pragma unroll
  for (int k = 0; k < PAIRS; ++k) accp[k] = {0.f, 0.f};

  const short* xls = (const short*)xl;

#define LOADR(R, IDX)                                                          \
  {                                                                            \
    int s_ = __builtin_amdgcn_readlane(sv, (IDX));                             \
    *(uint4*)(R) = *(const uint4*)((const u32*)(xls + (size_t)s_ * ldx + j0)); \
  }

  for (int base = beg; base < end; base += 64) {
    const int nb = min(64, end - base);
    int eidv = 0, sv = 0;
    if (lane < nb) {
      eidv = perm[base + lane];
      sv = src[eidv];
      float a0 = ea[3 * (size_t)eidv], a1 = ea[3 * (size_t)eidv + 1],
            a2 = ea[3 * (size_t)eidv + 2];
      s_ef[wv][lane] = make_float4(a0, a1, a2, a2);
    }
    asm volatile("s_waitcnt lgkmcnt(0)" ::: "memory");

    u32 r0[PAIRS], r1[PAIRS], r2[PAIRS], r3[PAIRS];
    LOADR(r0, 0);
    LOADR(r1, min(1, nb - 1));
    LOADR(r2, min(2, nb - 1));
    LOADR(r3, min(3, nb - 1));

#define PROC_PAIR(RA, RB, IBASE)                                               \
  {                                                                            \
    const int iA = (IBASE), iB = (IBASE) + 1;                                  \
    const bool hasA = iA < nb, hasB = iB < nb;                                 \
    const float4 efA = s_ef[wv][iA & 63];                                      \
    const float4 efB = s_ef[wv][iB & 63];                                      \
    f32x2 eA01, eA22, eB01, eB22;                                              \
    eA01[0] = efA.x; eA01[1] = efA.y; eA22[0] = efA.z; eA22[1] = efA.w;        \
    eB01[0] = efB.x; eB01[1] = efB.y; eB22[0] = efB.z; eB22[1] = efB.w;        \
    f32x2 xvA[PAIRS], xvB[PAIRS];                                              \
    f32x2 pa2 = {0.f, 0.f}, pb2 = {0.f, 0.f};                                  \
    _Pragma("unroll") for (int k = 0; k < PAIRS; ++k) {                        \
      xvA[k] = bf2pair((RA)[k]);                                               \
      f32x2 u = pk_add(xvA[k], xrp[k]);                                        \
      u = pk_fma_b0(w0p[k], eA01, u);                                          \
      u = pk_fma_b1(w1p[k], eA01, u);                                          \
      u = pk_fma(w2p[k], eA22, u);                                             \
      f32x2 t = pk_mul(u, p02);                                                \
      f32x2 l;                                                                 \
      l[0] = fmaxf(u[0], t[0]);                                                \
      l[1] = fmaxf(u[1], t[1]);                                                \
      pa2 = pk_fma(l, atp[k], pa2);                                            \
    }                                                                          \
    _Pragma("unroll") for (int k = 0; k < PAIRS; ++k) {                        \
      xvB[k] = bf2pair((RB)[k]);                                               \
      f32x2 u = pk_add(xvB[k], xrp[k]);                                        \
      u = pk_fma_b0(w0p[k], eB01, u);                                          \
      u = pk_fma_b1(w1p[k], eB01, u);                                          \
      u = pk_fma(w2p[k], eB22, u);                                             \
      f32x2 t = pk_mul(u, p02);                                                \
      f32x2 l;                                                                 \
      l[0] = fmaxf(u[0], t[0]);                                                \
      l[1] = fmaxf(u[1], t[1]);                                                \
      pb2 = pk_fma(l, atp[k], pb2);                                            \
    }                                                                          \
    float pA = pa2[0] + pa2[1];                                                \
    float pB = pb2[0] + pb2[1];                                                \
    if (iA + 4 < nb) LOADR(RA, iA + 4);                                        \
    if (iB + 4 < nb) LOADR(RB, iB + 4);                                        \
    pA = dpp_add<0xB1>(pA);  pB = dpp_add<0xB1>(pB);                           \
    pA = dpp_add<0x4E>(pA);  pB = dpp_add<0x4E>(pB);                           \
    pA = dpp_add<0x141>(pA); pB = dpp_add<0x141>(pB);                          \
    pA = dpp_add<0x140>(pA); pB = dpp_add<0x140>(pB);                          \
    pA = swz_add16(pA);      pB = swz_add16(pB);                               \
    if (hasA) {                                                                \
      if (WLOG && (lane & 31) == 0) {                                          \
        const int eidA = __builtin_amdgcn_readlane(eidv, iA);                  \
        logit_out[(size_t)eidA * 4 + hgrp] = pA;                               \
      }                                                                        \
      if (__any(pA > m_run)) {                                                 \
        const float nm = fmaxf(m_run, pA);                                     \
        const float sc = __expf(m_run - nm);                                   \
        ssum *= sc;                                                            \
        f32x2 scp; scp[0] = sc; scp[1] = sc;                                   \
        _Pragma("unroll") for (int k = 0; k < PAIRS; ++k)                      \
            accp[k] = pk_mul_b0(accp[k], scp);                                 \
        m_run = nm;                                                            \
      }                                                                        \
      const float pe = __expf(pA - m_run);                                     \
      ssum += pe;                                                              \
      f32x2 pep; pep[0] = pe; pep[1] = pe;                                     \
      _Pragma("unroll") for (int k = 0; k < PAIRS; ++k)                        \
          accp[k] = pk_fma_b0(xvA[k], pep, accp[k]);                           \
    }                                                                          \
    if (hasB) {                                                                \
      if (WLOG && (lane & 31) == 0) {                                          \
        const int eidB = __builtin_amdgcn_readlane(eidv, iB);                  \
        logit_out[(size_t)eidB * 4 + hgrp] = pB;                               \
      }                                                                        \
      if (__any(pB > m_run)) {                                                 \
        const float nm = fmaxf(m_run, pB);                                     \
        const float sc = __expf(m_run - nm);                                   \
        ssum *= sc;                                                            \
        f32x2 scp; scp[0] = sc; scp[1] = sc;                                   \
        _Pragma("unroll") for (int k = 0; k < PAIRS; ++k)                      \
            accp[k] = pk_mul_b0(accp[k], scp);                                 \
        m_run = nm;                                                            \
      }                                                                        \
      const float pe = __expf(pB - m_run);                                     \
      ssum += pe;                                                              \
      f32x2 pep; pep[0] = pe; pep[1] = pe;                                     \
      _Pragma("unroll") for (int k = 0; k < PAIRS; ++k)                        \
          accp[k] = pk_fma_b0(xvB[k], pep, accp[k]);                           \
    }                                                                          \
  }

    for (int i = 0; i < nb; i += 4) {
      PROC_PAIR(r0, r1, i);
      PROC_PAIR(r2, r3, i + 2);
    }
#undef PROC_PAIR
  }
#undef LOADR

  const float inv = (end > beg) ? 1.f / ssum : 0.f;
  u32 ow[PAIRS];
#pragma unroll
  for (int k = 0; k < PAIRS; ++k) {
    float o0 = accp[k][0] * inv + bias[j0 + 2 * k];
    float o1 = accp[k][1] * inv + bias[j0 + 2 * k + 1];
    hbf16 h0 = __float2bfloat16(o0), h1 = __float2bfloat16(o1);
    ow[k] = (u32)(*(unsigned short*)&h0) | ((u32)(*(unsigned short*)&h1) << 16);
  }
  *(uint4*)((u32*)((short*)out + (size_t)d * HC + j0)) = *(const uint4*)ow;
  if (WLOG && (lane & 31) == 0) {
    mfin[d * 4 + hgrp] = m_run;
    sfin[d * 4 + hgrp] = ssum;
  }
}

// in-place: logit -> alpha = exp(l - mfin[dst]) / sfin[dst]
__global__ __launch_bounds__(256) void alpha_kernel(
    float* __restrict__ la, const float* __restrict__ mfin,
    const float* __restrict__ sfin, const int* __restrict__ dst, int n4) {
  int i = blockIdx.x * 256 + threadIdx.x;
  if (i >= n4) return;
  int e = i >> 2, h = i & 3;
  int d = dst[e];
  la[i] = __expf(la[i] - mfin[d * 4 + h]) / sfin[d * 4 + h];
}

extern "C" void kernel_launch(void* const* d_in, const int* in_sizes, int n_in,
                              void* d_out, int out_size, void* d_ws, size_t ws_size,
                              hipStream_t stream) {
  const float* x    = (const float*)d_in[0];
  const int*   ei   = (const int*)d_in[1];
  const float* ea   = (const float*)d_in[2];
  const float* W1l  = (const float*)d_in[3];
  const float* b1l  = (const float*)d_in[4];
  const float* W1r  = (const float*)d_in[5];
  const float* b1r  = (const float*)d_in[6];
  const float* W1e  = (const float*)d_in[7];
  const float* att1 = (const float*)d_in[8];
  const float* bias1= (const float*)d_in[9];
  const float* W2l  = (const float*)d_in[10];
  const float* b2l  = (const float*)d_in[11];
  const float* W2r  = (const float*)d_in[12];
  const float* b2r  = (const float*)d_in[13];
  const float* W2e  = (const float*)d_in[14];
  const float* att2 = (const float*)d_in[15];
  const float* bias2= (const float*)d_in[16];
  const float* Wp   = (const float*)d_in[17];
  const float* bp   = (const float*)d_in[18];

  const int N = in_sizes[0] / 256;  // 10000
  const int E = in_sizes[1] / 2;    // 320000
  const int* srcI = ei;
  const int* dstI = ei + E;

  // workspace (~68 MB)
  float* wsf = (float*)d_ws;
  float* mfin = wsf;                              // 4N
  float* sfin = mfin + (size_t)4 * N;             // 4N
  int*   P    = (int*)(sfin + (size_t)4 * N);     // N
  int*   part = P + N;                            // 256 (scan partials)
  int*   perm = part + 256;                       // E
  hbf16* xb   = (hbf16*)(perm + E);               // N*256 (x bf16)
  hbf16* xlr  = xb + (size_t)N * 256;             // N*2048 (merged xl|xr; L1 uses N*512)
  hbf16* ho   = xlr + (size_t)N * 2048;           // N*1024 (h first N*256, then out2)
  hbf16* W1lt = ho + (size_t)N * 1024;            // 256*256  (W1rt adjacent)
  hbf16* W1rt = W1lt + 256 * 256;
  hbf16* W2lt = W1rt + 256 * 256;                 // 1024*256 (W2rt adjacent)
  hbf16* W2rt = W2lt + 1024 * 256;
  hbf16* Wpt  = W2rt + 1024 * 256;                // 256*1024

  float* yout = (float*)d_out;                    // N*256
  float* alpha_out = yout + (size_t)N * 256;      // E*4

  const int eB = (E + 255) / 256;
  const int sB = (N + 255) / 256;                 // 40 scan blocks
  const dim3 tb(32, 8);

  // CSR build: hist -> 2-level scan -> scatter
  hipMemsetAsync(P, 0, (size_t)N * 4, stream);
  hist_kernel<<<eB, 256, 0, stream>>>(dstI, P, E);
  scan_sum_kernel<<<sB, 256, 0, stream>>>(P, part, N);
  scan_part_kernel<<<1, 256, 0, stream>>>(part, sB);
  scan_apply_kernel<<<sB, 256, 0, stream>>>(P, part, N);
  scatter_kernel<<<eB, 256, 0, stream>>>(dstI, P, perm, E);

  // bf16 conversions
  cvt_kernel<<<(N * 256 / 4 + 255) / 256, 256, 0, stream>>>(x, xb, N * 256);
  transpose_cvt_kernel<<<dim3(256 / 32, 256 / 32), tb, 0, stream>>>(W1l, W1lt, 256, 256);
  transpose_cvt_kernel<<<dim3(256 / 32, 256 / 32), tb, 0, stream>>>(W1r, W1rt, 256, 256);
  transpose_cvt_kernel<<<dim3(1024 / 32, 256 / 32), tb, 0, stream>>>(W2l, W2lt, 256, 1024);
  transpose_cvt_kernel<<<dim3(1024 / 32, 256 / 32), tb, 0, stream>>>(W2r, W2rt, 256, 1024);
  transpose_cvt_kernel<<<dim3(256 / 32, 1024 / 32), tb, 0, stream>>>(Wp, Wpt, 1024, 256);

  // ---------------- layer 1 (HC=256), merged l|r GEMM N=512 ----------------
  mfma_gemm_kernel<hbf16><<<dim3(512 / 128, (N + 127) / 128), 256, 0, stream>>>(
      xb, W1lt, b1l, b1r, 256, xlr, N, 512, 256);
  fused_gat_wpn_kernel<2, true><<<(N + 3) / 4, 256, 0, stream>>>(
      xlr, xlr + 256, 512, ea, W1e, att1, srcI, P, perm, bias1, ho /*h*/, N);

  // ---------------- layer 2 (HC=1024), merged l|r GEMM N=2048 ----------------
  mfma_gemm_kernel<hbf16><<<dim3(2048 / 128, (N + 127) / 128), 256, 0, stream>>>(
      ho, W2lt, b2l, b2r, 1024, xlr, N, 2048, 256);
  fused_gat_w2_kernel<true><<<(N + 1) / 2, 256, 0, stream>>>(
      xlr, xlr + 1024, 2048, ea, W2e, att2, srcI, P, perm, bias2, ho /*out2*/,
      alpha_out, mfin, sfin, N);
  alpha_kernel<<<(E * 4 + 255) / 256, 256, 0, stream>>>(alpha_out, mfin, sfin, dstI, E * 4);

  // projector
  mfma_gemm_kernel<float><<<dim3(256 / 128, (N + 127) / 128), 256, 0, stream>>>(
      ho, Wpt, bp, bp, 256, yout, N, 256, 1024);
}

// Round 12
// 329.254 us; speedup vs baseline: 1.8902x; 1.0360x over previous
//
#include <hip/hip_runtime.h>
#include <hip/hip_bf16.h>

typedef __hip_bfloat16 hbf16;
typedef unsigned int u32;
typedef __attribute__((ext_vector_type(2))) float f32x2;
typedef __attribute__((ext_vector_type(8))) short bf16x8;
typedef __attribute__((ext_vector_type(4))) float f32x4;

__device__ __forceinline__ f32x2 bf2pair(u32 v) {
  f32x2 o;
  o[0] = __uint_as_float(v << 16);
  o[1] = __uint_as_float(v & 0xffff0000u);
  return o;
}

// ---- packed f32 VOP3P helpers ----
__device__ __forceinline__ f32x2 pk_add(f32x2 a, f32x2 b) {
  f32x2 d; asm("v_pk_add_f32 %0, %1, %2" : "=v"(d) : "v"(a), "v"(b)); return d;
}
__device__ __forceinline__ f32x2 pk_mul(f32x2 a, f32x2 b) {
  f32x2 d; asm("v_pk_mul_f32 %0, %1, %2" : "=v"(d) : "v"(a), "v"(b)); return d;
}
__device__ __forceinline__ f32x2 pk_fma(f32x2 a, f32x2 b, f32x2 c) {
  f32x2 d; asm("v_pk_fma_f32 %0, %1, %2, %3" : "=v"(d) : "v"(a), "v"(b), "v"(c)); return d;
}
__device__ __forceinline__ f32x2 pk_fma_b0(f32x2 a, f32x2 b, f32x2 c) {
  f32x2 d;
  asm("v_pk_fma_f32 %0, %1, %2, %3 op_sel:[0,0,0] op_sel_hi:[1,0,1]"
      : "=v"(d) : "v"(a), "v"(b), "v"(c));
  return d;
}
__device__ __forceinline__ f32x2 pk_fma_b1(f32x2 a, f32x2 b, f32x2 c) {
  f32x2 d;
  asm("v_pk_fma_f32 %0, %1, %2, %3 op_sel:[0,1,0] op_sel_hi:[1,1,1]"
      : "=v"(d) : "v"(a), "v"(b), "v"(c));
  return d;
}
__device__ __forceinline__ f32x2 pk_mul_b0(f32x2 a, f32x2 b) {
  f32x2 d;
  asm("v_pk_mul_f32 %0, %1, %2 op_sel:[0,0] op_sel_hi:[1,0]"
      : "=v"(d) : "v"(a), "v"(b));
  return d;
}

// ---- DPP butterfly add steps (pure VALU, no DS) ----
template <int CTRL>
__device__ __forceinline__ float dpp_add(float p) {
  int t = __builtin_amdgcn_update_dpp(0, __float_as_int(p), CTRL, 0xF, 0xF, true);
  return p + __int_as_float(t);
}
// xor16 within 32-lane group via ds_swizzle bit-mode (no addr calc)
__device__ __forceinline__ float swz_add16(float p) {
  int t = __builtin_amdgcn_ds_swizzle(__float_as_int(p), 0x401F);
  return p + __int_as_float(t);
}

__device__ __forceinline__ void storeO(float* p, float v) { *p = v; }
__device__ __forceinline__ void storeO(hbf16* p, float v) { *p = __float2bfloat16(v); }

// ---------------- merged prep: cvt(x) + 5 weight transposes, one launch ----------
__device__ __forceinline__ void tcvt_dev(const float* __restrict__ W,
                                         hbf16* __restrict__ Wt, int K, int N,
                                         int b, int tid, hbf16 (*tile)[33]) {
  const int nb32 = N >> 5;
  const int n0 = (b % nb32) << 5, k0 = (b / nb32) << 5;
  const int tx = tid & 31, ty = tid >> 5;
#pragma unroll
  for (int i = 0; i < 4; ++i)
    tile[ty * 4 + i][tx] = __float2bfloat16(W[(size_t)(k0 + ty * 4 + i) * N + n0 + tx]);
  __syncthreads();
#pragma unroll
  for (int i = 0; i < 4; ++i)
    Wt[(size_t)(n0 + ty * 4 + i) * K + k0 + tx] = tile[tx][ty * 4 + i];
}

__global__ __launch_bounds__(256) void prep_kernel(
    const float* __restrict__ x, hbf16* __restrict__ xb, int n, int nxB,
    const float* __restrict__ W1l, hbf16* __restrict__ W1lt,
    const float* __restrict__ W1r, hbf16* __restrict__ W1rt,
    const float* __restrict__ W2l, hbf16* __restrict__ W2lt,
    const float* __restrict__ W2r, hbf16* __restrict__ W2rt,
    const float* __restrict__ Wp, hbf16* __restrict__ Wpt) {
  __shared__ hbf16 tile[32][33];
  int b = blockIdx.x;
  const int tid = threadIdx.x;
  if (b < nxB) {
    int i = (b * 256 + tid) * 4;
    if (i < n) {
      float4 v = *(const float4*)(x + i);
      xb[i] = __float2bfloat16(v.x);
      xb[i + 1] = __float2bfloat16(v.y);
      xb[i + 2] = __float2bfloat16(v.z);
      xb[i + 3] = __float2bfloat16(v.w);
    }
    return;
  }
  b -= nxB;
  if (b < 64) { tcvt_dev(W1l, W1lt, 256, 256, b, tid, tile); return; }
  b -= 64;
  if (b < 64) { tcvt_dev(W1r, W1rt, 256, 256, b, tid, tile); return; }
  b -= 64;
  if (b < 256) { tcvt_dev(W2l, W2lt, 256, 1024, b, tid, tile); return; }
  b -= 256;
  if (b < 256) { tcvt_dev(W2r, W2rt, 256, 1024, b, tid, tile); return; }
  b -= 256;
  tcvt_dev(Wp, Wpt, 1024, 256, b, tid, tile);
}

// ---- MFMA GEMM: C[M,N] = A[M,K](bf16) @ Bt[N,K](bf16)^T + dual bias (split at NS) ----
// register double-buffered k-pipeline: load k+1 fragments before MFMAs of k.
template <typename OutT>
__global__ __launch_bounds__(256) void mfma_gemm_kernel(
    const hbf16* __restrict__ A, const hbf16* __restrict__ Bt,
    const float* __restrict__ bias0, const float* __restrict__ bias1, int NS,
    OutT* __restrict__ C, int M, int N, int K) {
  const int tid = threadIdx.x, lane = tid & 63, w = tid >> 6;
  const int wr = w >> 1, wc = w & 1;
  const int rowb = blockIdx.y * 128 + wr * 64;
  const int colb = blockIdx.x * 128 + wc * 64;
  const int lr = lane & 15, lk = (lane >> 4) * 8;

  f32x4 acc[4][4];
#pragma unroll
  for (int mi = 0; mi < 4; ++mi)
#pragma unroll
    for (int ni = 0; ni < 4; ++ni) acc[mi][ni] = {0.f, 0.f, 0.f, 0.f};

  const short* Ap = (const short*)A;
  const short* Bp = (const short*)Bt;

  int ar[4];
#pragma unroll
  for (int mi = 0; mi < 4; ++mi) {
    int r = rowb + mi * 16 + lr;
    ar[mi] = (r < M) ? r : (M - 1);  // clamp: garbage rows never stored
  }

  bf16x8 afC[4], bfC[4];
#pragma unroll
  for (int mi = 0; mi < 4; ++mi)
    afC[mi] = *(const bf16x8*)(Ap + (size_t)ar[mi] * K + lk);
#pragma unroll
  for (int ni = 0; ni < 4; ++ni)
    bfC[ni] = *(const bf16x8*)(Bp + (size_t)(colb + ni * 16 + lr) * K + lk);

  for (int k0 = 0; k0 < K; k0 += 32) {
    bf16x8 afN[4], bfN[4];
    const int kn = k0 + 32;
    if (kn < K) {
#pragma unroll
      for (int mi = 0; mi < 4; ++mi)
        afN[mi] = *(const bf16x8*)(Ap + (size_t)ar[mi] * K + kn + lk);
#pragma unroll
      for (int ni = 0; ni < 4; ++ni)
        bfN[ni] = *(const bf16x8*)(Bp + (size_t)(colb + ni * 16 + lr) * K + kn + lk);
    }
#pragma unroll
    for (int mi = 0; mi < 4; ++mi)
#pragma unroll
      for (int ni = 0; ni < 4; ++ni)
        acc[mi][ni] = __builtin_amdgcn_mfma_f32_16x16x32_bf16(afC[mi], bfC[ni],
                                                              acc[mi][ni], 0, 0, 0);
#pragma unroll
    for (int mi = 0; mi < 4; ++mi) afC[mi] = afN[mi];
#pragma unroll
    for (int ni = 0; ni < 4; ++ni) bfC[ni] = bfN[ni];
  }

  float bv[4];
#pragma unroll
  for (int ni = 0; ni < 4; ++ni) {
    int gc = colb + ni * 16 + lr;
    bv[ni] = (gc < NS) ? bias0[gc] : bias1[gc - NS];
  }
#pragma unroll
  for (int mi = 0; mi < 4; ++mi) {
    const int row0 = rowb + mi * 16 + (lane >> 4) * 4;
#pragma unroll
    for (int r = 0; r < 4; ++r) {
      const int row = row0 + r;
      if (row >= M) continue;
#pragma unroll
      for (int ni = 0; ni < 4; ++ni)
        storeO(&C[(size_t)row * N + colb + ni * 16 + lr], acc[mi][ni][r] + bv[ni]);
    }
  }
}

// ---------------- CSR build (parallel 2-level scan) ----------------
__global__ __launch_bounds__(256) void hist_kernel(const int* __restrict__ dst,
                                                   int* __restrict__ P, int E) {
  int i = blockIdx.x * 256 + threadIdx.x;
  if (i < E) atomicAdd(&P[dst[i]], 1);
}

__global__ __launch_bounds__(256) void scan_sum_kernel(const int* __restrict__ P,
                                                       int* __restrict__ part, int n) {
  __shared__ int s[256];
  int i = blockIdx.x * 256 + threadIdx.x;
  s[threadIdx.x] = (i < n) ? P[i] : 0;
  __syncthreads();
#pragma unroll
  for (int off = 128; off; off >>= 1) {
    if (threadIdx.x < off) s[threadIdx.x] += s[threadIdx.x + off];
    __syncthreads();
  }
  if (threadIdx.x == 0) part[blockIdx.x] = s[0];
}

__global__ __launch_bounds__(256) void scan_part_kernel(int* __restrict__ part, int nb) {
  __shared__ int s[256];
  int v = (threadIdx.x < nb) ? part[threadIdx.x] : 0;
  s[threadIdx.x] = v;
  __syncthreads();
#pragma unroll
  for (int off = 1; off < 256; off <<= 1) {
    int t = (threadIdx.x >= off) ? s[threadIdx.x - off] : 0;
    __syncthreads();
    s[threadIdx.x] += t;
    __syncthreads();
  }
  if (threadIdx.x < nb) part[threadIdx.x] = s[threadIdx.x] - v;
}

__global__ __launch_bounds__(256) void scan_apply_kernel(int* __restrict__ P,
                                                         const int* __restrict__ part,
                                                         int n) {
  __shared__ int s[256];
  int i = blockIdx.x * 256 + threadIdx.x;
  int v = (i < n) ? P[i] : 0;
  s[threadIdx.x] = v;
  __syncthreads();
#pragma unroll
  for (int off = 1; off < 256; off <<= 1) {
    int t = (threadIdx.x >= off) ? s[threadIdx.x - off] : 0;
    __syncthreads();
    s[threadIdx.x] += t;
    __syncthreads();
  }
  if (i < n) P[i] = s[threadIdx.x] - v + part[blockIdx.x];
}

__global__ __launch_bounds__(256) void scatter_kernel(const int* __restrict__ dst,
                                                      int* __restrict__ P,
                                                      int* __restrict__ perm, int E) {
  int i = blockIdx.x * 256 + threadIdx.x;
  if (i < E) {
    int pos = atomicAdd(&P[dst[i]], 1);
    perm[pos] = i;
  }
}

// ---------------- fused GATv2 layer 1: ONE WAVE PER NODE (PAIRS=2, CPT=4) --------
// 16-lane head groups; reduce = 4 DPP, zero DS; 4-edge-deep gather ring.
__global__ __launch_bounds__(256) void fused_gat_l1_kernel(
    const hbf16* __restrict__ xl, const hbf16* __restrict__ xr, int ldx,
    const float* __restrict__ ea, const float* __restrict__ We,
    const float* __restrict__ att, const int* __restrict__ src,
    const int* __restrict__ Pend, const int* __restrict__ perm,
    const float* __restrict__ bias, hbf16* __restrict__ out, int NN) {
  constexpr int PAIRS = 2, HC = 256;
  const int lane = threadIdx.x & 63;
  const int w = threadIdx.x >> 6;
  const int d = blockIdx.x * 4 + w;
  __shared__ float4 s_ef[4][64];
  if (d >= NN) return;
  const int beg = (d == 0) ? 0 : Pend[d - 1];
  const int end = Pend[d];
  const int j0 = lane * 4;

  f32x2 w0p[PAIRS], w1p[PAIRS], w2p[PAIRS], atp[PAIRS], xrp[PAIRS];
  {
    u32 xraw[PAIRS];
    *(uint2*)xraw = *(const uint2*)((const u32*)((const short*)xr + (size_t)d * ldx + j0));
#pragma unroll
    for (int k = 0; k < PAIRS; ++k) {
      xrp[k] = bf2pair(xraw[k]);
      w0p[k] = *(const f32x2*)(We + j0 + 2 * k);
      w1p[k] = *(const f32x2*)(We + HC + j0 + 2 * k);
      w2p[k] = *(const f32x2*)(We + 2 * HC + j0 + 2 * k);
      atp[k] = *(const f32x2*)(att + j0 + 2 * k);
    }
  }
  f32x2 p02;
  p02[0] = 0.2f; p02[1] = 0.2f;

  float m_run = -INFINITY, ssum = 0.f;
  f32x2 accp[PAIRS];
#pragma unroll
  for (int k = 0; k < PAIRS; ++k) accp[k] = {0.f, 0.f};

  const short* xls = (const short*)xl;

#define LOADR1(R, IDX)                                                          \
  {                                                                             \
    int s_ = __builtin_amdgcn_readlane(sv, (IDX));                              \
    *(uint2*)(R) = *(const uint2*)((const u32*)(xls + (size_t)s_ * ldx + j0));  \
  }

  for (int base = beg; base < end; base += 64) {
    const int nb = min(64, end - base);
    int sv = 0;
    if (lane < nb) {
      int eid = perm[base + lane];
      sv = src[eid];
      float a0 = ea[3 * (size_t)eid], a1 = ea[3 * (size_t)eid + 1],
            a2 = ea[3 * (size_t)eid + 2];
      s_ef[w][lane] = make_float4(a0, a1, a2, a2);
    }
    asm volatile("s_waitcnt lgkmcnt(0)" ::: "memory");

    u32 r0[PAIRS], r1[PAIRS], r2[PAIRS], r3[PAIRS];
    LOADR1(r0, 0);
    LOADR1(r1, min(1, nb - 1));
    LOADR1(r2, min(2, nb - 1));
    LOADR1(r3, min(3, nb - 1));

#define PROC1_PAIR(RA, RB, IBASE)                                              \
  {                                                                            \
    const int iA = (IBASE), iB = (IBASE) + 1;                                  \
    const bool hasA = iA < nb, hasB = iB < nb;                                 \
    const float4 efA = s_ef[w][iA & 63];                                       \
    const float4 efB = s_ef[w][iB & 63];                                       \
    f32x2 eA01, eA22, eB01, eB22;                                              \
    eA01[0] = efA.x; eA01[1] = efA.y; eA22[0] = efA.z; eA22[1] = efA.w;        \
    eB01[0] = efB.x; eB01[1] = efB.y; eB22[0] = efB.z; eB22[1] = efB.w;        \
    f32x2 xvA[PAIRS], xvB[PAIRS];                                              \
    f32x2 pa2 = {0.f, 0.f}, pb2 = {0.f, 0.f};                                  \
    _Pragma("unroll") for (int k = 0; k < PAIRS; ++k) {                        \
      xvA[k] = bf2pair((RA)[k]);                                               \
      f32x2 u = pk_add(xvA[k], xrp[k]);                                        \
      u = pk_fma_b0(w0p[k], eA01, u);                                          \
      u = pk_fma_b1(w1p[k], eA01, u);                                          \
      u = pk_fma(w2p[k], eA22, u);                                             \
      f32x2 t = pk_mul(u, p02);                                                \
      f32x2 l;                                                                 \
      l[0] = fmaxf(u[0], t[0]);                                                \
      l[1] = fmaxf(u[1], t[1]);                                                \
      pa2 = pk_fma(l, atp[k], pa2);                                            \
    }                                                                          \
    _Pragma("unroll") for (int k = 0; k < PAIRS; ++k) {                        \
      xvB[k] = bf2pair((RB)[k]);                                               \
      f32x2 u = pk_add(xvB[k], xrp[k]);                                        \
      u = pk_fma_b0(w0p[k], eB01, u);                                          \
      u = pk_fma_b1(w1p[k], eB01, u);                                          \
      u = pk_fma(w2p[k], eB22, u);                                             \
      f32x2 t = pk_mul(u, p02);                                                \
      f32x2 l;                                                                 \
      l[0] = fmaxf(u[0], t[0]);                                                \
      l[1] = fmaxf(u[1], t[1]);                                                \
      pb2 = pk_fma(l, atp[k], pb2);                                            \
    }                                                                          \
    float pA = pa2[0] + pa2[1];                                                \
    float pB = pb2[0] + pb2[1];                                                \
    if (iA + 4 < nb) LOADR1(RA, iA + 4);                                       \
    if (iB + 4 < nb) LOADR1(RB, iB + 4);                                       \
    pA = dpp_add<0xB1>(pA);  pB = dpp_add<0xB1>(pB);                           \
    pA = dpp_add<0x4E>(pA);  pB = dpp_add<0x4E>(pB);                           \
    pA = dpp_add<0x141>(pA); pB = dpp_add<0x141>(pB);                          \
    pA = dpp_add<0x140>(pA); pB = dpp_add<0x140>(pB);                          \
    if (hasA) {                                                                \
      if (__any(pA > m_run)) {                                                 \
        const float nm = fmaxf(m_run, pA);                                     \
        const float sc = __expf(m_run - nm);                                   \
        ssum *= sc;                                                            \
        f32x2 scp; scp[0] = sc; scp[1] = sc;                                   \
        _Pragma("unroll") for (int k = 0; k < PAIRS; ++k)                      \
            accp[k] = pk_mul_b0(accp[k], scp);                                 \
        m_run = nm;                                                            \
      }                                                                        \
      const float pe = __expf(pA - m_run);                                     \
      ssum += pe;                                                              \
      f32x2 pep; pep[0] = pe; pep[1] = pe;                                     \
      _Pragma("unroll") for (int k = 0; k < PAIRS; ++k)                        \
          accp[k] = pk_fma_b0(xvA[k], pep, accp[k]);                           \
    }                                                                          \
    if (hasB) {                                                                \
      if (__any(pB > m_run)) {                                                 \
        const float nm = fmaxf(m_run, pB);                                     \
        const float sc = __expf(m_run - nm);                                   \
        ssum *= sc;                                                            \
        f32x2 scp; scp[0] = sc; scp[1] = sc;                                   \
        _Pragma("unroll") for (int k = 0; k < PAIRS; ++k)                      \
            accp[k] = pk_mul_b0(accp[k], scp);                                 \
        m_run = nm;                                                            \
      }                                                                        \
      const float pe = __expf(pB - m_run);                                     \
      ssum += pe;                                                              \
      f32x2 pep; pep[0] = pe; pep[1] = pe;                                     \
      _Pragma("unroll") for (int k = 0; k < PAIRS; ++k)                        \
          accp[k] = pk_fma_b0(xvB[k], pep, accp[k]);                           \
    }                                                                          \
  }

    for (int i = 0; i < nb; i += 4) {
      PROC1_PAIR(r0, r1, i);
      PROC1_PAIR(r2, r3, i + 2);
    }
#undef PROC1_PAIR
  }
#undef LOADR1

  const float inv = (end > beg) ? 1.f / ssum : 0.f;
  u32 ow[PAIRS];
#pragma unroll
  for (int k = 0; k < PAIRS; ++k) {
    float o0 = accp[k][0] * inv + bias[j0 + 2 * k];
    float o1 = accp[k][1] * inv + bias[j0 + 2 * k + 1];
    o0 = o0 / (1.f + __expf(-o0));
    o1 = o1 / (1.f + __expf(-o1));
    hbf16 h0 = __float2bfloat16(o0), h1 = __float2bfloat16(o1);
    ow[k] = (u32)(*(unsigned short*)&h0) | ((u32)(*(unsigned short*)&h1) << 16);
  }
  *(uint2*)((u32*)((short*)out + (size_t)d * HC + j0)) = *(const uint2*)ow;
}

// ---------------- fused GATv2 layer 2: TWO WAVES PER NODE (PAIRS=4, CPT=8) --------
template <bool WLOG>
__global__ __launch_bounds__(256) void fused_gat_w2_kernel(
    const hbf16* __restrict__ xl, const hbf16* __restrict__ xr, int ldx,
    const float* __restrict__ ea, const float* __restrict__ We,
    const float* __restrict__ att, const int* __restrict__ src,
    const int* __restrict__ Pend, const int* __restrict__ perm,
    const float* __restrict__ bias, hbf16* __restrict__ out,
    float* __restrict__ logit_out, float2* __restrict__ msbuf, int NN) {
  constexpr int PAIRS = 4, HC = 1024;
  const int lane = threadIdx.x & 63;
  const int wv = threadIdx.x >> 6;
  const int w = wv & 1;
  const int d = blockIdx.x * 2 + (wv >> 1);
  __shared__ float4 s_ef[4][64];
  if (d >= NN) return;
  const int beg = (d == 0) ? 0 : Pend[d - 1];
  const int end = Pend[d];
  const int hgrp = (w << 1) | (lane >> 5);
  const int j0 = hgrp * 256 + (lane & 31) * 8;

  f32x2 w0p[PAIRS], w1p[PAIRS], w2p[PAIRS], atp[PAIRS], xrp[PAIRS];
  {
    u32 xraw[PAIRS];
    *(uint4*)xraw = *(const uint4*)((const u32*)((const short*)xr + (size_t)d * ldx + j0));
#pragma unroll
    for (int k = 0; k < PAIRS; ++k) {
      xrp[k] = bf2pair(xraw[k]);
      w0p[k] = *(const f32x2*)(We + j0 + 2 * k);
      w1p[k] = *(const f32x2*)(We + HC + j0 + 2 * k);
      w2p[k] = *(const f32x2*)(We + 2 * HC + j0 + 2 * k);
      atp[k] = *(const f32x2*)(att + j0 + 2 * k);
    }
  }
  f32x2 p02;
  p02[0] = 0.2f; p02[1] = 0.2f;

  float m_run = -INFINITY, ssum = 0.f;
  f32x2 accp[PAIRS];
#pragma unroll
  for (int k = 0; k < PAIRS; ++k) accp[k] = {0.f, 0.f};

  const short* xls = (const short*)xl;

#define LOADR(R, IDX)                                                          \
  {                                                                            \
    int s_ = __builtin_amdgcn_readlane(sv, (IDX));                             \
    *(uint4*)(R) = *(const uint4*)((const u32*)(xls + (size_t)s_ * ldx + j0)); \
  }

  for (int base = beg; base < end; base += 64) {
    const int nb = min(64, end - base);
    int eidv = 0, sv = 0;
    if (lane < nb) {
      eidv = perm[base + lane];
      sv = src[eidv];
      float a0 = ea[3 * (size_t)eidv], a1 = ea[3 * (size_t)eidv + 1],
            a2 = ea[3 * (size_t)eidv + 2];
      s_ef[wv][lane] = make_float4(a0, a1, a2, a2);
    }
    asm volatile("s_waitcnt lgkmcnt(0)" ::: "memory");

    u32 r0[PAIRS], r1[PAIRS], r2[PAIRS], r3[PAIRS];
    LOADR(r0, 0);
    LOADR(r1, min(1, nb - 1));
    LOADR(r2, min(2, nb - 1));
    LOADR(r3, min(3, nb - 1));

#define PROC_PAIR(RA, RB, IBASE)                                               \
  {                                                                            \
    const int iA = (IBASE), iB = (IBASE) + 1;                                  \
    const bool hasA = iA < nb, hasB = iB < nb;                                 \
    const float4 efA = s_ef[wv][iA & 63];                                      \
    const float4 efB = s_ef[wv][iB & 63];                                      \
    f32x2 eA01, eA22, eB01, eB22;                                              \
    eA01[0] = efA.x; eA01[1] = efA.y; eA22[0] = efA.z; eA22[1] = efA.w;        \
    eB01[0] = efB.x; eB01[1] = efB.y; eB22[0] = efB.z; eB22[1] = efB.w;        \
    f32x2 xvA[PAIRS], xvB[PAIRS];                                              \
    f32x2 pa2 = {0.f, 0.f}, pb2 = {0.f, 0.f};                                  \
    _Pragma("unroll") for (int k = 0; k < PAIRS; ++k) {                        \
      xvA[k] = bf2pair((RA)[k]);                                               \
      f32x2 u = pk_add(xvA[k], xrp[k]);                                        \
      u = pk_fma_b0(w0p[k], eA01, u);                                          \
      u = pk_fma_b1(w1p[k], eA01, u);                                          \
      u = pk_fma(w2p[k], eA22, u);                                             \
      f32x2 t = pk_mul(u, p02);                                                \
      f32x2 l;                                                                 \
      l[0] = fmaxf(u[0], t[0]);                                                \
      l[1] = fmaxf(u[1], t[1]);                                                \
      pa2 = pk_fma(l, atp[k], pa2);                                            \
    }                                                                          \
    _Pragma("unroll") for (int k = 0; k < PAIRS; ++k) {                        \
      xvB[k] = bf2pair((RB)[k]);                                               \
      f32x2 u = pk_add(xvB[k], xrp[k]);                                        \
      u = pk_fma_b0(w0p[k], eB01, u);                                          \
      u = pk_fma_b1(w1p[k], eB01, u);                                          \
      u = pk_fma(w2p[k], eB22, u);                                             \
      f32x2 t = pk_mul(u, p02);                                                \
      f32x2 l;                                                                 \
      l[0] = fmaxf(u[0], t[0]);                                                \
      l[1] = fmaxf(u[1], t[1]);                                                \
      pb2 = pk_fma(l, atp[k], pb2);                                            \
    }                                                                          \
    float pA = pa2[0] + pa2[1];                                                \
    float pB = pb2[0] + pb2[1];                                                \
    if (iA + 4 < nb) LOADR(RA, iA + 4);                                        \
    if (iB + 4 < nb) LOADR(RB, iB + 4);                                        \
    pA = dpp_add<0xB1>(pA);  pB = dpp_add<0xB1>(pB);                           \
    pA = dpp_add<0x4E>(pA);  pB = dpp_add<0x4E>(pB);                           \
    pA = dpp_add<0x141>(pA); pB = dpp_add<0x141>(pB);                          \
    pA = dpp_add<0x140>(pA); pB = dpp_add<0x140>(pB);                          \
    pA = swz_add16(pA);      pB = swz_add16(pB);                               \
    if (hasA) {                                                                \
      if (WLOG && (lane & 31) == 0) {                                          \
        const int eidA = __builtin_amdgcn_readlane(eidv, iA);                  \
        logit_out[(size_t)eidA * 4 + hgrp] = pA;                               \
      }                                                                        \
      if (__any(pA > m_run)) {                                                 \
        const float nm = fmaxf(m_run, pA);                                     \
        const float sc = __expf(m_run - nm);                                   \
        ssum *= sc;                                                            \
        f32x2 scp; scp[0] = sc; scp[1] = sc;                                   \
        _Pragma("unroll") for (int k = 0; k < PAIRS; ++k)                      \
            accp[k] = pk_mul_b0(accp[k], scp);                                 \
        m_run = nm;                                                            \
      }                                                                        \
      const float pe = __expf(pA - m_run);                                     \
      ssum += pe;                                                              \
      f32x2 pep; pep[0] = pe; pep[1] = pe;                                     \
      _Pragma("unroll") for (int k = 0; k < PAIRS; ++k)                        \
          accp[k] = pk_fma_b0(xvA[k], pep, accp[k]);                           \
    }                                                                          \
    if (hasB) {                                                                \
      if (WLOG && (lane & 31) == 0) {                                          \
        const int eidB = __builtin_amdgcn_readlane(eidv, iB);                  \
        logit_out[(size_t)eidB * 4 + hgrp] = pB;                               \
      }                                                                        \
      if (__any(pB > m_run)) {                                                 \
        const float nm = fmaxf(m_run, pB);                                     \
        const float sc = __expf(m_run - nm);                                   \
        ssum *= sc;                                                            \
        f32x2 scp; scp[0] = sc; scp[1] = sc;                                   \
        _Pragma("unroll") for (int k = 0; k < PAIRS; ++k)                      \
            accp[k] = pk_mul_b0(accp[k], scp);                                 \
        m_run = nm;                                                            \
      }                                                                        \
      const float pe = __expf(pB - m_run);                                     \
      ssum += pe;                                                              \
      f32x2 pep; pep[0] = pe; pep[1] = pe;                                     \
      _Pragma("unroll") for (int k = 0; k < PAIRS; ++k)                        \
          accp[k] = pk_fma_b0(xvB[k], pep, accp[k]);                           \
    }                                                                          \
  }

    for (int i = 0; i < nb; i += 4) {
      PROC_PAIR(r0, r1, i);
      PROC_PAIR(r2, r3, i + 2);
    }
#undef PROC_PAIR
  }
#undef LOADR

  const float inv = (end > beg) ? 1.f / ssum : 0.f;
  u32 ow[PAIRS];
#pragma unroll
  for (int k = 0; k < PAIRS; ++k) {
    float o0 = accp[k][0] * inv + bias[j0 + 2 * k];
    float o1 = accp[k][1] * inv + bias[j0 + 2 * k + 1];
    hbf16 h0 = __float2bfloat16(o0), h1 = __float2bfloat16(o1);
    ow[k] = (u32)(*(unsigned short*)&h0) | ((u32)(*(unsigned short*)&h1) << 16);
  }
  *(uint4*)((u32*)((short*)out + (size_t)d * HC + j0)) = *(const uint4*)ow;
  if (WLOG && (lane & 31) == 0) msbuf[d * 4 + hgrp] = make_float2(m_run, ssum);
}

// in-place: logit -> alpha = exp(l - m)/s, (m,s) packed as float2
__global__ __launch_bounds__(256) void alpha_kernel(
    float* __restrict__ la, const float2* __restrict__ msbuf,
    const int* __restrict__ dst, int n4) {
  int i = blockIdx.x * 256 + threadIdx.x;
  if (i >= n4) return;
  int e = i >> 2, h = i & 3;
  int d = dst[e];
  float2 ms = msbuf[d * 4 + h];
  la[i] = __expf(la[i] - ms.x) / ms.y;
}

extern "C" void kernel_launch(void* const* d_in, const int* in_sizes, int n_in,
                              void* d_out, int out_size, void* d_ws, size_t ws_size,
                              hipStream_t stream) {
  const float* x    = (const float*)d_in[0];
  const int*   ei   = (const int*)d_in[1];
  const float* ea   = (const float*)d_in[2];
  const float* W1l  = (const float*)d_in[3];
  const float* b1l  = (const float*)d_in[4];
  const float* W1r  = (const float*)d_in[5];
  const float* b1r  = (const float*)d_in[6];
  const float* W1e  = (const float*)d_in[7];
  const float* att1 = (const float*)d_in[8];
  const float* bias1= (const float*)d_in[9];
  const float* W2l  = (const float*)d_in[10];
  const float* b2l  = (const float*)d_in[11];
  const float* W2r  = (const float*)d_in[12];
  const float* b2r  = (const float*)d_in[13];
  const float* W2e  = (const float*)d_in[14];
  const float* att2 = (const float*)d_in[15];
  const float* bias2= (const float*)d_in[16];
  const float* Wp   = (const float*)d_in[17];
  const float* bp   = (const float*)d_in[18];

  const int N = in_sizes[0] / 256;  // 10000
  const int E = in_sizes[1] / 2;    // 320000
  const int* srcI = ei;
  const int* dstI = ei + E;

  // workspace (~68 MB)
  float* wsf = (float*)d_ws;
  float2* msbuf = (float2*)wsf;                   // 4N float2
  int*   P    = (int*)(wsf + (size_t)8 * N);      // N
  int*   part = P + N;                            // 256 (scan partials)
  int*   perm = part + 256;                       // E
  hbf16* xb   = (hbf16*)(perm + E);               // N*256 (x bf16)
  hbf16* xlr  = xb + (size_t)N * 256;             // N*2048 (merged xl|xr; L1 uses N*512)
  hbf16* ho   = xlr + (size_t)N * 2048;           // N*1024 (h first N*256, then out2)
  hbf16* W1lt = ho + (size_t)N * 1024;            // 256*256  (W1rt adjacent)
  hbf16* W1rt = W1lt + 256 * 256;
  hbf16* W2lt = W1rt + 256 * 256;                 // 1024*256 (W2rt adjacent)
  hbf16* W2rt = W2lt + 1024 * 256;
  hbf16* Wpt  = W2rt + 1024 * 256;                // 256*1024

  float* yout = (float*)d_out;                    // N*256
  float* alpha_out = yout + (size_t)N * 256;      // E*4

  const int eB = (E + 255) / 256;
  const int sB = (N + 255) / 256;                 // 40 scan blocks

  // CSR build: hist -> 2-level scan -> scatter
  hipMemsetAsync(P, 0, (size_t)N * 4, stream);
  hist_kernel<<<eB, 256, 0, stream>>>(dstI, P, E);
  scan_sum_kernel<<<sB, 256, 0, stream>>>(P, part, N);
  scan_part_kernel<<<1, 256, 0, stream>>>(part, sB);
  scan_apply_kernel<<<sB, 256, 0, stream>>>(P, part, N);
  scatter_kernel<<<eB, 256, 0, stream>>>(dstI, P, perm, E);

  // merged prep: cvt(x) + 5 weight transposes
  const int nx = N * 256;
  const int nxB = (nx / 4 + 255) / 256;
  prep_kernel<<<nxB + 896, 256, 0, stream>>>(x, xb, nx, nxB, W1l, W1lt, W1r, W1rt,
                                             W2l, W2lt, W2r, W2rt, Wp, Wpt);

  // ---------------- layer 1 (HC=256), merged l|r GEMM N=512 ----------------
  mfma_gemm_kernel<hbf16><<<dim3(512 / 128, (N + 127) / 128), 256, 0, stream>>>(
      xb, W1lt, b1l, b1r, 256, xlr, N, 512, 256);
  fused_gat_l1_kernel<<<(N + 3) / 4, 256, 0, stream>>>(
      xlr, xlr + 256, 512, ea, W1e, att1, srcI, P, perm, bias1, ho /*h*/, N);

  // ---------------- layer 2 (HC=1024), merged l|r GEMM N=2048 ----------------
  mfma_gemm_kernel<hbf16><<<dim3(2048 / 128, (N + 127) / 128), 256, 0, stream>>>(
      ho, W2lt, b2l, b2r, 1024, xlr, N, 2048, 256);
  fused_gat_w2_kernel<true><<<(N + 1) / 2, 256, 0, stream>>>(
      xlr, xlr + 1024, 2048, ea, W2e, att2, srcI, P, perm, bias2, ho /*out2*/,
      alpha_out, msbuf, N);
  alpha_kernel<<<(E * 4 + 255) / 256, 256, 0, stream>>>(alpha_out, msbuf, dstI, E * 4);

  // projector
  mfma_gemm_kernel<float><<<dim3(256 / 128, (N + 127) / 128), 256, 0, stream>>>(
      ho, Wpt, bp, bp, 256, yout, N, 256, 1024);
}